// Round 1
// baseline (2243.712 us; speedup 1.0000x reference)
//
#include <hip/hip_runtime.h>

#define NTX   50000
#define NADDR 50000
#define NE    500000
#define GG    512
#define NEG   0.2f

__device__ __forceinline__ float lrelu(float x) { return x > 0.f ? x : NEG * x; }

// ---------------------------------------------------------------------------
// K1: h = x @ W + b  (N x 128 @ 128 x 128), fused attention-logit dots
//     al_k[n,h] = sum_d h[n, h*32+d] * a_k[h*32+d]
// block = 256 threads (2 x 128 channels), 16 rows per block, W staged in LDS.
// ---------------------------------------------------------------------------
__global__ __launch_bounds__(256) void proj_kernel(
    const float* __restrict__ x, const float* __restrict__ W, const float* __restrict__ b,
    float* __restrict__ h,
    const float* __restrict__ a0, float* __restrict__ al0,
    const float* __restrict__ a1, float* __restrict__ al1,
    const float* __restrict__ a2, float* __restrict__ al2)
{
    __shared__ float Ws[128 * 128];
    __shared__ float xs[16][128];
    const int t = threadIdx.x;
    for (int i = t; i < 128 * 128; i += 256) Ws[i] = W[i];
    const int row0 = blockIdx.x * 16;
    for (int i = t; i < 16 * 128; i += 256) {
        int r = i >> 7, c = i & 127;
        xs[r][c] = x[(size_t)(row0 + r) * 128 + c];
    }
    __syncthreads();

    const int r = t >> 7;   // 0..1
    const int c = t & 127;
    float acc[8];
    const float bc = b[c];
#pragma unroll
    for (int i = 0; i < 8; i++) acc[i] = bc;

    for (int j = 0; j < 128; j++) {
        float w = Ws[j * 128 + c];
#pragma unroll
        for (int i = 0; i < 8; i++)
            acc[i] += xs[r + 2 * i][j] * w;
    }

#pragma unroll
    for (int i = 0; i < 8; i++) {
        int row = row0 + r + 2 * i;
        h[(size_t)row * 128 + c] = acc[i];
    }

    const int head = c >> 5;
    const bool wlead = (c & 31) == 0;

    if (a0) {
        float av = a0[c];
#pragma unroll
        for (int i = 0; i < 8; i++) {
            float p = acc[i] * av;
            for (int off = 16; off >= 1; off >>= 1) p += __shfl_xor(p, off);
            if (wlead) al0[(size_t)(row0 + r + 2 * i) * 4 + head] = p;
        }
    }
    if (a1) {
        float av = a1[c];
#pragma unroll
        for (int i = 0; i < 8; i++) {
            float p = acc[i] * av;
            for (int off = 16; off >= 1; off >>= 1) p += __shfl_xor(p, off);
            if (wlead) al1[(size_t)(row0 + r + 2 * i) * 4 + head] = p;
        }
    }
    if (a2) {
        float av = a2[c];
#pragma unroll
        for (int i = 0; i < 8; i++) {
            float p = acc[i] * av;
            for (int off = 16; off >= 1; off >>= 1) p += __shfl_xor(p, off);
            if (wlead) al2[(size_t)(row0 + r + 2 * i) * 4 + head] = p;
        }
    }
}

// ---------------------------------------------------------------------------
// K3: per (edge, head): ex = exp(leakyrelu(al_s[src]+al_d[dst])); denom[dst] += ex
// (no max-subtraction: logits are O(1), exp is safe in fp32; ratio is exact math)
// ---------------------------------------------------------------------------
__global__ __launch_bounds__(256) void edge_exp_kernel(
    const int* __restrict__ ei,
    const float* __restrict__ al_s, const float* __restrict__ al_d,
    float* __restrict__ ex, float* __restrict__ den)
{
    int idx = blockIdx.x * 256 + threadIdx.x;
    if (idx >= NE * 4) return;
    int e = idx >> 2, hh = idx & 3;
    int s = ei[e], d = ei[NE + e];
    float a = lrelu(al_s[s * 4 + hh] + al_d[d * 4 + hh]);
    float v = expf(a);
    ex[idx] = v;
    atomicAdd(&den[d * 4 + hh], v);
}

// ---------------------------------------------------------------------------
// K4: per (edge, 4-channel chunk): out[dst, c] += h_src[src, c] * ex/(den+eps)
// 32 threads per edge, float4 gathers, 4 fp32 atomics per thread.
// ---------------------------------------------------------------------------
__global__ __launch_bounds__(256) void agg_kernel(
    const int* __restrict__ ei,
    const float* __restrict__ ex, const float* __restrict__ den,
    const float* __restrict__ hsrc, float* __restrict__ out)
{
    int idx = blockIdx.x * 256 + threadIdx.x;  // e*32 + c4
    int e = idx >> 5, c4 = idx & 31;
    int s = ei[e], d = ei[NE + e];
    int hh = c4 >> 3;
    float w = ex[e * 4 + hh] / (den[d * 4 + hh] + 1e-16f);
    const float4 v = *reinterpret_cast<const float4*>(hsrc + (size_t)s * 128 + c4 * 4);
    float* o = out + (size_t)d * 128 + c4 * 4;
    atomicAdd(o + 0, v.x * w);
    atomicAdd(o + 1, v.y * w);
    atomicAdd(o + 2, v.z * w);
    atomicAdd(o + 3, v.w * w);
}

// ---------------------------------------------------------------------------
// K5: per metapath k: relu(out_k); S_k[c] += tanh(row @ Wk + bk)[c];
//     sums_k[batch[n], c] += relu(out_k[n,c]); cnt[g] += 1 (k==0 only).
// block = 256 (2 nodes x 128 channels), 32 nodes/block, Wk staged in LDS.
// ---------------------------------------------------------------------------
__global__ __launch_bounds__(256) void semantic_kernel(
    const float* __restrict__ outk, const float* __restrict__ Wk, const float* __restrict__ bkv,
    const int* __restrict__ batch, float* __restrict__ S, float* __restrict__ sums,
    float* __restrict__ cnt, int do_cnt)
{
    __shared__ float Ws[128 * 128];
    __shared__ float row[2][128];
    const int t = threadIdx.x;
    const int sub = t >> 7, c = t & 127;
    for (int i = t; i < 128 * 128; i += 256) Ws[i] = Wk[i];
    const int n0 = blockIdx.x * 32;
    float accS = 0.f;
    const float bkc = bkv[c];

    for (int i = 0; i < 16; i++) {
        int n = n0 + 2 * i + sub;
        bool ok = n < NTX;
        float v = 0.f;
        if (ok) {
            v = outk[(size_t)n * 128 + c];
            v = v > 0.f ? v : 0.f;
            int g = batch[n];
            atomicAdd(&sums[(size_t)g * 128 + c], v);
            if (do_cnt && c == 0) atomicAdd(cnt + g, 1.0f);
        }
        __syncthreads();            // prior iteration's reads of row[] done
        row[sub][c] = v;
        __syncthreads();            // row staged (also covers Ws staging, i==0)
        if (ok) {
            float y = bkc;
            for (int j = 0; j < 128; j++) y += row[sub][j] * Ws[j * 128 + c];
            accS += tanhf(y);
        }
    }
    atomicAdd(&S[c], accS);
}

// ---------------------------------------------------------------------------
// attn: score_k = (q . S_k) / NTX; attn = softmax over k=2
// ---------------------------------------------------------------------------
__global__ __launch_bounds__(128) void attn_kernel(
    const float* __restrict__ S0, const float* __restrict__ S1,
    const float* __restrict__ q, float* __restrict__ attn)
{
    __shared__ float r0[128], r1[128];
    int c = threadIdx.x;
    r0[c] = q[c] * S0[c];
    r1[c] = q[c] * S1[c];
    __syncthreads();
    for (int s = 64; s > 0; s >>= 1) {
        if (c < s) { r0[c] += r0[c + s]; r1[c] += r1[c + s]; }
        __syncthreads();
    }
    if (c == 0) {
        float s0 = r0[0] / (float)NTX, s1 = r1[0] / (float)NTX;
        float m = fmaxf(s0, s1);
        float e0 = expf(s0 - m), e1 = expf(s1 - m);
        float inv = 1.f / (e0 + e1);
        attn[0] = e0 * inv;
        attn[1] = e1 * inv;
    }
}

// ---------------------------------------------------------------------------
// final: pooled[g,c] = (attn0*sums_at + attn1*sums_tt)/max(cnt,1); out = pooled@Wl + bl
// one block per group, 128 threads, 2-way reduce.
// ---------------------------------------------------------------------------
__global__ __launch_bounds__(128) void final_kernel(
    const float* __restrict__ sums0, const float* __restrict__ sums1,
    const float* __restrict__ cnt, const float* __restrict__ attn,
    const float* __restrict__ Wl, const float* __restrict__ bl,
    float* __restrict__ out)
{
    __shared__ float r0[128], r1[128];
    int g = blockIdx.x, c = threadIdx.x;
    float ct = fmaxf(cnt[g], 1.0f);
    float pooled = (attn[0] * sums0[(size_t)g * 128 + c] +
                    attn[1] * sums1[(size_t)g * 128 + c]) / ct;
    r0[c] = pooled * Wl[c * 2 + 0];
    r1[c] = pooled * Wl[c * 2 + 1];
    __syncthreads();
    for (int s = 64; s > 0; s >>= 1) {
        if (c < s) { r0[c] += r0[c + s]; r1[c] += r1[c + s]; }
        __syncthreads();
    }
    if (c == 0) {
        out[g * 2 + 0] = r0[0] + bl[0];
        out[g * 2 + 1] = r1[0] + bl[1];
    }
}

// ---------------------------------------------------------------------------
extern "C" void kernel_launch(void* const* d_in, const int* in_sizes, int n_in,
                              void* d_out, int out_size, void* d_ws, size_t ws_size,
                              hipStream_t stream)
{
    const float* x_tx     = (const float*)d_in[0];
    const float* x_ad     = (const float*)d_in[1];
    // d_in[2] = ei_ta (dead: out_ta never consumed)
    const int*   ei_at    = (const int*)d_in[3];
    const int*   ei_tt    = (const int*)d_in[4];
    const int*   batch    = (const int*)d_in[5];
    const float* W_tx     = (const float*)d_in[6];
    const float* b_tx     = (const float*)d_in[7];
    const float* W_ad     = (const float*)d_in[8];
    const float* b_ad     = (const float*)d_in[9];
    // d_in[10], d_in[11] = a_src_ta, a_dst_ta (dead)
    const float* a_src_at = (const float*)d_in[12];
    const float* a_dst_at = (const float*)d_in[13];
    const float* a_src_tt = (const float*)d_in[14];
    const float* a_dst_tt = (const float*)d_in[15];
    const float* Wk       = (const float*)d_in[16];
    const float* bk       = (const float*)d_in[17];
    const float* q        = (const float*)d_in[18];
    const float* Wl       = (const float*)d_in[19];
    const float* bl       = (const float*)d_in[20];
    float* out = (float*)d_out;

    char* ws = (char*)d_ws;
    size_t off = 0;
    auto alloc = [&](size_t bytes) -> void* {
        void* p = ws + off;
        off += (bytes + 255) & ~(size_t)255;
        return p;
    };
    float* h_tx   = (float*)alloc((size_t)NTX * 128 * 4);
    float* h_ad   = (float*)alloc((size_t)NADDR * 128 * 4);
    float* al_sat = (float*)alloc((size_t)NADDR * 4 * 4);  // a_src_at . h_ad
    float* al_dat = (float*)alloc((size_t)NTX * 4 * 4);    // a_dst_at . h_tx
    float* al_stt = (float*)alloc((size_t)NTX * 4 * 4);
    float* al_dtt = (float*)alloc((size_t)NTX * 4 * 4);
    float* ex_at  = (float*)alloc((size_t)NE * 4 * 4);
    float* ex_tt  = (float*)alloc((size_t)NE * 4 * 4);
    // ---- zeroed region (accumulators) ----
    char* zero0 = ws + off;
    float* den_at  = (float*)alloc((size_t)NTX * 4 * 4);
    float* den_tt  = (float*)alloc((size_t)NTX * 4 * 4);
    float* out_at  = (float*)alloc((size_t)NTX * 128 * 4);
    float* out_tt  = (float*)alloc((size_t)NTX * 128 * 4);
    float* sums_at = (float*)alloc((size_t)GG * 128 * 4);
    float* sums_tt = (float*)alloc((size_t)GG * 128 * 4);
    float* S_at    = (float*)alloc(128 * 4);
    float* S_tt    = (float*)alloc(128 * 4);
    float* cnt     = (float*)alloc(GG * 4);
    size_t zbytes = (size_t)((ws + off) - zero0);
    float* attnw   = (float*)alloc(2 * 4);

    hipMemsetAsync(zero0, 0, zbytes, stream);

    // projections + attention-logit dots
    proj_kernel<<<NTX / 16, 256, 0, stream>>>(x_tx, W_tx, b_tx, h_tx,
        a_dst_at, al_dat, a_src_tt, al_stt, a_dst_tt, al_dtt);
    proj_kernel<<<NADDR / 16, 256, 0, stream>>>(x_ad, W_ad, b_ad, h_ad,
        a_src_at, al_sat, nullptr, nullptr, nullptr, nullptr);

    // edge softmax numerators + denominators
    int eb = (NE * 4 + 255) / 256;
    edge_exp_kernel<<<eb, 256, 0, stream>>>(ei_at, al_sat, al_dat, ex_at, den_at);
    edge_exp_kernel<<<eb, 256, 0, stream>>>(ei_tt, al_stt, al_dtt, ex_tt, den_tt);

    // weighted aggregation
    int ab = NE * 32 / 256;
    agg_kernel<<<ab, 256, 0, stream>>>(ei_at, ex_at, den_at, h_ad, out_at);
    agg_kernel<<<ab, 256, 0, stream>>>(ei_tt, ex_tt, den_tt, h_tx, out_tt);

    // semantic attention column sums + graph pooling
    int sb = (NTX + 31) / 32;
    semantic_kernel<<<sb, 256, 0, stream>>>(out_at, Wk, bk, batch, S_at, sums_at, cnt, 1);
    semantic_kernel<<<sb, 256, 0, stream>>>(out_tt, Wk, bk, batch, S_tt, sums_tt, cnt, 0);

    attn_kernel<<<1, 128, 0, stream>>>(S_at, S_tt, q, attnw);
    final_kernel<<<GG, 128, 0, stream>>>(sums_at, sums_tt, cnt, attnw, Wl, bl, out);
}

// Round 2
// 919.192 us; speedup vs baseline: 2.4410x; 2.4410x over previous
//
#include <hip/hip_runtime.h>

#define NTX   50000
#define NADDR 50000
#define NE    500000
#define GG    512
#define NEG   0.2f

__device__ __forceinline__ float lrelu(float x) { return x > 0.f ? x : NEG * x; }

// ---------------------------------------------------------------------------
// K1: h = x @ W + b  (N x 128 @ 128 x 128), fused attention-logit dots
//     al_k[n,h] = sum_d h[n, h*32+d] * a_k[h*32+d]
// block = 256 threads (2 x 128 channels), 16 rows per block, W staged in LDS.
// ---------------------------------------------------------------------------
__global__ __launch_bounds__(256) void proj_kernel(
    const float* __restrict__ x, const float* __restrict__ W, const float* __restrict__ b,
    float* __restrict__ h,
    const float* __restrict__ a0, float* __restrict__ al0,
    const float* __restrict__ a1, float* __restrict__ al1,
    const float* __restrict__ a2, float* __restrict__ al2)
{
    __shared__ float Ws[128 * 128];
    __shared__ float xs[16][128];
    const int t = threadIdx.x;
    for (int i = t; i < 128 * 128; i += 256) Ws[i] = W[i];
    const int row0 = blockIdx.x * 16;
    for (int i = t; i < 16 * 128; i += 256) {
        int r = i >> 7, c = i & 127;
        xs[r][c] = x[(size_t)(row0 + r) * 128 + c];
    }
    __syncthreads();

    const int r = t >> 7;   // 0..1
    const int c = t & 127;
    float acc[8];
    const float bc = b[c];
#pragma unroll
    for (int i = 0; i < 8; i++) acc[i] = bc;

    for (int j = 0; j < 128; j++) {
        float w = Ws[j * 128 + c];
#pragma unroll
        for (int i = 0; i < 8; i++)
            acc[i] += xs[r + 2 * i][j] * w;
    }

#pragma unroll
    for (int i = 0; i < 8; i++) {
        int row = row0 + r + 2 * i;
        h[(size_t)row * 128 + c] = acc[i];
    }

    const int head = c >> 5;
    const bool wlead = (c & 31) == 0;

    if (a0) {
        float av = a0[c];
#pragma unroll
        for (int i = 0; i < 8; i++) {
            float p = acc[i] * av;
            for (int off = 16; off >= 1; off >>= 1) p += __shfl_xor(p, off);
            if (wlead) al0[(size_t)(row0 + r + 2 * i) * 4 + head] = p;
        }
    }
    if (a1) {
        float av = a1[c];
#pragma unroll
        for (int i = 0; i < 8; i++) {
            float p = acc[i] * av;
            for (int off = 16; off >= 1; off >>= 1) p += __shfl_xor(p, off);
            if (wlead) al1[(size_t)(row0 + r + 2 * i) * 4 + head] = p;
        }
    }
    if (a2) {
        float av = a2[c];
#pragma unroll
        for (int i = 0; i < 8; i++) {
            float p = acc[i] * av;
            for (int off = 16; off >= 1; off >>= 1) p += __shfl_xor(p, off);
            if (wlead) al2[(size_t)(row0 + r + 2 * i) * 4 + head] = p;
        }
    }
}

// ---------------------------------------------------------------------------
// CSR build: degree count -> exclusive scan -> slot fill
// ---------------------------------------------------------------------------
__global__ __launch_bounds__(256) void deg_kernel(const int* __restrict__ ei,
                                                  int* __restrict__ deg)
{
    int e = blockIdx.x * 256 + threadIdx.x;
    if (e >= NE) return;
    atomicAdd(&deg[ei[NE + e]], 1);
}

__global__ __launch_bounds__(256) void scan_kernel(const int* __restrict__ deg,
                                                   int* __restrict__ row_start)
{
    __shared__ int part[256];
    const int t = threadIdx.x;
    const int per = (NTX + 255) / 256;  // 196
    const int base = t * per;
    int s = 0;
    for (int i = 0; i < per; i++) {
        int idx = base + i;
        if (idx < NTX) s += deg[idx];
    }
    part[t] = s;
    __syncthreads();
    for (int off = 1; off < 256; off <<= 1) {
        int v = (t >= off) ? part[t - off] : 0;
        __syncthreads();
        part[t] += v;
        __syncthreads();
    }
    int run = (t == 0) ? 0 : part[t - 1];
    for (int i = 0; i < per; i++) {
        int idx = base + i;
        if (idx < NTX) { row_start[idx] = run; run += deg[idx]; }
    }
}

__global__ __launch_bounds__(256) void fill_kernel(const int* __restrict__ ei,
                                                   const int* __restrict__ row_start,
                                                   int* __restrict__ cursor,
                                                   int* __restrict__ csr_src)
{
    int e = blockIdx.x * 256 + threadIdx.x;
    if (e >= NE) return;
    int d = ei[NE + e];
    int pos = row_start[d] + atomicAdd(&cursor[d], 1);
    csr_src[pos] = ei[e];
}

// ---------------------------------------------------------------------------
// Gather GAT: one block (128 thr = 128 channels) per dst node.
// out[d,c] = relu( (sum_e ex_e * h[src_e,c]) / (sum_e ex_e + 1e-16) )
// ex_e = exp(leakyrelu(al_s[src_e,head] + al_d[d,head]))  -- per-dst softmax
// normalization hoisted out of the edge loop (exact algebra, no atomics).
// ---------------------------------------------------------------------------
__global__ __launch_bounds__(128) void gat_gather_kernel(
    const int* __restrict__ row_start, const int* __restrict__ deg,
    const int* __restrict__ csr_src,
    const float* __restrict__ al_s, const float* __restrict__ al_d,
    const float* __restrict__ h_src, float* __restrict__ out)
{
    const int d = blockIdx.x;
    const int c = threadIdx.x;
    const int head = c >> 5;
    const float ald = al_d[d * 4 + head];
    const int beg = row_start[d];
    const int n = deg[d];
    float acc = 0.f, den = 0.f;
    for (int i = 0; i < n; i++) {
        int s = csr_src[beg + i];
        float ex = expf(lrelu(al_s[s * 4 + head] + ald));
        den += ex;
        acc += ex * h_src[(size_t)s * 128 + c];
    }
    float v = acc / (den + 1e-16f);
    out[(size_t)d * 128 + c] = v > 0.f ? v : 0.f;
}

// ---------------------------------------------------------------------------
// K5: per metapath k (input already relu'd):
//     S_k[c] += tanh(row @ Wk + bk)[c]; sums_k[batch[n], c] += out_k[n,c];
//     cnt[g] += 1 (k==0 only).
// ---------------------------------------------------------------------------
__global__ __launch_bounds__(256) void semantic_kernel(
    const float* __restrict__ outk, const float* __restrict__ Wk, const float* __restrict__ bkv,
    const int* __restrict__ batch, float* __restrict__ S, float* __restrict__ sums,
    float* __restrict__ cnt, int do_cnt)
{
    __shared__ float Ws[128 * 128];
    __shared__ float row[2][128];
    const int t = threadIdx.x;
    const int sub = t >> 7, c = t & 127;
    for (int i = t; i < 128 * 128; i += 256) Ws[i] = Wk[i];
    const int n0 = blockIdx.x * 32;
    float accS = 0.f;
    const float bkc = bkv[c];

    for (int i = 0; i < 16; i++) {
        int n = n0 + 2 * i + sub;
        bool ok = n < NTX;
        float v = 0.f;
        if (ok) {
            v = outk[(size_t)n * 128 + c];
            int g = batch[n];
            atomicAdd(&sums[(size_t)g * 128 + c], v);
            if (do_cnt && c == 0) atomicAdd(cnt + g, 1.0f);
        }
        __syncthreads();            // prior iteration's reads of row[] done
        row[sub][c] = v;
        __syncthreads();            // row staged (also covers Ws staging, i==0)
        if (ok) {
            float y = bkc;
            for (int j = 0; j < 128; j++) y += row[sub][j] * Ws[j * 128 + c];
            accS += tanhf(y);
        }
    }
    atomicAdd(&S[c], accS);
}

// ---------------------------------------------------------------------------
// attn: score_k = (q . S_k) / NTX; attn = softmax over k=2
// ---------------------------------------------------------------------------
__global__ __launch_bounds__(128) void attn_kernel(
    const float* __restrict__ S0, const float* __restrict__ S1,
    const float* __restrict__ q, float* __restrict__ attn)
{
    __shared__ float r0[128], r1[128];
    int c = threadIdx.x;
    r0[c] = q[c] * S0[c];
    r1[c] = q[c] * S1[c];
    __syncthreads();
    for (int s = 64; s > 0; s >>= 1) {
        if (c < s) { r0[c] += r0[c + s]; r1[c] += r1[c + s]; }
        __syncthreads();
    }
    if (c == 0) {
        float s0 = r0[0] / (float)NTX, s1 = r1[0] / (float)NTX;
        float m = fmaxf(s0, s1);
        float e0 = expf(s0 - m), e1 = expf(s1 - m);
        float inv = 1.f / (e0 + e1);
        attn[0] = e0 * inv;
        attn[1] = e1 * inv;
    }
}

// ---------------------------------------------------------------------------
// final: pooled[g,c] = (attn0*sums_at + attn1*sums_tt)/max(cnt,1); out = pooled@Wl + bl
// ---------------------------------------------------------------------------
__global__ __launch_bounds__(128) void final_kernel(
    const float* __restrict__ sums0, const float* __restrict__ sums1,
    const float* __restrict__ cnt, const float* __restrict__ attn,
    const float* __restrict__ Wl, const float* __restrict__ bl,
    float* __restrict__ out)
{
    __shared__ float r0[128], r1[128];
    int g = blockIdx.x, c = threadIdx.x;
    float ct = fmaxf(cnt[g], 1.0f);
    float pooled = (attn[0] * sums0[(size_t)g * 128 + c] +
                    attn[1] * sums1[(size_t)g * 128 + c]) / ct;
    r0[c] = pooled * Wl[c * 2 + 0];
    r1[c] = pooled * Wl[c * 2 + 1];
    __syncthreads();
    for (int s = 64; s > 0; s >>= 1) {
        if (c < s) { r0[c] += r0[c + s]; r1[c] += r1[c + s]; }
        __syncthreads();
    }
    if (c == 0) {
        out[g * 2 + 0] = r0[0] + bl[0];
        out[g * 2 + 1] = r1[0] + bl[1];
    }
}

// ---------------------------------------------------------------------------
extern "C" void kernel_launch(void* const* d_in, const int* in_sizes, int n_in,
                              void* d_out, int out_size, void* d_ws, size_t ws_size,
                              hipStream_t stream)
{
    const float* x_tx     = (const float*)d_in[0];
    const float* x_ad     = (const float*)d_in[1];
    // d_in[2] = ei_ta (dead: out_ta never consumed)
    const int*   ei_at    = (const int*)d_in[3];
    const int*   ei_tt    = (const int*)d_in[4];
    const int*   batch    = (const int*)d_in[5];
    const float* W_tx     = (const float*)d_in[6];
    const float* b_tx     = (const float*)d_in[7];
    const float* W_ad     = (const float*)d_in[8];
    const float* b_ad     = (const float*)d_in[9];
    // d_in[10], d_in[11] = a_src_ta, a_dst_ta (dead)
    const float* a_src_at = (const float*)d_in[12];
    const float* a_dst_at = (const float*)d_in[13];
    const float* a_src_tt = (const float*)d_in[14];
    const float* a_dst_tt = (const float*)d_in[15];
    const float* Wk       = (const float*)d_in[16];
    const float* bk       = (const float*)d_in[17];
    const float* q        = (const float*)d_in[18];
    const float* Wl       = (const float*)d_in[19];
    const float* bl       = (const float*)d_in[20];
    float* out = (float*)d_out;

    char* ws = (char*)d_ws;
    size_t off = 0;
    auto alloc = [&](size_t bytes) -> void* {
        void* p = ws + off;
        off += (bytes + 255) & ~(size_t)255;
        return p;
    };
    float* h_tx    = (float*)alloc((size_t)NTX * 128 * 4);
    float* h_ad    = (float*)alloc((size_t)NADDR * 128 * 4);
    float* al_sat  = (float*)alloc((size_t)NADDR * 4 * 4);  // a_src_at . h_ad
    float* al_dat  = (float*)alloc((size_t)NTX * 4 * 4);    // a_dst_at . h_tx
    float* al_stt  = (float*)alloc((size_t)NTX * 4 * 4);
    float* al_dtt  = (float*)alloc((size_t)NTX * 4 * 4);
    float* out_at  = (float*)alloc((size_t)NTX * 128 * 4);  // fully written by gather
    float* out_tt  = (float*)alloc((size_t)NTX * 128 * 4);
    int* csr_at    = (int*)alloc((size_t)NE * 4);
    int* csr_tt    = (int*)alloc((size_t)NE * 4);
    int* row_at    = (int*)alloc((size_t)NTX * 4);
    int* row_tt    = (int*)alloc((size_t)NTX * 4);
    // ---- zeroed region (accumulators / counters) ----
    char* zero0 = ws + off;
    int* deg_at    = (int*)alloc((size_t)NTX * 4);
    int* deg_tt    = (int*)alloc((size_t)NTX * 4);
    int* cur_at    = (int*)alloc((size_t)NTX * 4);
    int* cur_tt    = (int*)alloc((size_t)NTX * 4);
    float* sums_at = (float*)alloc((size_t)GG * 128 * 4);
    float* sums_tt = (float*)alloc((size_t)GG * 128 * 4);
    float* S_at    = (float*)alloc(128 * 4);
    float* S_tt    = (float*)alloc(128 * 4);
    float* cnt     = (float*)alloc(GG * 4);
    size_t zbytes = (size_t)((ws + off) - zero0);
    float* attnw   = (float*)alloc(2 * 4);

    hipMemsetAsync(zero0, 0, zbytes, stream);

    // projections + attention-logit dots
    proj_kernel<<<NTX / 16, 256, 0, stream>>>(x_tx, W_tx, b_tx, h_tx,
        a_dst_at, al_dat, a_src_tt, al_stt, a_dst_tt, al_dtt);
    proj_kernel<<<NADDR / 16, 256, 0, stream>>>(x_ad, W_ad, b_ad, h_ad,
        a_src_at, al_sat, nullptr, nullptr, nullptr, nullptr);

    // CSR build (dst-major) for both edge types
    int eb = (NE + 255) / 256;
    deg_kernel<<<eb, 256, 0, stream>>>(ei_at, deg_at);
    deg_kernel<<<eb, 256, 0, stream>>>(ei_tt, deg_tt);
    scan_kernel<<<1, 256, 0, stream>>>(deg_at, row_at);
    scan_kernel<<<1, 256, 0, stream>>>(deg_tt, row_tt);
    fill_kernel<<<eb, 256, 0, stream>>>(ei_at, row_at, cur_at, csr_at);
    fill_kernel<<<eb, 256, 0, stream>>>(ei_tt, row_tt, cur_tt, csr_tt);

    // gather-style GAT (no atomics, fused softmax-normalize + relu)
    gat_gather_kernel<<<NTX, 128, 0, stream>>>(row_at, deg_at, csr_at,
                                               al_sat, al_dat, h_ad, out_at);
    gat_gather_kernel<<<NTX, 128, 0, stream>>>(row_tt, deg_tt, csr_tt,
                                               al_stt, al_dtt, h_tx, out_tt);

    // semantic attention column sums + graph pooling
    int sb = (NTX + 31) / 32;
    semantic_kernel<<<sb, 256, 0, stream>>>(out_at, Wk, bk, batch, S_at, sums_at, cnt, 1);
    semantic_kernel<<<sb, 256, 0, stream>>>(out_tt, Wk, bk, batch, S_tt, sums_tt, cnt, 0);

    attn_kernel<<<1, 128, 0, stream>>>(S_at, S_tt, q, attnw);
    final_kernel<<<GG, 128, 0, stream>>>(sums_at, sums_tt, cnt, attnw, Wl, bl, out);
}

// Round 3
// 625.444 us; speedup vs baseline: 3.5874x; 1.4697x over previous
//
#include <hip/hip_runtime.h>

#define NTX   50000
#define NADDR 50000
#define NE    500000
#define GG    512
#define NEG   0.2f
#define PB    3125   // 50000/16 rows-per-block tiles

__device__ __forceinline__ float lrelu(float x) { return x > 0.f ? x : NEG * x; }

// ---------------------------------------------------------------------------
// proj2: both node-type projections in one dispatch.
// h = x @ W + b  (N x 128 @ 128 x 128), fused attention-logit dots.
// block = 256 threads (2 x 128 channels), 16 rows/block, W staged in LDS.
// blocks [0,PB) = tx, [PB,2PB) = addr.
// ---------------------------------------------------------------------------
__global__ __launch_bounds__(256) void proj2_kernel(
    const float* __restrict__ x_tx, const float* __restrict__ W_tx,
    const float* __restrict__ b_tx, float* __restrict__ h_tx,
    const float* __restrict__ x_ad, const float* __restrict__ W_ad,
    const float* __restrict__ b_ad, float* __restrict__ h_ad,
    const float* __restrict__ a_dat, float* __restrict__ al_dat,
    const float* __restrict__ a_stt, float* __restrict__ al_stt,
    const float* __restrict__ a_dtt, float* __restrict__ al_dtt,
    const float* __restrict__ a_sat, float* __restrict__ al_sat)
{
    __shared__ float Ws[128 * 128];
    __shared__ float xs[16][128];
    const bool is_tx = blockIdx.x < PB;
    const float* x = is_tx ? x_tx : x_ad;
    const float* W = is_tx ? W_tx : W_ad;
    const float* b = is_tx ? b_tx : b_ad;
    float* h       = is_tx ? h_tx : h_ad;
    const int row0 = (is_tx ? blockIdx.x : blockIdx.x - PB) * 16;

    const int t = threadIdx.x;
    {
        const float4* W4 = (const float4*)W;
        float4* Ws4 = (float4*)Ws;
        for (int i = t; i < 128 * 32; i += 256) Ws4[i] = W4[i];
        const float4* x4 = (const float4*)(x + (size_t)row0 * 128);
        float4* xs4 = (float4*)&xs[0][0];
        for (int i = t; i < 16 * 32; i += 256) xs4[i] = x4[i];
    }
    __syncthreads();

    const int r = t >> 7;   // 0..1
    const int c = t & 127;
    float acc[8];
    const float bc = b[c];
#pragma unroll
    for (int i = 0; i < 8; i++) acc[i] = bc;

    for (int j = 0; j < 128; j++) {
        float w = Ws[j * 128 + c];
#pragma unroll
        for (int i = 0; i < 8; i++)
            acc[i] = fmaf(xs[r + 2 * i][j], w, acc[i]);
    }

#pragma unroll
    for (int i = 0; i < 8; i++)
        h[(size_t)(row0 + r + 2 * i) * 128 + c] = acc[i];

    const int head = c >> 5;
    const bool wlead = (c & 31) == 0;
    auto do_dot = [&](const float* __restrict__ a, float* __restrict__ al) {
        float av = a[c];
#pragma unroll
        for (int i = 0; i < 8; i++) {
            float p = acc[i] * av;
            for (int off = 16; off >= 1; off >>= 1) p += __shfl_xor(p, off);
            if (wlead) al[(size_t)(row0 + r + 2 * i) * 4 + head] = p;
        }
    };
    if (is_tx) {
        do_dot(a_dat, al_dat);
        do_dot(a_stt, al_stt);
        do_dot(a_dtt, al_dtt);
    } else {
        do_dot(a_sat, al_sat);
    }
}

// ---------------------------------------------------------------------------
// CSR build (both edge types per dispatch): degree -> scan -> fill
// ---------------------------------------------------------------------------
__global__ __launch_bounds__(256) void deg2_kernel(
    const int* __restrict__ ei0, const int* __restrict__ ei1,
    int* __restrict__ deg0, int* __restrict__ deg1)
{
    int idx = blockIdx.x * 256 + threadIdx.x;
    if (idx < NE) atomicAdd(&deg0[ei0[NE + idx]], 1);
    else if (idx < 2 * NE) atomicAdd(&deg1[ei1[NE + (idx - NE)]], 1);
}

__global__ __launch_bounds__(256) void scan2_kernel(
    const int* __restrict__ deg0, int* __restrict__ row0,
    const int* __restrict__ deg1, int* __restrict__ row1)
{
    const int* deg = blockIdx.x == 0 ? deg0 : deg1;
    int* row_start  = blockIdx.x == 0 ? row0 : row1;
    __shared__ int part[256];
    const int t = threadIdx.x;
    const int per = (NTX + 255) / 256;
    const int base = t * per;
    int s = 0;
    for (int i = 0; i < per; i++) {
        int idx = base + i;
        if (idx < NTX) s += deg[idx];
    }
    part[t] = s;
    __syncthreads();
    for (int off = 1; off < 256; off <<= 1) {
        int v = (t >= off) ? part[t - off] : 0;
        __syncthreads();
        part[t] += v;
        __syncthreads();
    }
    int run = (t == 0) ? 0 : part[t - 1];
    for (int i = 0; i < per; i++) {
        int idx = base + i;
        if (idx < NTX) { row_start[idx] = run; run += deg[idx]; }
    }
}

__global__ __launch_bounds__(256) void fill2_kernel(
    const int* __restrict__ ei0, const int* __restrict__ row0,
    int* __restrict__ cur0, int* __restrict__ csr0,
    const int* __restrict__ ei1, const int* __restrict__ row1,
    int* __restrict__ cur1, int* __restrict__ csr1)
{
    int idx = blockIdx.x * 256 + threadIdx.x;
    if (idx < NE) {
        int d = ei0[NE + idx];
        int pos = row0[d] + atomicAdd(&cur0[d], 1);
        csr0[pos] = ei0[idx];
    } else if (idx < 2 * NE) {
        int e = idx - NE;
        int d = ei1[NE + e];
        int pos = row1[d] + atomicAdd(&cur1[d], 1);
        csr1[pos] = ei1[e];
    }
}

// ---------------------------------------------------------------------------
// Gather GAT (both edge types via blockIdx.y). One block (128 thr) per dst.
// out[d,c] = relu( (sum_e ex_e * h[src_e,c]) / (sum_e ex_e + 1e-16) )
// 2-edge unroll for memory-level parallelism.
// ---------------------------------------------------------------------------
__global__ __launch_bounds__(128) void gat_gather2_kernel(
    const int* __restrict__ row_at, const int* __restrict__ deg_at,
    const int* __restrict__ csr_at, const float* __restrict__ als_at,
    const float* __restrict__ ald_at, const float* __restrict__ h_at,
    float* __restrict__ out_at,
    const int* __restrict__ row_tt, const int* __restrict__ deg_tt,
    const int* __restrict__ csr_tt, const float* __restrict__ als_tt,
    const float* __restrict__ ald_tt, const float* __restrict__ h_tt,
    float* __restrict__ out_tt)
{
    const bool at = (blockIdx.y == 0);
    const int* rs = at ? row_at : row_tt;
    const int* dg = at ? deg_at : deg_tt;
    const int* cs = at ? csr_at : csr_tt;
    const float* als = at ? als_at : als_tt;
    const float* ald = at ? ald_at : ald_tt;
    const float* hsrc = at ? h_at : h_tt;
    float* out = at ? out_at : out_tt;

    const int d = blockIdx.x;
    const int c = threadIdx.x;
    const int head = c >> 5;
    const float aldv = ald[d * 4 + head];
    const int beg = rs[d];
    const int n = dg[d];
    float acc = 0.f, den = 0.f;
    int i = 0;
    for (; i + 2 <= n; i += 2) {
        int s0 = cs[beg + i], s1 = cs[beg + i + 1];
        float l0 = als[s0 * 4 + head], l1 = als[s1 * 4 + head];
        float h0 = hsrc[(size_t)s0 * 128 + c], h1 = hsrc[(size_t)s1 * 128 + c];
        float e0 = expf(lrelu(l0 + aldv));
        float e1 = expf(lrelu(l1 + aldv));
        den += e0 + e1;
        acc = fmaf(e0, h0, fmaf(e1, h1, acc));
    }
    if (i < n) {
        int s0 = cs[beg + i];
        float e0 = expf(lrelu(als[s0 * 4 + head] + aldv));
        den += e0;
        acc = fmaf(e0, hsrc[(size_t)s0 * 128 + c], acc);
    }
    float v = acc / (den + 1e-16f);
    out[(size_t)d * 128 + c] = v > 0.f ? v : 0.f;
}

// ---------------------------------------------------------------------------
// tanh GEMM (both metapaths via blockIdx.y):
// part[k][bx][c] = sum over 16-row tile of tanh((out_k @ Wk + bk))[.,c]
// proj-style register tiling; per-block partials, NO atomics.
// ---------------------------------------------------------------------------
__global__ __launch_bounds__(256) void tanh_gemm_kernel(
    const float* __restrict__ out_at, const float* __restrict__ out_tt,
    const float* __restrict__ Wk, const float* __restrict__ bk,
    float* __restrict__ part)    // [2][PB][128]
{
    const float* src = (blockIdx.y == 0) ? out_at : out_tt;
    __shared__ float Ws[128 * 128];
    __shared__ float xs[16][128];
    const int t = threadIdx.x;
    {
        const float4* W4 = (const float4*)Wk;
        float4* Ws4 = (float4*)Ws;
        for (int i = t; i < 128 * 32; i += 256) Ws4[i] = W4[i];
        const float4* x4 = (const float4*)(src + (size_t)blockIdx.x * 16 * 128);
        float4* xs4 = (float4*)&xs[0][0];
        for (int i = t; i < 16 * 32; i += 256) xs4[i] = x4[i];
    }
    __syncthreads();

    const int r = t >> 7;
    const int c = t & 127;
    float acc[8];
    const float bc = bk[c];
#pragma unroll
    for (int i = 0; i < 8; i++) acc[i] = bc;

    for (int j = 0; j < 128; j++) {
        float w = Ws[j * 128 + c];
#pragma unroll
        for (int i = 0; i < 8; i++)
            acc[i] = fmaf(xs[r + 2 * i][j], w, acc[i]);
    }
    float s = 0.f;
#pragma unroll
    for (int i = 0; i < 8; i++) s += tanhf(acc[i]);

    __syncthreads();
    xs[r][c] = s;
    __syncthreads();
    if (r == 0)
        part[((size_t)blockIdx.y * PB + blockIdx.x) * 128 + c] = s + xs[1][c];
}

// ---------------------------------------------------------------------------
// reduce partials -> S_k[c] (64 chunks x 2 metapaths, few atomics)
// ---------------------------------------------------------------------------
__global__ __launch_bounds__(128) void reduceS_kernel(
    const float* __restrict__ part, float* __restrict__ S_at, float* __restrict__ S_tt)
{
    const int k = blockIdx.y;
    const int c = threadIdx.x;
    float* S = (k == 0) ? S_at : S_tt;
    const int b0 = blockIdx.x * 49;
    const int b1 = min(b0 + 49, PB);
    float s = 0.f;
    for (int b = b0; b < b1; b++)
        s += part[((size_t)k * PB + b) * 128 + c];
    atomicAdd(&S[c], s);
}

// ---------------------------------------------------------------------------
// attn: score_k = (q . S_k) / NTX; attn = softmax over k=2
// ---------------------------------------------------------------------------
__global__ __launch_bounds__(128) void attn_kernel(
    const float* __restrict__ S0, const float* __restrict__ S1,
    const float* __restrict__ q, float* __restrict__ attn)
{
    __shared__ float r0[128], r1[128];
    int c = threadIdx.x;
    r0[c] = q[c] * S0[c];
    r1[c] = q[c] * S1[c];
    __syncthreads();
    for (int s = 64; s > 0; s >>= 1) {
        if (c < s) { r0[c] += r0[c + s]; r1[c] += r1[c + s]; }
        __syncthreads();
    }
    if (c == 0) {
        float s0 = r0[0] / (float)NTX, s1 = r1[0] / (float)NTX;
        float m = fmaxf(s0, s1);
        float e0 = expf(s0 - m), e1 = expf(s1 - m);
        float inv = 1.f / (e0 + e1);
        attn[0] = e0 * inv;
        attn[1] = e1 * inv;
    }
}

// ---------------------------------------------------------------------------
// final_pool: batch is SORTED -> group g is a contiguous run [lo,hi).
// pooled[g,c] = (a0*sum_at + a1*sum_tt)/max(hi-lo,1); out = pooled @ Wl + bl.
// No atomics anywhere.
// ---------------------------------------------------------------------------
__device__ __forceinline__ int lower_bound_g(const int* __restrict__ batch, int val)
{
    int lo = 0, hi = NTX;
    while (lo < hi) {
        int mid = (lo + hi) >> 1;
        if (batch[mid] < val) lo = mid + 1; else hi = mid;
    }
    return lo;
}

__global__ __launch_bounds__(128) void final_pool_kernel(
    const float* __restrict__ out_at, const float* __restrict__ out_tt,
    const int* __restrict__ batch, const float* __restrict__ attn,
    const float* __restrict__ Wl, const float* __restrict__ bl,
    float* __restrict__ out)
{
    __shared__ float r0[128], r1[128];
    const int g = blockIdx.x, c = threadIdx.x;
    const int lo = lower_bound_g(batch, g);
    const int hi = lower_bound_g(batch, g + 1);
    float s0 = 0.f, s1 = 0.f;
    for (int n = lo; n < hi; n++) {
        s0 += out_at[(size_t)n * 128 + c];
        s1 += out_tt[(size_t)n * 128 + c];
    }
    float pooled = (attn[0] * s0 + attn[1] * s1) / fmaxf((float)(hi - lo), 1.f);
    r0[c] = pooled * Wl[c * 2 + 0];
    r1[c] = pooled * Wl[c * 2 + 1];
    __syncthreads();
    for (int s = 64; s > 0; s >>= 1) {
        if (c < s) { r0[c] += r0[c + s]; r1[c] += r1[c + s]; }
        __syncthreads();
    }
    if (c == 0) {
        out[g * 2 + 0] = r0[0] + bl[0];
        out[g * 2 + 1] = r1[0] + bl[1];
    }
}

// ---------------------------------------------------------------------------
extern "C" void kernel_launch(void* const* d_in, const int* in_sizes, int n_in,
                              void* d_out, int out_size, void* d_ws, size_t ws_size,
                              hipStream_t stream)
{
    const float* x_tx     = (const float*)d_in[0];
    const float* x_ad     = (const float*)d_in[1];
    // d_in[2] = ei_ta (dead: out_ta never consumed)
    const int*   ei_at    = (const int*)d_in[3];
    const int*   ei_tt    = (const int*)d_in[4];
    const int*   batch    = (const int*)d_in[5];
    const float* W_tx     = (const float*)d_in[6];
    const float* b_tx     = (const float*)d_in[7];
    const float* W_ad     = (const float*)d_in[8];
    const float* b_ad     = (const float*)d_in[9];
    // d_in[10], d_in[11] = a_src_ta, a_dst_ta (dead)
    const float* a_src_at = (const float*)d_in[12];
    const float* a_dst_at = (const float*)d_in[13];
    const float* a_src_tt = (const float*)d_in[14];
    const float* a_dst_tt = (const float*)d_in[15];
    const float* Wk       = (const float*)d_in[16];
    const float* bk       = (const float*)d_in[17];
    const float* q        = (const float*)d_in[18];
    const float* Wl       = (const float*)d_in[19];
    const float* bl       = (const float*)d_in[20];
    float* out = (float*)d_out;

    char* ws = (char*)d_ws;
    size_t off = 0;
    auto alloc = [&](size_t bytes) -> void* {
        void* p = ws + off;
        off += (bytes + 255) & ~(size_t)255;
        return p;
    };
    float* h_tx    = (float*)alloc((size_t)NTX * 128 * 4);
    float* h_ad    = (float*)alloc((size_t)NADDR * 128 * 4);
    float* al_sat  = (float*)alloc((size_t)NADDR * 4 * 4);
    float* al_dat  = (float*)alloc((size_t)NTX * 4 * 4);
    float* al_stt  = (float*)alloc((size_t)NTX * 4 * 4);
    float* al_dtt  = (float*)alloc((size_t)NTX * 4 * 4);
    float* out_at  = (float*)alloc((size_t)NTX * 128 * 4);  // fully written by gather
    float* out_tt  = (float*)alloc((size_t)NTX * 128 * 4);
    int* csr_at    = (int*)alloc((size_t)NE * 4);
    int* csr_tt    = (int*)alloc((size_t)NE * 4);
    int* row_at    = (int*)alloc((size_t)NTX * 4);
    int* row_tt    = (int*)alloc((size_t)NTX * 4);
    float* part    = (float*)alloc((size_t)2 * PB * 128 * 4);
    // ---- zeroed region (counters / S accumulators) ----
    char* zero0 = ws + off;
    int* deg_at    = (int*)alloc((size_t)NTX * 4);
    int* deg_tt    = (int*)alloc((size_t)NTX * 4);
    int* cur_at    = (int*)alloc((size_t)NTX * 4);
    int* cur_tt    = (int*)alloc((size_t)NTX * 4);
    float* S_at    = (float*)alloc(128 * 4);
    float* S_tt    = (float*)alloc(128 * 4);
    size_t zbytes = (size_t)((ws + off) - zero0);
    float* attnw   = (float*)alloc(2 * 4);

    hipMemsetAsync(zero0, 0, zbytes, stream);

    // projections + attention-logit dots (both node types, one dispatch)
    proj2_kernel<<<2 * PB, 256, 0, stream>>>(
        x_tx, W_tx, b_tx, h_tx, x_ad, W_ad, b_ad, h_ad,
        a_dst_at, al_dat, a_src_tt, al_stt, a_dst_tt, al_dtt,
        a_src_at, al_sat);

    // CSR build (dst-major), both edge types per dispatch
    int eb2 = (2 * NE + 255) / 256;
    deg2_kernel<<<eb2, 256, 0, stream>>>(ei_at, ei_tt, deg_at, deg_tt);
    scan2_kernel<<<2, 256, 0, stream>>>(deg_at, row_at, deg_tt, row_tt);
    fill2_kernel<<<eb2, 256, 0, stream>>>(ei_at, row_at, cur_at, csr_at,
                                          ei_tt, row_tt, cur_tt, csr_tt);

    // gather-style GAT (no atomics, fused softmax-normalize + relu)
    dim3 ggrid(NTX, 2);
    gat_gather2_kernel<<<ggrid, 128, 0, stream>>>(
        row_at, deg_at, csr_at, al_sat, al_dat, h_ad, out_at,
        row_tt, deg_tt, csr_tt, al_stt, al_dtt, h_tx, out_tt);

    // semantic attention: tanh GEMM partials -> reduce -> softmax over 2
    dim3 tgrid(PB, 2);
    tanh_gemm_kernel<<<tgrid, 256, 0, stream>>>(out_at, out_tt, Wk, bk, part);
    dim3 rgrid(64, 2);
    reduceS_kernel<<<rgrid, 128, 0, stream>>>(part, S_at, S_tt);
    attn_kernel<<<1, 128, 0, stream>>>(S_at, S_tt, q, attnw);

    // fused pooling (sorted batch -> contiguous runs) + final linear
    final_pool_kernel<<<GG, 128, 0, stream>>>(out_at, out_tt, batch, attnw, Wl, bl, out);
}

// Round 4
// 466.221 us; speedup vs baseline: 4.8125x; 1.3415x over previous
//
#include <hip/hip_runtime.h>

#define NTX   50000
#define NADDR 50000
#define NE    500000
#define GG    512
#define NEG   0.2f
#define BM    32
#define PB2   1563   // ceil(50000/32)

__device__ __forceinline__ float lrelu(float x) { return x > 0.f ? x : NEG * x; }

// ---------------------------------------------------------------------------
// proj2: both node-type projections in one dispatch, 4x4 register tiling.
// h = x @ W + b  (N x 128 @ 128 x 128), fused attention-logit dots.
// block = 256 thr = 32 col-groups x 8 row-groups; thread owns 4 rows x 4 cols.
// blocks [0,PB2) = tx, [PB2,2*PB2) = addr. Tail rows guarded.
// ---------------------------------------------------------------------------
__global__ __launch_bounds__(256) void proj2_kernel(
    const float* __restrict__ x_tx, const float* __restrict__ W_tx,
    const float* __restrict__ b_tx, float* __restrict__ h_tx,
    const float* __restrict__ x_ad, const float* __restrict__ W_ad,
    const float* __restrict__ b_ad, float* __restrict__ h_ad,
    const float* __restrict__ a_dat, float* __restrict__ al_dat,
    const float* __restrict__ a_stt, float* __restrict__ al_stt,
    const float* __restrict__ a_dtt, float* __restrict__ al_dtt,
    const float* __restrict__ a_sat, float* __restrict__ al_sat)
{
    __shared__ float Ws[128 * 128];   // 64 KiB
    __shared__ float xs[BM][128];     // 16 KiB
    const bool is_tx = blockIdx.x < PB2;
    const float* x = is_tx ? x_tx : x_ad;
    const float* W = is_tx ? W_tx : W_ad;
    const float* b = is_tx ? b_tx : b_ad;
    float* h       = is_tx ? h_tx : h_ad;
    const int row0 = (is_tx ? blockIdx.x : blockIdx.x - PB2) * BM;

    const int t = threadIdx.x;
    {
        const float4* W4 = (const float4*)W;
        float4* Ws4 = (float4*)Ws;
#pragma unroll 4
        for (int i = t; i < 128 * 32; i += 256) Ws4[i] = W4[i];
        const float4* x4 = (const float4*)x;
        float4* xs4 = (float4*)&xs[0][0];
        for (int i = t; i < BM * 32; i += 256) {
            int rr = i >> 5, q = i & 31;
            int gr = row0 + rr; if (gr >= NTX) gr = NTX - 1;
            xs4[i] = x4[(size_t)gr * 32 + q];
        }
    }
    __syncthreads();

    const int cg = t & 31, rg = t >> 5;
    const int c0 = cg * 4;
    float acc[4][4];
    {
        float4 bv = *(const float4*)(b + c0);
#pragma unroll
        for (int rr = 0; rr < 4; rr++) {
            acc[rr][0] = bv.x; acc[rr][1] = bv.y; acc[rr][2] = bv.z; acc[rr][3] = bv.w;
        }
    }

    for (int j = 0; j < 128; j += 4) {
        float xq[4][4];
#pragma unroll
        for (int rr = 0; rr < 4; rr++) {
            float4 v = *(const float4*)&xs[rg * 4 + rr][j];
            xq[rr][0] = v.x; xq[rr][1] = v.y; xq[rr][2] = v.z; xq[rr][3] = v.w;
        }
#pragma unroll
        for (int jj = 0; jj < 4; jj++) {
            float4 wv = *(const float4*)&Ws[(j + jj) * 128 + c0];
#pragma unroll
            for (int rr = 0; rr < 4; rr++) {
                acc[rr][0] = fmaf(xq[rr][jj], wv.x, acc[rr][0]);
                acc[rr][1] = fmaf(xq[rr][jj], wv.y, acc[rr][1]);
                acc[rr][2] = fmaf(xq[rr][jj], wv.z, acc[rr][2]);
                acc[rr][3] = fmaf(xq[rr][jj], wv.w, acc[rr][3]);
            }
        }
    }

#pragma unroll
    for (int rr = 0; rr < 4; rr++) {
        int row = row0 + rg * 4 + rr;
        if (row < NTX)
            *(float4*)&h[(size_t)row * 128 + c0] =
                make_float4(acc[rr][0], acc[rr][1], acc[rr][2], acc[rr][3]);
    }

    const int head = cg >> 3;
    const bool wlead = (cg & 7) == 0;
    auto do_dot = [&](const float* __restrict__ a, float* __restrict__ al) {
        float4 av = *(const float4*)(a + c0);
#pragma unroll
        for (int rr = 0; rr < 4; rr++) {
            float p = acc[rr][0] * av.x + acc[rr][1] * av.y
                    + acc[rr][2] * av.z + acc[rr][3] * av.w;
            p += __shfl_xor(p, 1); p += __shfl_xor(p, 2); p += __shfl_xor(p, 4);
            int row = row0 + rg * 4 + rr;
            if (wlead && row < NTX) al[(size_t)row * 4 + head] = p;
        }
    };
    if (is_tx) { do_dot(a_dat, al_dat); do_dot(a_stt, al_stt); do_dot(a_dtt, al_dtt); }
    else       { do_dot(a_sat, al_sat); }
}

// ---------------------------------------------------------------------------
// CSR build (both edge types per dispatch): degree -> scan -> fill
// ---------------------------------------------------------------------------
__global__ __launch_bounds__(256) void deg2_kernel(
    const int* __restrict__ ei0, const int* __restrict__ ei1,
    int* __restrict__ deg0, int* __restrict__ deg1)
{
    int idx = blockIdx.x * 256 + threadIdx.x;
    if (idx < NE) atomicAdd(&deg0[ei0[NE + idx]], 1);
    else if (idx < 2 * NE) atomicAdd(&deg1[ei1[NE + (idx - NE)]], 1);
}

__global__ __launch_bounds__(256) void scan2_kernel(
    const int* __restrict__ deg0, int* __restrict__ row0,
    const int* __restrict__ deg1, int* __restrict__ row1)
{
    const int* deg = blockIdx.x == 0 ? deg0 : deg1;
    int* row_start  = blockIdx.x == 0 ? row0 : row1;
    __shared__ int part[256];
    const int t = threadIdx.x;
    const int per = (NTX + 255) / 256;
    const int base = t * per;
    int s = 0;
    for (int i = 0; i < per; i++) {
        int idx = base + i;
        if (idx < NTX) s += deg[idx];
    }
    part[t] = s;
    __syncthreads();
    for (int off = 1; off < 256; off <<= 1) {
        int v = (t >= off) ? part[t - off] : 0;
        __syncthreads();
        part[t] += v;
        __syncthreads();
    }
    int run = (t == 0) ? 0 : part[t - 1];
    for (int i = 0; i < per; i++) {
        int idx = base + i;
        if (idx < NTX) { row_start[idx] = run; run += deg[idx]; }
    }
}

__global__ __launch_bounds__(256) void fill2_kernel(
    const int* __restrict__ ei0, const int* __restrict__ row0,
    int* __restrict__ cur0, int* __restrict__ csr0,
    const int* __restrict__ ei1, const int* __restrict__ row1,
    int* __restrict__ cur1, int* __restrict__ csr1)
{
    int idx = blockIdx.x * 256 + threadIdx.x;
    if (idx < NE) {
        int d = ei0[NE + idx];
        int pos = row0[d] + atomicAdd(&cur0[d], 1);
        csr0[pos] = ei0[idx];
    } else if (idx < 2 * NE) {
        int e = idx - NE;
        int d = ei1[NE + e];
        int pos = row1[d] + atomicAdd(&cur1[d], 1);
        csr1[pos] = ei1[e];
    }
}

// ---------------------------------------------------------------------------
// Gather GAT (both edge types via blockIdx.y). One block (128 thr) per dst.
// out[d,c] = relu( (sum_e ex_e * h[src_e,c]) / (sum_e ex_e + 1e-16) )
// 4-edge unroll for memory-level parallelism.
// ---------------------------------------------------------------------------
__global__ __launch_bounds__(128) void gat_gather2_kernel(
    const int* __restrict__ row_at, const int* __restrict__ deg_at,
    const int* __restrict__ csr_at, const float* __restrict__ als_at,
    const float* __restrict__ ald_at, const float* __restrict__ h_at,
    float* __restrict__ out_at,
    const int* __restrict__ row_tt, const int* __restrict__ deg_tt,
    const int* __restrict__ csr_tt, const float* __restrict__ als_tt,
    const float* __restrict__ ald_tt, const float* __restrict__ h_tt,
    float* __restrict__ out_tt)
{
    const bool at = (blockIdx.y == 0);
    const int* rs = at ? row_at : row_tt;
    const int* dg = at ? deg_at : deg_tt;
    const int* cs = at ? csr_at : csr_tt;
    const float* als = at ? als_at : als_tt;
    const float* ald = at ? ald_at : ald_tt;
    const float* hsrc = at ? h_at : h_tt;
    float* out = at ? out_at : out_tt;

    const int d = blockIdx.x;
    const int c = threadIdx.x;
    const int head = c >> 5;
    const float aldv = ald[d * 4 + head];
    const int beg = rs[d];
    const int n = dg[d];
    float acc = 0.f, den = 0.f;
    int i = 0;
    for (; i + 4 <= n; i += 4) {
        int s0 = cs[beg + i], s1 = cs[beg + i + 1];
        int s2 = cs[beg + i + 2], s3 = cs[beg + i + 3];
        float l0 = als[s0 * 4 + head], l1 = als[s1 * 4 + head];
        float l2 = als[s2 * 4 + head], l3 = als[s3 * 4 + head];
        float h0 = hsrc[(size_t)s0 * 128 + c], h1 = hsrc[(size_t)s1 * 128 + c];
        float h2 = hsrc[(size_t)s2 * 128 + c], h3 = hsrc[(size_t)s3 * 128 + c];
        float e0 = expf(lrelu(l0 + aldv));
        float e1 = expf(lrelu(l1 + aldv));
        float e2 = expf(lrelu(l2 + aldv));
        float e3 = expf(lrelu(l3 + aldv));
        den += (e0 + e1) + (e2 + e3);
        acc = fmaf(e0, h0, fmaf(e1, h1, fmaf(e2, h2, fmaf(e3, h3, acc))));
    }
    for (; i < n; i++) {
        int s0 = cs[beg + i];
        float e0 = expf(lrelu(als[s0 * 4 + head] + aldv));
        den += e0;
        acc = fmaf(e0, hsrc[(size_t)s0 * 128 + c], acc);
    }
    float v = acc / (den + 1e-16f);
    out[(size_t)d * 128 + c] = v > 0.f ? v : 0.f;
}

// ---------------------------------------------------------------------------
// tanh GEMM (both metapaths via blockIdx.y), same 4x4 register tiling:
// part[k][bx][c] = sum over 32-row tile of tanh((out_k @ Wk + bk))[.,c]
// ---------------------------------------------------------------------------
__global__ __launch_bounds__(256) void tanh_gemm_kernel(
    const float* __restrict__ out_at, const float* __restrict__ out_tt,
    const float* __restrict__ Wk, const float* __restrict__ bk,
    float* __restrict__ part)    // [2][PB2][128]
{
    __shared__ float Ws[128 * 128];
    __shared__ float xs[BM][128];
    const float* src = (blockIdx.y == 0) ? out_at : out_tt;
    const int row0 = blockIdx.x * BM;
    const int t = threadIdx.x;
    {
        const float4* W4 = (const float4*)Wk;
        float4* Ws4 = (float4*)Ws;
#pragma unroll 4
        for (int i = t; i < 128 * 32; i += 256) Ws4[i] = W4[i];
        const float4* x4 = (const float4*)src;
        float4* xs4 = (float4*)&xs[0][0];
        for (int i = t; i < BM * 32; i += 256) {
            int rr = i >> 5, q = i & 31;
            int gr = row0 + rr; if (gr >= NTX) gr = NTX - 1;
            xs4[i] = x4[(size_t)gr * 32 + q];
        }
    }
    __syncthreads();

    const int cg = t & 31, rg = t >> 5;
    const int c0 = cg * 4;
    float acc[4][4];
    {
        float4 bv = *(const float4*)(bk + c0);
#pragma unroll
        for (int rr = 0; rr < 4; rr++) {
            acc[rr][0] = bv.x; acc[rr][1] = bv.y; acc[rr][2] = bv.z; acc[rr][3] = bv.w;
        }
    }

    for (int j = 0; j < 128; j += 4) {
        float xq[4][4];
#pragma unroll
        for (int rr = 0; rr < 4; rr++) {
            float4 v = *(const float4*)&xs[rg * 4 + rr][j];
            xq[rr][0] = v.x; xq[rr][1] = v.y; xq[rr][2] = v.z; xq[rr][3] = v.w;
        }
#pragma unroll
        for (int jj = 0; jj < 4; jj++) {
            float4 wv = *(const float4*)&Ws[(j + jj) * 128 + c0];
#pragma unroll
            for (int rr = 0; rr < 4; rr++) {
                acc[rr][0] = fmaf(xq[rr][jj], wv.x, acc[rr][0]);
                acc[rr][1] = fmaf(xq[rr][jj], wv.y, acc[rr][1]);
                acc[rr][2] = fmaf(xq[rr][jj], wv.z, acc[rr][2]);
                acc[rr][3] = fmaf(xq[rr][jj], wv.w, acc[rr][3]);
            }
        }
    }

    float s0 = 0.f, s1 = 0.f, s2 = 0.f, s3 = 0.f;
#pragma unroll
    for (int rr = 0; rr < 4; rr++) {
        int row = row0 + rg * 4 + rr;
        if (row < NTX) {
            s0 += tanhf(acc[rr][0]); s1 += tanhf(acc[rr][1]);
            s2 += tanhf(acc[rr][2]); s3 += tanhf(acc[rr][3]);
        }
    }
    __syncthreads();                 // everyone done reading xs
    *(float4*)&xs[rg][c0] = make_float4(s0, s1, s2, s3);   // reuse xs[0..7][*]
    __syncthreads();
    if (t < 128) {
        float r = 0.f;
#pragma unroll
        for (int g = 0; g < 8; g++) r += xs[g][t];
        part[((size_t)blockIdx.y * PB2 + blockIdx.x) * 128 + t] = r;
    }
}

// ---------------------------------------------------------------------------
// reduce partials -> S_k[c] (32 chunks x 2 metapaths, few atomics)
// ---------------------------------------------------------------------------
__global__ __launch_bounds__(128) void reduceS_kernel(
    const float* __restrict__ part, float* __restrict__ S_at, float* __restrict__ S_tt)
{
    const int k = blockIdx.y;
    const int c = threadIdx.x;
    float* S = (k == 0) ? S_at : S_tt;
    const int b0 = blockIdx.x * 49;
    const int b1 = min(b0 + 49, PB2);
    float s = 0.f;
    for (int b = b0; b < b1; b++)
        s += part[((size_t)k * PB2 + b) * 128 + c];
    atomicAdd(&S[c], s);
}

// ---------------------------------------------------------------------------
// attn: score_k = (q . S_k) / NTX; attn = softmax over k=2
// ---------------------------------------------------------------------------
__global__ __launch_bounds__(128) void attn_kernel(
    const float* __restrict__ S0, const float* __restrict__ S1,
    const float* __restrict__ q, float* __restrict__ attn)
{
    __shared__ float r0[128], r1[128];
    int c = threadIdx.x;
    r0[c] = q[c] * S0[c];
    r1[c] = q[c] * S1[c];
    __syncthreads();
    for (int s = 64; s > 0; s >>= 1) {
        if (c < s) { r0[c] += r0[c + s]; r1[c] += r1[c + s]; }
        __syncthreads();
    }
    if (c == 0) {
        float s0 = r0[0] / (float)NTX, s1 = r1[0] / (float)NTX;
        float m = fmaxf(s0, s1);
        float e0 = expf(s0 - m), e1 = expf(s1 - m);
        float inv = 1.f / (e0 + e1);
        attn[0] = e0 * inv;
        attn[1] = e1 * inv;
    }
}

// ---------------------------------------------------------------------------
// final_pool: batch is SORTED -> group g is a contiguous run [lo,hi).
// pooled[g,c] = (a0*sum_at + a1*sum_tt)/max(hi-lo,1); out = pooled @ Wl + bl.
// ---------------------------------------------------------------------------
__device__ __forceinline__ int lower_bound_g(const int* __restrict__ batch, int val)
{
    int lo = 0, hi = NTX;
    while (lo < hi) {
        int mid = (lo + hi) >> 1;
        if (batch[mid] < val) lo = mid + 1; else hi = mid;
    }
    return lo;
}

__global__ __launch_bounds__(128) void final_pool_kernel(
    const float* __restrict__ out_at, const float* __restrict__ out_tt,
    const int* __restrict__ batch, const float* __restrict__ attn,
    const float* __restrict__ Wl, const float* __restrict__ bl,
    float* __restrict__ out)
{
    __shared__ float r0[128], r1[128];
    const int g = blockIdx.x, c = threadIdx.x;
    const int lo = lower_bound_g(batch, g);
    const int hi = lower_bound_g(batch, g + 1);
    float s0 = 0.f, s1 = 0.f;
    for (int n = lo; n < hi; n++) {
        s0 += out_at[(size_t)n * 128 + c];
        s1 += out_tt[(size_t)n * 128 + c];
    }
    float pooled = (attn[0] * s0 + attn[1] * s1) / fmaxf((float)(hi - lo), 1.f);
    r0[c] = pooled * Wl[c * 2 + 0];
    r1[c] = pooled * Wl[c * 2 + 1];
    __syncthreads();
    for (int s = 64; s > 0; s >>= 1) {
        if (c < s) { r0[c] += r0[c + s]; r1[c] += r1[c + s]; }
        __syncthreads();
    }
    if (c == 0) {
        out[g * 2 + 0] = r0[0] + bl[0];
        out[g * 2 + 1] = r1[0] + bl[1];
    }
}

// ---------------------------------------------------------------------------
extern "C" void kernel_launch(void* const* d_in, const int* in_sizes, int n_in,
                              void* d_out, int out_size, void* d_ws, size_t ws_size,
                              hipStream_t stream)
{
    const float* x_tx     = (const float*)d_in[0];
    const float* x_ad     = (const float*)d_in[1];
    // d_in[2] = ei_ta (dead: out_ta never consumed)
    const int*   ei_at    = (const int*)d_in[3];
    const int*   ei_tt    = (const int*)d_in[4];
    const int*   batch    = (const int*)d_in[5];
    const float* W_tx     = (const float*)d_in[6];
    const float* b_tx     = (const float*)d_in[7];
    const float* W_ad     = (const float*)d_in[8];
    const float* b_ad     = (const float*)d_in[9];
    // d_in[10], d_in[11] = a_src_ta, a_dst_ta (dead)
    const float* a_src_at = (const float*)d_in[12];
    const float* a_dst_at = (const float*)d_in[13];
    const float* a_src_tt = (const float*)d_in[14];
    const float* a_dst_tt = (const float*)d_in[15];
    const float* Wk       = (const float*)d_in[16];
    const float* bk       = (const float*)d_in[17];
    const float* q        = (const float*)d_in[18];
    const float* Wl       = (const float*)d_in[19];
    const float* bl       = (const float*)d_in[20];
    float* out = (float*)d_out;

    char* ws = (char*)d_ws;
    size_t off = 0;
    auto alloc = [&](size_t bytes) -> void* {
        void* p = ws + off;
        off += (bytes + 255) & ~(size_t)255;
        return p;
    };
    float* h_tx    = (float*)alloc((size_t)NTX * 128 * 4);
    float* h_ad    = (float*)alloc((size_t)NADDR * 128 * 4);
    float* al_sat  = (float*)alloc((size_t)NADDR * 4 * 4);
    float* al_dat  = (float*)alloc((size_t)NTX * 4 * 4);
    float* al_stt  = (float*)alloc((size_t)NTX * 4 * 4);
    float* al_dtt  = (float*)alloc((size_t)NTX * 4 * 4);
    float* out_at  = (float*)alloc((size_t)NTX * 128 * 4);  // fully written by gather
    float* out_tt  = (float*)alloc((size_t)NTX * 128 * 4);
    int* csr_at    = (int*)alloc((size_t)NE * 4);
    int* csr_tt    = (int*)alloc((size_t)NE * 4);
    int* row_at    = (int*)alloc((size_t)NTX * 4);
    int* row_tt    = (int*)alloc((size_t)NTX * 4);
    float* part    = (float*)alloc((size_t)2 * PB2 * 128 * 4);
    // ---- zeroed region (counters / S accumulators) ----
    char* zero0 = ws + off;
    int* deg_at    = (int*)alloc((size_t)NTX * 4);
    int* deg_tt    = (int*)alloc((size_t)NTX * 4);
    int* cur_at    = (int*)alloc((size_t)NTX * 4);
    int* cur_tt    = (int*)alloc((size_t)NTX * 4);
    float* S_at    = (float*)alloc(128 * 4);
    float* S_tt    = (float*)alloc(128 * 4);
    size_t zbytes = (size_t)((ws + off) - zero0);
    float* attnw   = (float*)alloc(2 * 4);

    hipMemsetAsync(zero0, 0, zbytes, stream);

    // projections + attention-logit dots (both node types, one dispatch)
    proj2_kernel<<<2 * PB2, 256, 0, stream>>>(
        x_tx, W_tx, b_tx, h_tx, x_ad, W_ad, b_ad, h_ad,
        a_dst_at, al_dat, a_src_tt, al_stt, a_dst_tt, al_dtt,
        a_src_at, al_sat);

    // CSR build (dst-major), both edge types per dispatch
    int eb2 = (2 * NE + 255) / 256;
    deg2_kernel<<<eb2, 256, 0, stream>>>(ei_at, ei_tt, deg_at, deg_tt);
    scan2_kernel<<<2, 256, 0, stream>>>(deg_at, row_at, deg_tt, row_tt);
    fill2_kernel<<<eb2, 256, 0, stream>>>(ei_at, row_at, cur_at, csr_at,
                                          ei_tt, row_tt, cur_tt, csr_tt);

    // gather-style GAT (no atomics, fused softmax-normalize + relu)
    dim3 ggrid(NTX, 2);
    gat_gather2_kernel<<<ggrid, 128, 0, stream>>>(
        row_at, deg_at, csr_at, al_sat, al_dat, h_ad, out_at,
        row_tt, deg_tt, csr_tt, al_stt, al_dtt, h_tx, out_tt);

    // semantic attention: tanh GEMM partials -> reduce -> softmax over 2
    dim3 tgrid(PB2, 2);
    tanh_gemm_kernel<<<tgrid, 256, 0, stream>>>(out_at, out_tt, Wk, bk, part);
    dim3 rgrid(32, 2);
    reduceS_kernel<<<rgrid, 128, 0, stream>>>(part, S_at, S_tt);
    attn_kernel<<<1, 128, 0, stream>>>(S_at, S_tt, q, attnw);

    // fused pooling (sorted batch -> contiguous runs) + final linear
    final_pool_kernel<<<GG, 128, 0, stream>>>(out_at, out_tt, batch, attnw, Wl, bl, out);
}

// Round 5
// 376.457 us; speedup vs baseline: 5.9601x; 1.2384x over previous
//
#include <hip/hip_runtime.h>

#define NTX   50000
#define NADDR 50000
#define NE    500000
#define GG    512
#define NEG   0.2f
#define BM    32
#define PB2   1563   // ceil(50000/32)
#define NCHUNK 196   // ceil(50000/256)

__device__ __forceinline__ float lrelu(float x) { return x > 0.f ? x : NEG * x; }

// ---------------------------------------------------------------------------
// proj2: both node-type projections in one dispatch, 4x4 register tiling.
// ---------------------------------------------------------------------------
__global__ __launch_bounds__(256) void proj2_kernel(
    const float* __restrict__ x_tx, const float* __restrict__ W_tx,
    const float* __restrict__ b_tx, float* __restrict__ h_tx,
    const float* __restrict__ x_ad, const float* __restrict__ W_ad,
    const float* __restrict__ b_ad, float* __restrict__ h_ad,
    const float* __restrict__ a_dat, float* __restrict__ al_dat,
    const float* __restrict__ a_stt, float* __restrict__ al_stt,
    const float* __restrict__ a_dtt, float* __restrict__ al_dtt,
    const float* __restrict__ a_sat, float* __restrict__ al_sat)
{
    __shared__ float Ws[128 * 128];   // 64 KiB
    __shared__ float xs[BM][128];     // 16 KiB
    const bool is_tx = blockIdx.x < PB2;
    const float* x = is_tx ? x_tx : x_ad;
    const float* W = is_tx ? W_tx : W_ad;
    const float* b = is_tx ? b_tx : b_ad;
    float* h       = is_tx ? h_tx : h_ad;
    const int row0 = (is_tx ? blockIdx.x : blockIdx.x - PB2) * BM;

    const int t = threadIdx.x;
    {
        const float4* W4 = (const float4*)W;
        float4* Ws4 = (float4*)Ws;
#pragma unroll 4
        for (int i = t; i < 128 * 32; i += 256) Ws4[i] = W4[i];
        const float4* x4 = (const float4*)x;
        float4* xs4 = (float4*)&xs[0][0];
        for (int i = t; i < BM * 32; i += 256) {
            int rr = i >> 5, q = i & 31;
            int gr = row0 + rr; if (gr >= NTX) gr = NTX - 1;
            xs4[i] = x4[(size_t)gr * 32 + q];
        }
    }
    __syncthreads();

    const int cg = t & 31, rg = t >> 5;
    const int c0 = cg * 4;
    float acc[4][4];
    {
        float4 bv = *(const float4*)(b + c0);
#pragma unroll
        for (int rr = 0; rr < 4; rr++) {
            acc[rr][0] = bv.x; acc[rr][1] = bv.y; acc[rr][2] = bv.z; acc[rr][3] = bv.w;
        }
    }

    for (int j = 0; j < 128; j += 4) {
        float xq[4][4];
#pragma unroll
        for (int rr = 0; rr < 4; rr++) {
            float4 v = *(const float4*)&xs[rg * 4 + rr][j];
            xq[rr][0] = v.x; xq[rr][1] = v.y; xq[rr][2] = v.z; xq[rr][3] = v.w;
        }
#pragma unroll
        for (int jj = 0; jj < 4; jj++) {
            float4 wv = *(const float4*)&Ws[(j + jj) * 128 + c0];
#pragma unroll
            for (int rr = 0; rr < 4; rr++) {
                acc[rr][0] = fmaf(xq[rr][jj], wv.x, acc[rr][0]);
                acc[rr][1] = fmaf(xq[rr][jj], wv.y, acc[rr][1]);
                acc[rr][2] = fmaf(xq[rr][jj], wv.z, acc[rr][2]);
                acc[rr][3] = fmaf(xq[rr][jj], wv.w, acc[rr][3]);
            }
        }
    }

#pragma unroll
    for (int rr = 0; rr < 4; rr++) {
        int row = row0 + rg * 4 + rr;
        if (row < NTX)
            *(float4*)&h[(size_t)row * 128 + c0] =
                make_float4(acc[rr][0], acc[rr][1], acc[rr][2], acc[rr][3]);
    }

    const int head = cg >> 3;
    const bool wlead = (cg & 7) == 0;
    auto do_dot = [&](const float* __restrict__ a, float* __restrict__ al) {
        float4 av = *(const float4*)(a + c0);
#pragma unroll
        for (int rr = 0; rr < 4; rr++) {
            float p = acc[rr][0] * av.x + acc[rr][1] * av.y
                    + acc[rr][2] * av.z + acc[rr][3] * av.w;
            p += __shfl_xor(p, 1); p += __shfl_xor(p, 2); p += __shfl_xor(p, 4);
            int row = row0 + rg * 4 + rr;
            if (wlead && row < NTX) al[(size_t)row * 4 + head] = p;
        }
    };
    if (is_tx) { do_dot(a_dat, al_dat); do_dot(a_stt, al_stt); do_dot(a_dtt, al_dtt); }
    else       { do_dot(a_sat, al_sat); }
}

// ---------------------------------------------------------------------------
// CSR build: degree -> (chunksum, chunkscan, scanwrite) -> fill
// ---------------------------------------------------------------------------
__global__ __launch_bounds__(256) void deg2_kernel(
    const int* __restrict__ ei0, const int* __restrict__ ei1,
    int* __restrict__ deg0, int* __restrict__ deg1)
{
    int idx = blockIdx.x * 256 + threadIdx.x;
    if (idx < NE) atomicAdd(&deg0[ei0[NE + idx]], 1);
    else if (idx < 2 * NE) atomicAdd(&deg1[ei1[NE + (idx - NE)]], 1);
}

// chunk sums: grid (NCHUNK, 2)
__global__ __launch_bounds__(256) void chunksum_kernel(
    const int* __restrict__ deg0, const int* __restrict__ deg1,
    int* __restrict__ csum)   // [2][NCHUNK]
{
    const int* deg = blockIdx.y == 0 ? deg0 : deg1;
    __shared__ int s[256];
    const int t = threadIdx.x;
    int idx = blockIdx.x * 256 + t;
    s[t] = idx < NTX ? deg[idx] : 0;
    __syncthreads();
    for (int o = 128; o > 0; o >>= 1) {
        if (t < o) s[t] += s[t + o];
        __syncthreads();
    }
    if (t == 0) csum[blockIdx.y * NCHUNK + blockIdx.x] = s[0];
}

// exclusive scan of chunk sums: grid (2)
__global__ __launch_bounds__(256) void chunkscan_kernel(int* __restrict__ csum)
{
    __shared__ int s[256];
    const int t = threadIdx.x;
    int* base = csum + blockIdx.x * NCHUNK;
    int v = t < NCHUNK ? base[t] : 0;
    s[t] = v;
    __syncthreads();
    for (int o = 1; o < 256; o <<= 1) {
        int u = (t >= o) ? s[t - o] : 0;
        __syncthreads();
        s[t] += u;
        __syncthreads();
    }
    if (t < NCHUNK) base[t] = s[t] - v;   // exclusive
}

// per-element exclusive scan + chunk offset: grid (NCHUNK, 2)
__global__ __launch_bounds__(256) void scanwrite_kernel(
    const int* __restrict__ deg0, const int* __restrict__ deg1,
    const int* __restrict__ csum,
    int* __restrict__ row0, int* __restrict__ row1)
{
    const int* deg = blockIdx.y == 0 ? deg0 : deg1;
    int* row       = blockIdx.y == 0 ? row0 : row1;
    __shared__ int s[256];
    const int t = threadIdx.x;
    int idx = blockIdx.x * 256 + t;
    int v = idx < NTX ? deg[idx] : 0;
    s[t] = v;
    __syncthreads();
    for (int o = 1; o < 256; o <<= 1) {
        int u = (t >= o) ? s[t - o] : 0;
        __syncthreads();
        s[t] += u;
        __syncthreads();
    }
    if (idx < NTX)
        row[idx] = s[t] - v + csum[blockIdx.y * NCHUNK + blockIdx.x];
}

__global__ __launch_bounds__(256) void fill2_kernel(
    const int* __restrict__ ei0, const int* __restrict__ row0,
    int* __restrict__ cur0, int* __restrict__ csr0,
    const int* __restrict__ ei1, const int* __restrict__ row1,
    int* __restrict__ cur1, int* __restrict__ csr1)
{
    int idx = blockIdx.x * 256 + threadIdx.x;
    if (idx < NE) {
        int d = ei0[NE + idx];
        int pos = row0[d] + atomicAdd(&cur0[d], 1);
        csr0[pos] = ei0[idx];
    } else if (idx < 2 * NE) {
        int e = idx - NE;
        int d = ei1[NE + e];
        int pos = row1[d] + atomicAdd(&cur1[d], 1);
        csr1[pos] = ei1[e];
    }
}

// ---------------------------------------------------------------------------
// Gather GAT (both edge types via blockIdx.y). One block (128 thr) per dst.
// ---------------------------------------------------------------------------
__global__ __launch_bounds__(128) void gat_gather2_kernel(
    const int* __restrict__ row_at, const int* __restrict__ deg_at,
    const int* __restrict__ csr_at, const float* __restrict__ als_at,
    const float* __restrict__ ald_at, const float* __restrict__ h_at,
    float* __restrict__ out_at,
    const int* __restrict__ row_tt, const int* __restrict__ deg_tt,
    const int* __restrict__ csr_tt, const float* __restrict__ als_tt,
    const float* __restrict__ ald_tt, const float* __restrict__ h_tt,
    float* __restrict__ out_tt)
{
    const bool at = (blockIdx.y == 0);
    const int* rs = at ? row_at : row_tt;
    const int* dg = at ? deg_at : deg_tt;
    const int* cs = at ? csr_at : csr_tt;
    const float* als = at ? als_at : als_tt;
    const float* ald = at ? ald_at : ald_tt;
    const float* hsrc = at ? h_at : h_tt;
    float* out = at ? out_at : out_tt;

    const int d = blockIdx.x;
    const int c = threadIdx.x;
    const int head = c >> 5;
    const float aldv = ald[d * 4 + head];
    const int beg = rs[d];
    const int n = dg[d];
    float acc = 0.f, den = 0.f;
    int i = 0;
    for (; i + 4 <= n; i += 4) {
        int s0 = cs[beg + i], s1 = cs[beg + i + 1];
        int s2 = cs[beg + i + 2], s3 = cs[beg + i + 3];
        float l0 = als[s0 * 4 + head], l1 = als[s1 * 4 + head];
        float l2 = als[s2 * 4 + head], l3 = als[s3 * 4 + head];
        float h0 = hsrc[(size_t)s0 * 128 + c], h1 = hsrc[(size_t)s1 * 128 + c];
        float h2 = hsrc[(size_t)s2 * 128 + c], h3 = hsrc[(size_t)s3 * 128 + c];
        float e0 = expf(lrelu(l0 + aldv));
        float e1 = expf(lrelu(l1 + aldv));
        float e2 = expf(lrelu(l2 + aldv));
        float e3 = expf(lrelu(l3 + aldv));
        den += (e0 + e1) + (e2 + e3);
        acc = fmaf(e0, h0, fmaf(e1, h1, fmaf(e2, h2, fmaf(e3, h3, acc))));
    }
    for (; i < n; i++) {
        int s0 = cs[beg + i];
        float e0 = expf(lrelu(als[s0 * 4 + head] + aldv));
        den += e0;
        acc = fmaf(e0, hsrc[(size_t)s0 * 128 + c], acc);
    }
    float v = acc / (den + 1e-16f);
    out[(size_t)d * 128 + c] = v > 0.f ? v : 0.f;
}

// ---------------------------------------------------------------------------
// tanh GEMM (both metapaths via blockIdx.y), 4x4 register tiling.
// ---------------------------------------------------------------------------
__global__ __launch_bounds__(256) void tanh_gemm_kernel(
    const float* __restrict__ out_at, const float* __restrict__ out_tt,
    const float* __restrict__ Wk, const float* __restrict__ bk,
    float* __restrict__ part)    // [2][PB2][128]
{
    __shared__ float Ws[128 * 128];
    __shared__ float xs[BM][128];
    const float* src = (blockIdx.y == 0) ? out_at : out_tt;
    const int row0 = blockIdx.x * BM;
    const int t = threadIdx.x;
    {
        const float4* W4 = (const float4*)Wk;
        float4* Ws4 = (float4*)Ws;
#pragma unroll 4
        for (int i = t; i < 128 * 32; i += 256) Ws4[i] = W4[i];
        const float4* x4 = (const float4*)src;
        float4* xs4 = (float4*)&xs[0][0];
        for (int i = t; i < BM * 32; i += 256) {
            int rr = i >> 5, q = i & 31;
            int gr = row0 + rr; if (gr >= NTX) gr = NTX - 1;
            xs4[i] = x4[(size_t)gr * 32 + q];
        }
    }
    __syncthreads();

    const int cg = t & 31, rg = t >> 5;
    const int c0 = cg * 4;
    float acc[4][4];
    {
        float4 bv = *(const float4*)(bk + c0);
#pragma unroll
        for (int rr = 0; rr < 4; rr++) {
            acc[rr][0] = bv.x; acc[rr][1] = bv.y; acc[rr][2] = bv.z; acc[rr][3] = bv.w;
        }
    }

    for (int j = 0; j < 128; j += 4) {
        float xq[4][4];
#pragma unroll
        for (int rr = 0; rr < 4; rr++) {
            float4 v = *(const float4*)&xs[rg * 4 + rr][j];
            xq[rr][0] = v.x; xq[rr][1] = v.y; xq[rr][2] = v.z; xq[rr][3] = v.w;
        }
#pragma unroll
        for (int jj = 0; jj < 4; jj++) {
            float4 wv = *(const float4*)&Ws[(j + jj) * 128 + c0];
#pragma unroll
            for (int rr = 0; rr < 4; rr++) {
                acc[rr][0] = fmaf(xq[rr][jj], wv.x, acc[rr][0]);
                acc[rr][1] = fmaf(xq[rr][jj], wv.y, acc[rr][1]);
                acc[rr][2] = fmaf(xq[rr][jj], wv.z, acc[rr][2]);
                acc[rr][3] = fmaf(xq[rr][jj], wv.w, acc[rr][3]);
            }
        }
    }

    float s0 = 0.f, s1 = 0.f, s2 = 0.f, s3 = 0.f;
#pragma unroll
    for (int rr = 0; rr < 4; rr++) {
        int row = row0 + rg * 4 + rr;
        if (row < NTX) {
            s0 += tanhf(acc[rr][0]); s1 += tanhf(acc[rr][1]);
            s2 += tanhf(acc[rr][2]); s3 += tanhf(acc[rr][3]);
        }
    }
    __syncthreads();                 // everyone done reading xs
    *(float4*)&xs[rg][c0] = make_float4(s0, s1, s2, s3);   // reuse xs[0..7][*]
    __syncthreads();
    if (t < 128) {
        float r = 0.f;
#pragma unroll
        for (int g = 0; g < 8; g++) r += xs[g][t];
        part[((size_t)blockIdx.y * PB2 + blockIdx.x) * 128 + t] = r;
    }
}

// ---------------------------------------------------------------------------
// reduce partials -> S_k[c]
// ---------------------------------------------------------------------------
__global__ __launch_bounds__(128) void reduceS_kernel(
    const float* __restrict__ part, float* __restrict__ S_at, float* __restrict__ S_tt)
{
    const int k = blockIdx.y;
    const int c = threadIdx.x;
    float* S = (k == 0) ? S_at : S_tt;
    const int b0 = blockIdx.x * 49;
    const int b1 = min(b0 + 49, PB2);
    float s = 0.f;
    for (int b = b0; b < b1; b++)
        s += part[((size_t)k * PB2 + b) * 128 + c];
    atomicAdd(&S[c], s);
}

// ---------------------------------------------------------------------------
// attn: score_k = (q . S_k) / NTX; attn = softmax over k=2
// ---------------------------------------------------------------------------
__global__ __launch_bounds__(128) void attn_kernel(
    const float* __restrict__ S0, const float* __restrict__ S1,
    const float* __restrict__ q, float* __restrict__ attn)
{
    __shared__ float r0[128], r1[128];
    int c = threadIdx.x;
    r0[c] = q[c] * S0[c];
    r1[c] = q[c] * S1[c];
    __syncthreads();
    for (int s = 64; s > 0; s >>= 1) {
        if (c < s) { r0[c] += r0[c + s]; r1[c] += r1[c + s]; }
        __syncthreads();
    }
    if (c == 0) {
        float s0 = r0[0] / (float)NTX, s1 = r1[0] / (float)NTX;
        float m = fmaxf(s0, s1);
        float e0 = expf(s0 - m), e1 = expf(s1 - m);
        float inv = 1.f / (e0 + e1);
        attn[0] = e0 * inv;
        attn[1] = e1 * inv;
    }
}

// ---------------------------------------------------------------------------
// final_pool: batch is SORTED -> group g is a contiguous run [lo,hi).
// ---------------------------------------------------------------------------
__device__ __forceinline__ int lower_bound_g(const int* __restrict__ batch, int val)
{
    int lo = 0, hi = NTX;
    while (lo < hi) {
        int mid = (lo + hi) >> 1;
        if (batch[mid] < val) lo = mid + 1; else hi = mid;
    }
    return lo;
}

__global__ __launch_bounds__(128) void final_pool_kernel(
    const float* __restrict__ out_at, const float* __restrict__ out_tt,
    const int* __restrict__ batch, const float* __restrict__ attn,
    const float* __restrict__ Wl, const float* __restrict__ bl,
    float* __restrict__ out)
{
    __shared__ float r0[128], r1[128];
    const int g = blockIdx.x, c = threadIdx.x;
    const int lo = lower_bound_g(batch, g);
    const int hi = lower_bound_g(batch, g + 1);
    float s0 = 0.f, s1 = 0.f;
    for (int n = lo; n < hi; n++) {
        s0 += out_at[(size_t)n * 128 + c];
        s1 += out_tt[(size_t)n * 128 + c];
    }
    float pooled = (attn[0] * s0 + attn[1] * s1) / fmaxf((float)(hi - lo), 1.f);
    r0[c] = pooled * Wl[c * 2 + 0];
    r1[c] = pooled * Wl[c * 2 + 1];
    __syncthreads();
    for (int s = 64; s > 0; s >>= 1) {
        if (c < s) { r0[c] += r0[c + s]; r1[c] += r1[c + s]; }
        __syncthreads();
    }
    if (c == 0) {
        out[g * 2 + 0] = r0[0] + bl[0];
        out[g * 2 + 1] = r1[0] + bl[1];
    }
}

// ---------------------------------------------------------------------------
extern "C" void kernel_launch(void* const* d_in, const int* in_sizes, int n_in,
                              void* d_out, int out_size, void* d_ws, size_t ws_size,
                              hipStream_t stream)
{
    const float* x_tx     = (const float*)d_in[0];
    const float* x_ad     = (const float*)d_in[1];
    // d_in[2] = ei_ta (dead: out_ta never consumed)
    const int*   ei_at    = (const int*)d_in[3];
    const int*   ei_tt    = (const int*)d_in[4];
    const int*   batch    = (const int*)d_in[5];
    const float* W_tx     = (const float*)d_in[6];
    const float* b_tx     = (const float*)d_in[7];
    const float* W_ad     = (const float*)d_in[8];
    const float* b_ad     = (const float*)d_in[9];
    // d_in[10], d_in[11] = a_src_ta, a_dst_ta (dead)
    const float* a_src_at = (const float*)d_in[12];
    const float* a_dst_at = (const float*)d_in[13];
    const float* a_src_tt = (const float*)d_in[14];
    const float* a_dst_tt = (const float*)d_in[15];
    const float* Wk       = (const float*)d_in[16];
    const float* bk       = (const float*)d_in[17];
    const float* q        = (const float*)d_in[18];
    const float* Wl       = (const float*)d_in[19];
    const float* bl       = (const float*)d_in[20];
    float* out = (float*)d_out;

    char* ws = (char*)d_ws;
    size_t off = 0;
    auto alloc = [&](size_t bytes) -> void* {
        void* p = ws + off;
        off += (bytes + 255) & ~(size_t)255;
        return p;
    };
    float* h_tx    = (float*)alloc((size_t)NTX * 128 * 4);
    float* h_ad    = (float*)alloc((size_t)NADDR * 128 * 4);
    float* al_sat  = (float*)alloc((size_t)NADDR * 4 * 4);
    float* al_dat  = (float*)alloc((size_t)NTX * 4 * 4);
    float* al_stt  = (float*)alloc((size_t)NTX * 4 * 4);
    float* al_dtt  = (float*)alloc((size_t)NTX * 4 * 4);
    float* out_at  = (float*)alloc((size_t)NTX * 128 * 4);  // fully written by gather
    float* out_tt  = (float*)alloc((size_t)NTX * 128 * 4);
    int* csr_at    = (int*)alloc((size_t)NE * 4);
    int* csr_tt    = (int*)alloc((size_t)NE * 4);
    int* row_at    = (int*)alloc((size_t)NTX * 4);
    int* row_tt    = (int*)alloc((size_t)NTX * 4);
    int* csum      = (int*)alloc((size_t)2 * NCHUNK * 4);
    float* part    = (float*)alloc((size_t)2 * PB2 * 128 * 4);
    // ---- zeroed region (counters / S accumulators) ----
    char* zero0 = ws + off;
    int* deg_at    = (int*)alloc((size_t)NTX * 4);
    int* deg_tt    = (int*)alloc((size_t)NTX * 4);
    int* cur_at    = (int*)alloc((size_t)NTX * 4);
    int* cur_tt    = (int*)alloc((size_t)NTX * 4);
    float* S_at    = (float*)alloc(128 * 4);
    float* S_tt    = (float*)alloc(128 * 4);
    size_t zbytes = (size_t)((ws + off) - zero0);
    float* attnw   = (float*)alloc(2 * 4);

    hipMemsetAsync(zero0, 0, zbytes, stream);

    // projections + attention-logit dots (both node types, one dispatch)
    proj2_kernel<<<2 * PB2, 256, 0, stream>>>(
        x_tx, W_tx, b_tx, h_tx, x_ad, W_ad, b_ad, h_ad,
        a_dst_at, al_dat, a_src_tt, al_stt, a_dst_tt, al_dtt,
        a_src_at, al_sat);

    // CSR build (dst-major), both edge types per dispatch
    int eb2 = (2 * NE + 255) / 256;
    deg2_kernel<<<eb2, 256, 0, stream>>>(ei_at, ei_tt, deg_at, deg_tt);
    dim3 sgrid(NCHUNK, 2);
    chunksum_kernel<<<sgrid, 256, 0, stream>>>(deg_at, deg_tt, csum);
    chunkscan_kernel<<<2, 256, 0, stream>>>(csum);
    scanwrite_kernel<<<sgrid, 256, 0, stream>>>(deg_at, deg_tt, csum, row_at, row_tt);
    fill2_kernel<<<eb2, 256, 0, stream>>>(ei_at, row_at, cur_at, csr_at,
                                          ei_tt, row_tt, cur_tt, csr_tt);

    // gather-style GAT (no atomics, fused softmax-normalize + relu)
    dim3 ggrid(NTX, 2);
    gat_gather2_kernel<<<ggrid, 128, 0, stream>>>(
        row_at, deg_at, csr_at, al_sat, al_dat, h_ad, out_at,
        row_tt, deg_tt, csr_tt, al_stt, al_dtt, h_tx, out_tt);

    // semantic attention: tanh GEMM partials -> reduce -> softmax over 2
    dim3 tgrid(PB2, 2);
    tanh_gemm_kernel<<<tgrid, 256, 0, stream>>>(out_at, out_tt, Wk, bk, part);
    dim3 rgrid(32, 2);
    reduceS_kernel<<<rgrid, 128, 0, stream>>>(part, S_at, S_tt);
    attn_kernel<<<1, 128, 0, stream>>>(S_at, S_tt, q, attnw);

    // fused pooling (sorted batch -> contiguous runs) + final linear
    final_pool_kernel<<<GG, 128, 0, stream>>>(out_at, out_tt, batch, attnw, Wl, bl, out);
}

// Round 6
// 356.870 us; speedup vs baseline: 6.2872x; 1.0549x over previous
//
#include <hip/hip_runtime.h>
#include <hip/hip_fp16.h>

#define NTX   50000
#define NADDR 50000
#define NE    500000
#define GG    512
#define NEG   0.2f
#define BM    32
#define PB2   1563   // ceil(50000/32)
#define NCHUNK 196   // ceil(50000/256)

__device__ __forceinline__ float lrelu(float x) { return x > 0.f ? x : NEG * x; }

// ---------------------------------------------------------------------------
// proj2: both node-type projections in one dispatch, 4x4 register tiling.
// h output stored FP16 (only consumer is the gather); al dots in fp32.
// ---------------------------------------------------------------------------
__global__ __launch_bounds__(256) void proj2_kernel(
    const float* __restrict__ x_tx, const float* __restrict__ W_tx,
    const float* __restrict__ b_tx, __half* __restrict__ h_tx,
    const float* __restrict__ x_ad, const float* __restrict__ W_ad,
    const float* __restrict__ b_ad, __half* __restrict__ h_ad,
    const float* __restrict__ a_dat, float* __restrict__ al_dat,
    const float* __restrict__ a_stt, float* __restrict__ al_stt,
    const float* __restrict__ a_dtt, float* __restrict__ al_dtt,
    const float* __restrict__ a_sat, float* __restrict__ al_sat)
{
    __shared__ float Ws[128 * 128];   // 64 KiB
    __shared__ float xs[BM][128];     // 16 KiB
    const bool is_tx = blockIdx.x < PB2;
    const float* x = is_tx ? x_tx : x_ad;
    const float* W = is_tx ? W_tx : W_ad;
    const float* b = is_tx ? b_tx : b_ad;
    __half* h      = is_tx ? h_tx : h_ad;
    const int row0 = (is_tx ? blockIdx.x : blockIdx.x - PB2) * BM;

    const int t = threadIdx.x;
    {
        const float4* W4 = (const float4*)W;
        float4* Ws4 = (float4*)Ws;
#pragma unroll 4
        for (int i = t; i < 128 * 32; i += 256) Ws4[i] = W4[i];
        const float4* x4 = (const float4*)x;
        float4* xs4 = (float4*)&xs[0][0];
        for (int i = t; i < BM * 32; i += 256) {
            int rr = i >> 5, q = i & 31;
            int gr = row0 + rr; if (gr >= NTX) gr = NTX - 1;
            xs4[i] = x4[(size_t)gr * 32 + q];
        }
    }
    __syncthreads();

    const int cg = t & 31, rg = t >> 5;
    const int c0 = cg * 4;
    float acc[4][4];
    {
        float4 bv = *(const float4*)(b + c0);
#pragma unroll
        for (int rr = 0; rr < 4; rr++) {
            acc[rr][0] = bv.x; acc[rr][1] = bv.y; acc[rr][2] = bv.z; acc[rr][3] = bv.w;
        }
    }

    for (int j = 0; j < 128; j += 4) {
        float xq[4][4];
#pragma unroll
        for (int rr = 0; rr < 4; rr++) {
            float4 v = *(const float4*)&xs[rg * 4 + rr][j];
            xq[rr][0] = v.x; xq[rr][1] = v.y; xq[rr][2] = v.z; xq[rr][3] = v.w;
        }
#pragma unroll
        for (int jj = 0; jj < 4; jj++) {
            float4 wv = *(const float4*)&Ws[(j + jj) * 128 + c0];
#pragma unroll
            for (int rr = 0; rr < 4; rr++) {
                acc[rr][0] = fmaf(xq[rr][jj], wv.x, acc[rr][0]);
                acc[rr][1] = fmaf(xq[rr][jj], wv.y, acc[rr][1]);
                acc[rr][2] = fmaf(xq[rr][jj], wv.z, acc[rr][2]);
                acc[rr][3] = fmaf(xq[rr][jj], wv.w, acc[rr][3]);
            }
        }
    }

#pragma unroll
    for (int rr = 0; rr < 4; rr++) {
        int row = row0 + rg * 4 + rr;
        if (row < NTX) {
            __half2 p0 = __floats2half2_rn(acc[rr][0], acc[rr][1]);
            __half2 p1 = __floats2half2_rn(acc[rr][2], acc[rr][3]);
            __half2* dst = (__half2*)&h[(size_t)row * 128 + c0];
            dst[0] = p0; dst[1] = p1;
        }
    }

    const int head = cg >> 3;
    const bool wlead = (cg & 7) == 0;
    auto do_dot = [&](const float* __restrict__ a, float* __restrict__ al) {
        float4 av = *(const float4*)(a + c0);
#pragma unroll
        for (int rr = 0; rr < 4; rr++) {
            float p = acc[rr][0] * av.x + acc[rr][1] * av.y
                    + acc[rr][2] * av.z + acc[rr][3] * av.w;
            p += __shfl_xor(p, 1); p += __shfl_xor(p, 2); p += __shfl_xor(p, 4);
            int row = row0 + rg * 4 + rr;
            if (wlead && row < NTX) al[(size_t)row * 4 + head] = p;
        }
    };
    if (is_tx) { do_dot(a_dat, al_dat); do_dot(a_stt, al_stt); do_dot(a_dtt, al_dtt); }
    else       { do_dot(a_sat, al_sat); }
}

// ---------------------------------------------------------------------------
// CSR build: degree -> (chunksum, chunkscan, scanwrite) -> fill(+exp)
// ---------------------------------------------------------------------------
__global__ __launch_bounds__(256) void deg2_kernel(
    const int* __restrict__ ei0, const int* __restrict__ ei1,
    int* __restrict__ deg0, int* __restrict__ deg1)
{
    int idx = blockIdx.x * 256 + threadIdx.x;
    if (idx < NE) atomicAdd(&deg0[ei0[NE + idx]], 1);
    else if (idx < 2 * NE) atomicAdd(&deg1[ei1[NE + (idx - NE)]], 1);
}

// chunk sums: grid (NCHUNK, 2)
__global__ __launch_bounds__(256) void chunksum_kernel(
    const int* __restrict__ deg0, const int* __restrict__ deg1,
    int* __restrict__ csum)   // [2][NCHUNK]
{
    const int* deg = blockIdx.y == 0 ? deg0 : deg1;
    __shared__ int s[256];
    const int t = threadIdx.x;
    int idx = blockIdx.x * 256 + t;
    s[t] = idx < NTX ? deg[idx] : 0;
    __syncthreads();
    for (int o = 128; o > 0; o >>= 1) {
        if (t < o) s[t] += s[t + o];
        __syncthreads();
    }
    if (t == 0) csum[blockIdx.y * NCHUNK + blockIdx.x] = s[0];
}

// exclusive scan of chunk sums: grid (2)
__global__ __launch_bounds__(256) void chunkscan_kernel(int* __restrict__ csum)
{
    __shared__ int s[256];
    const int t = threadIdx.x;
    int* base = csum + blockIdx.x * NCHUNK;
    int v = t < NCHUNK ? base[t] : 0;
    s[t] = v;
    __syncthreads();
    for (int o = 1; o < 256; o <<= 1) {
        int u = (t >= o) ? s[t - o] : 0;
        __syncthreads();
        s[t] += u;
        __syncthreads();
    }
    if (t < NCHUNK) base[t] = s[t] - v;   // exclusive
}

// per-element exclusive scan + chunk offset: grid (NCHUNK, 2)
__global__ __launch_bounds__(256) void scanwrite_kernel(
    const int* __restrict__ deg0, const int* __restrict__ deg1,
    const int* __restrict__ csum,
    int* __restrict__ row0, int* __restrict__ row1)
{
    const int* deg = blockIdx.y == 0 ? deg0 : deg1;
    int* row       = blockIdx.y == 0 ? row0 : row1;
    __shared__ int s[256];
    const int t = threadIdx.x;
    int idx = blockIdx.x * 256 + t;
    int v = idx < NTX ? deg[idx] : 0;
    s[t] = v;
    __syncthreads();
    for (int o = 1; o < 256; o <<= 1) {
        int u = (t >= o) ? s[t - o] : 0;
        __syncthreads();
        s[t] += u;
        __syncthreads();
    }
    if (idx < NTX)
        row[idx] = s[t] - v + csum[blockIdx.y * NCHUNK + blockIdx.x];
}

// fill CSR slots AND compute edge softmax numerators (4 heads) in CSR order.
__global__ __launch_bounds__(256) void fill2_kernel(
    const int* __restrict__ ei0, const int* __restrict__ row0,
    int* __restrict__ cur0, int* __restrict__ csr0,
    const float* __restrict__ als0, const float* __restrict__ ald0,
    float* __restrict__ ex0,
    const int* __restrict__ ei1, const int* __restrict__ row1,
    int* __restrict__ cur1, int* __restrict__ csr1,
    const float* __restrict__ als1, const float* __restrict__ ald1,
    float* __restrict__ ex1)
{
    int idx = blockIdx.x * 256 + threadIdx.x;
    const int* ei; const int* row; int* cur; int* csr;
    const float* als; const float* ald; float* ex;
    int e;
    if (idx < NE) {
        ei = ei0; row = row0; cur = cur0; csr = csr0;
        als = als0; ald = ald0; ex = ex0; e = idx;
    } else if (idx < 2 * NE) {
        ei = ei1; row = row1; cur = cur1; csr = csr1;
        als = als1; ald = ald1; ex = ex1; e = idx - NE;
    } else return;
    int s = ei[e];
    int d = ei[NE + e];
    int pos = row[d] + atomicAdd(&cur[d], 1);
    csr[pos] = s;
    float4 as = *(const float4*)(als + (size_t)s * 4);
    float4 ad = *(const float4*)(ald + (size_t)d * 4);
    float4 exv;
    exv.x = __expf(lrelu(as.x + ad.x));
    exv.y = __expf(lrelu(as.y + ad.y));
    exv.z = __expf(lrelu(as.z + ad.z));
    exv.w = __expf(lrelu(as.w + ad.w));
    *(float4*)&ex[(size_t)pos * 4] = exv;
}

// ---------------------------------------------------------------------------
// Gather GAT (both edge types via blockIdx.y). One block (128 thr) per dst.
// Weights precomputed in CSR order; h in fp16. Inner loop = load+fma only.
// ---------------------------------------------------------------------------
__global__ __launch_bounds__(128) void gat_gather2_kernel(
    const int* __restrict__ row_at, const int* __restrict__ deg_at,
    const int* __restrict__ csr_at, const float* __restrict__ ex_at,
    const __half* __restrict__ h_at, float* __restrict__ out_at,
    const int* __restrict__ row_tt, const int* __restrict__ deg_tt,
    const int* __restrict__ csr_tt, const float* __restrict__ ex_tt,
    const __half* __restrict__ h_tt, float* __restrict__ out_tt)
{
    const bool at = (blockIdx.y == 0);
    const int* rs = at ? row_at : row_tt;
    const int* dg = at ? deg_at : deg_tt;
    const int* cs = at ? csr_at : csr_tt;
    const float* ex = at ? ex_at : ex_tt;
    const __half* hsrc = at ? h_at : h_tt;
    float* out = at ? out_at : out_tt;

    const int d = blockIdx.x;
    const int c = threadIdx.x;
    const int head = c >> 5;
    const int beg = rs[d];
    const int n = dg[d];
    float acc = 0.f, den = 0.f;
    int i = 0;
    for (; i + 4 <= n; i += 4) {
        int s0 = cs[beg + i], s1 = cs[beg + i + 1];
        int s2 = cs[beg + i + 2], s3 = cs[beg + i + 3];
        float w0 = ex[(size_t)(beg + i) * 4 + head];
        float w1 = ex[(size_t)(beg + i + 1) * 4 + head];
        float w2 = ex[(size_t)(beg + i + 2) * 4 + head];
        float w3 = ex[(size_t)(beg + i + 3) * 4 + head];
        float h0 = __half2float(hsrc[(size_t)s0 * 128 + c]);
        float h1 = __half2float(hsrc[(size_t)s1 * 128 + c]);
        float h2 = __half2float(hsrc[(size_t)s2 * 128 + c]);
        float h3 = __half2float(hsrc[(size_t)s3 * 128 + c]);
        den += (w0 + w1) + (w2 + w3);
        acc = fmaf(w0, h0, fmaf(w1, h1, fmaf(w2, h2, fmaf(w3, h3, acc))));
    }
    for (; i < n; i++) {
        int s0 = cs[beg + i];
        float w0 = ex[(size_t)(beg + i) * 4 + head];
        den += w0;
        acc = fmaf(w0, __half2float(hsrc[(size_t)s0 * 128 + c]), acc);
    }
    float v = acc / (den + 1e-16f);
    out[(size_t)d * 128 + c] = v > 0.f ? v : 0.f;
}

// ---------------------------------------------------------------------------
// tanh GEMM (both metapaths via blockIdx.y), 4x4 register tiling.
// ---------------------------------------------------------------------------
__global__ __launch_bounds__(256) void tanh_gemm_kernel(
    const float* __restrict__ out_at, const float* __restrict__ out_tt,
    const float* __restrict__ Wk, const float* __restrict__ bk,
    float* __restrict__ part)    // [2][PB2][128]
{
    __shared__ float Ws[128 * 128];
    __shared__ float xs[BM][128];
    const float* src = (blockIdx.y == 0) ? out_at : out_tt;
    const int row0 = blockIdx.x * BM;
    const int t = threadIdx.x;
    {
        const float4* W4 = (const float4*)Wk;
        float4* Ws4 = (float4*)Ws;
#pragma unroll 4
        for (int i = t; i < 128 * 32; i += 256) Ws4[i] = W4[i];
        const float4* x4 = (const float4*)src;
        float4* xs4 = (float4*)&xs[0][0];
        for (int i = t; i < BM * 32; i += 256) {
            int rr = i >> 5, q = i & 31;
            int gr = row0 + rr; if (gr >= NTX) gr = NTX - 1;
            xs4[i] = x4[(size_t)gr * 32 + q];
        }
    }
    __syncthreads();

    const int cg = t & 31, rg = t >> 5;
    const int c0 = cg * 4;
    float acc[4][4];
    {
        float4 bv = *(const float4*)(bk + c0);
#pragma unroll
        for (int rr = 0; rr < 4; rr++) {
            acc[rr][0] = bv.x; acc[rr][1] = bv.y; acc[rr][2] = bv.z; acc[rr][3] = bv.w;
        }
    }

    for (int j = 0; j < 128; j += 4) {
        float xq[4][4];
#pragma unroll
        for (int rr = 0; rr < 4; rr++) {
            float4 v = *(const float4*)&xs[rg * 4 + rr][j];
            xq[rr][0] = v.x; xq[rr][1] = v.y; xq[rr][2] = v.z; xq[rr][3] = v.w;
        }
#pragma unroll
        for (int jj = 0; jj < 4; jj++) {
            float4 wv = *(const float4*)&Ws[(j + jj) * 128 + c0];
#pragma unroll
            for (int rr = 0; rr < 4; rr++) {
                acc[rr][0] = fmaf(xq[rr][jj], wv.x, acc[rr][0]);
                acc[rr][1] = fmaf(xq[rr][jj], wv.y, acc[rr][1]);
                acc[rr][2] = fmaf(xq[rr][jj], wv.z, acc[rr][2]);
                acc[rr][3] = fmaf(xq[rr][jj], wv.w, acc[rr][3]);
            }
        }
    }

    float s0 = 0.f, s1 = 0.f, s2 = 0.f, s3 = 0.f;
#pragma unroll
    for (int rr = 0; rr < 4; rr++) {
        int row = row0 + rg * 4 + rr;
        if (row < NTX) {
            s0 += tanhf(acc[rr][0]); s1 += tanhf(acc[rr][1]);
            s2 += tanhf(acc[rr][2]); s3 += tanhf(acc[rr][3]);
        }
    }
    __syncthreads();                 // everyone done reading xs
    *(float4*)&xs[rg][c0] = make_float4(s0, s1, s2, s3);   // reuse xs[0..7][*]
    __syncthreads();
    if (t < 128) {
        float r = 0.f;
#pragma unroll
        for (int g = 0; g < 8; g++) r += xs[g][t];
        part[((size_t)blockIdx.y * PB2 + blockIdx.x) * 128 + t] = r;
    }
}

// ---------------------------------------------------------------------------
// reduce partials -> S_k[c]
// ---------------------------------------------------------------------------
__global__ __launch_bounds__(128) void reduceS_kernel(
    const float* __restrict__ part, float* __restrict__ S_at, float* __restrict__ S_tt)
{
    const int k = blockIdx.y;
    const int c = threadIdx.x;
    float* S = (k == 0) ? S_at : S_tt;
    const int b0 = blockIdx.x * 49;
    const int b1 = min(b0 + 49, PB2);
    float s = 0.f;
    for (int b = b0; b < b1; b++)
        s += part[((size_t)k * PB2 + b) * 128 + c];
    atomicAdd(&S[c], s);
}

// ---------------------------------------------------------------------------
// attn: score_k = (q . S_k) / NTX; attn = softmax over k=2
// ---------------------------------------------------------------------------
__global__ __launch_bounds__(128) void attn_kernel(
    const float* __restrict__ S0, const float* __restrict__ S1,
    const float* __restrict__ q, float* __restrict__ attn)
{
    __shared__ float r0[128], r1[128];
    int c = threadIdx.x;
    r0[c] = q[c] * S0[c];
    r1[c] = q[c] * S1[c];
    __syncthreads();
    for (int s = 64; s > 0; s >>= 1) {
        if (c < s) { r0[c] += r0[c + s]; r1[c] += r1[c + s]; }
        __syncthreads();
    }
    if (c == 0) {
        float s0 = r0[0] / (float)NTX, s1 = r1[0] / (float)NTX;
        float m = fmaxf(s0, s1);
        float e0 = expf(s0 - m), e1 = expf(s1 - m);
        float inv = 1.f / (e0 + e1);
        attn[0] = e0 * inv;
        attn[1] = e1 * inv;
    }
}

// ---------------------------------------------------------------------------
// final_pool: batch is SORTED -> group g is a contiguous run [lo,hi).
// ---------------------------------------------------------------------------
__device__ __forceinline__ int lower_bound_g(const int* __restrict__ batch, int val)
{
    int lo = 0, hi = NTX;
    while (lo < hi) {
        int mid = (lo + hi) >> 1;
        if (batch[mid] < val) lo = mid + 1; else hi = mid;
    }
    return lo;
}

__global__ __launch_bounds__(128) void final_pool_kernel(
    const float* __restrict__ out_at, const float* __restrict__ out_tt,
    const int* __restrict__ batch, const float* __restrict__ attn,
    const float* __restrict__ Wl, const float* __restrict__ bl,
    float* __restrict__ out)
{
    __shared__ float r0[128], r1[128];
    const int g = blockIdx.x, c = threadIdx.x;
    const int lo = lower_bound_g(batch, g);
    const int hi = lower_bound_g(batch, g + 1);
    float s0 = 0.f, s1 = 0.f;
    for (int n = lo; n < hi; n++) {
        s0 += out_at[(size_t)n * 128 + c];
        s1 += out_tt[(size_t)n * 128 + c];
    }
    float pooled = (attn[0] * s0 + attn[1] * s1) / fmaxf((float)(hi - lo), 1.f);
    r0[c] = pooled * Wl[c * 2 + 0];
    r1[c] = pooled * Wl[c * 2 + 1];
    __syncthreads();
    for (int s = 64; s > 0; s >>= 1) {
        if (c < s) { r0[c] += r0[c + s]; r1[c] += r1[c + s]; }
        __syncthreads();
    }
    if (c == 0) {
        out[g * 2 + 0] = r0[0] + bl[0];
        out[g * 2 + 1] = r1[0] + bl[1];
    }
}

// ---------------------------------------------------------------------------
extern "C" void kernel_launch(void* const* d_in, const int* in_sizes, int n_in,
                              void* d_out, int out_size, void* d_ws, size_t ws_size,
                              hipStream_t stream)
{
    const float* x_tx     = (const float*)d_in[0];
    const float* x_ad     = (const float*)d_in[1];
    // d_in[2] = ei_ta (dead: out_ta never consumed)
    const int*   ei_at    = (const int*)d_in[3];
    const int*   ei_tt    = (const int*)d_in[4];
    const int*   batch    = (const int*)d_in[5];
    const float* W_tx     = (const float*)d_in[6];
    const float* b_tx     = (const float*)d_in[7];
    const float* W_ad     = (const float*)d_in[8];
    const float* b_ad     = (const float*)d_in[9];
    // d_in[10], d_in[11] = a_src_ta, a_dst_ta (dead)
    const float* a_src_at = (const float*)d_in[12];
    const float* a_dst_at = (const float*)d_in[13];
    const float* a_src_tt = (const float*)d_in[14];
    const float* a_dst_tt = (const float*)d_in[15];
    const float* Wk       = (const float*)d_in[16];
    const float* bk       = (const float*)d_in[17];
    const float* q        = (const float*)d_in[18];
    const float* Wl       = (const float*)d_in[19];
    const float* bl       = (const float*)d_in[20];
    float* out = (float*)d_out;

    char* ws = (char*)d_ws;
    size_t off = 0;
    auto alloc = [&](size_t bytes) -> void* {
        void* p = ws + off;
        off += (bytes + 255) & ~(size_t)255;
        return p;
    };
    __half* h_tx   = (__half*)alloc((size_t)NTX * 128 * 2);
    __half* h_ad   = (__half*)alloc((size_t)NADDR * 128 * 2);
    float* al_sat  = (float*)alloc((size_t)NADDR * 4 * 4);
    float* al_dat  = (float*)alloc((size_t)NTX * 4 * 4);
    float* al_stt  = (float*)alloc((size_t)NTX * 4 * 4);
    float* al_dtt  = (float*)alloc((size_t)NTX * 4 * 4);
    float* out_at  = (float*)alloc((size_t)NTX * 128 * 4);  // fully written by gather
    float* out_tt  = (float*)alloc((size_t)NTX * 128 * 4);
    int* csr_at    = (int*)alloc((size_t)NE * 4);
    int* csr_tt    = (int*)alloc((size_t)NE * 4);
    float* ex_at   = (float*)alloc((size_t)NE * 4 * 4);     // CSR-ordered, 4 heads
    float* ex_tt   = (float*)alloc((size_t)NE * 4 * 4);
    int* row_at    = (int*)alloc((size_t)NTX * 4);
    int* row_tt    = (int*)alloc((size_t)NTX * 4);
    int* csum      = (int*)alloc((size_t)2 * NCHUNK * 4);
    float* part    = (float*)alloc((size_t)2 * PB2 * 128 * 4);
    // ---- zeroed region (counters / S accumulators) ----
    char* zero0 = ws + off;
    int* deg_at    = (int*)alloc((size_t)NTX * 4);
    int* deg_tt    = (int*)alloc((size_t)NTX * 4);
    int* cur_at    = (int*)alloc((size_t)NTX * 4);
    int* cur_tt    = (int*)alloc((size_t)NTX * 4);
    float* S_at    = (float*)alloc(128 * 4);
    float* S_tt    = (float*)alloc(128 * 4);
    size_t zbytes = (size_t)((ws + off) - zero0);
    float* attnw   = (float*)alloc(2 * 4);

    hipMemsetAsync(zero0, 0, zbytes, stream);

    // projections + attention-logit dots (both node types, one dispatch)
    proj2_kernel<<<2 * PB2, 256, 0, stream>>>(
        x_tx, W_tx, b_tx, h_tx, x_ad, W_ad, b_ad, h_ad,
        a_dst_at, al_dat, a_src_tt, al_stt, a_dst_tt, al_dtt,
        a_src_at, al_sat);

    // CSR build (dst-major), both edge types per dispatch
    int eb2 = (2 * NE + 255) / 256;
    deg2_kernel<<<eb2, 256, 0, stream>>>(ei_at, ei_tt, deg_at, deg_tt);
    dim3 sgrid(NCHUNK, 2);
    chunksum_kernel<<<sgrid, 256, 0, stream>>>(deg_at, deg_tt, csum);
    chunkscan_kernel<<<2, 256, 0, stream>>>(csum);
    scanwrite_kernel<<<sgrid, 256, 0, stream>>>(deg_at, deg_tt, csum, row_at, row_tt);
    fill2_kernel<<<eb2, 256, 0, stream>>>(
        ei_at, row_at, cur_at, csr_at, al_sat, al_dat, ex_at,
        ei_tt, row_tt, cur_tt, csr_tt, al_stt, al_dtt, ex_tt);

    // gather-style GAT (no atomics, precomputed weights, fp16 h)
    dim3 ggrid(NTX, 2);
    gat_gather2_kernel<<<ggrid, 128, 0, stream>>>(
        row_at, deg_at, csr_at, ex_at, h_ad, out_at,
        row_tt, deg_tt, csr_tt, ex_tt, h_tx, out_tt);

    // semantic attention: tanh GEMM partials -> reduce -> softmax over 2
    dim3 tgrid(PB2, 2);
    tanh_gemm_kernel<<<tgrid, 256, 0, stream>>>(out_at, out_tt, Wk, bk, part);
    dim3 rgrid(32, 2);
    reduceS_kernel<<<rgrid, 128, 0, stream>>>(part, S_at, S_tt);
    attn_kernel<<<1, 128, 0, stream>>>(S_at, S_tt, q, attnw);

    // fused pooling (sorted batch -> contiguous runs) + final linear
    final_pool_kernel<<<GG, 128, 0, stream>>>(out_at, out_tt, batch, attnw, Wl, bl, out);
}

// Round 7
// 291.345 us; speedup vs baseline: 7.7012x; 1.2249x over previous
//
#include <hip/hip_runtime.h>

#define NTX   50000
#define NADDR 50000
#define NE    500000
#define GG    512
#define NEG   0.2f
#define MBLK  64
#define PBM   782    // ceil(50000/64)
#define NCHUNK 196   // ceil(50000/256)

typedef _Float16 f16;
typedef f16 f16x4 __attribute__((ext_vector_type(4)));
typedef f16 f16x8 __attribute__((ext_vector_type(8)));
typedef float f32x4 __attribute__((ext_vector_type(4)));

__device__ __forceinline__ float lrelu(float x) { return x > 0.f ? x : NEG * x; }

// ---------------------------------------------------------------------------
// proj2 (MFMA): h = fp16(x @ W + b), fused attention-logit dots (fp32).
// 64 rows/block, 4 waves; A = x rows (fp16 LDS, row-major), B = W^T (fp16 LDS).
// mfma_f32_16x16x32_f16: A[l&15][(l>>4)*8+j], B[(l>>4)*8+j][l&15],
// C col=l&15, row=(l>>4)*4+reg  (m89-verified C layout).
// blocks [0,PBM) = tx, [PBM,2*PBM) = addr.
// ---------------------------------------------------------------------------
__global__ __launch_bounds__(256) void proj2_kernel(
    const float* __restrict__ x_tx, const float* __restrict__ W_tx,
    const float* __restrict__ b_tx, f16* __restrict__ h_tx,
    const float* __restrict__ x_ad, const float* __restrict__ W_ad,
    const float* __restrict__ b_ad, f16* __restrict__ h_ad,
    const float* __restrict__ a_dat, float* __restrict__ al_dat,
    const float* __restrict__ a_stt, float* __restrict__ al_stt,
    const float* __restrict__ a_dtt, float* __restrict__ al_dtt,
    const float* __restrict__ a_sat, float* __restrict__ al_sat)
{
    __shared__ f16 Wt[128][136];   // W^T, padded: 272 B row stride (16B-aligned)
    __shared__ f16 xt[MBLK][136];
    const bool is_tx = blockIdx.x < PBM;
    const float* x = is_tx ? x_tx : x_ad;
    const float* W = is_tx ? W_tx : W_ad;
    const float* b = is_tx ? b_tx : b_ad;
    f16* h         = is_tx ? h_tx : h_ad;
    const int row0 = (is_tx ? blockIdx.x : blockIdx.x - PBM) * MBLK;
    const int t = threadIdx.x;

    // stage W^T as fp16 (transpose during store)
    for (int i = t; i < 128 * 128; i += 256) {
        int j = i >> 7, c = i & 127;     // W[j][c]
        Wt[c][j] = (f16)W[i];
    }
    // stage x rows as fp16 (no transpose needed for A fragments)
    for (int i = t; i < MBLK * 32; i += 256) {
        int r = i >> 5, q = i & 31;
        int gr = row0 + r; if (gr >= NTX) gr = NTX - 1;
        float4 v = ((const float4*)x)[(size_t)gr * 32 + q];
        f16x4 p = {(f16)v.x, (f16)v.y, (f16)v.z, (f16)v.w};
        *(f16x4*)&xt[r][q * 4] = p;
    }
    __syncthreads();

    const int l = t & 63, w = t >> 6;
    const int l15 = l & 15, lq = l >> 4;

    f16x8 afrag[4];
#pragma unroll
    for (int kt = 0; kt < 4; kt++)
        afrag[kt] = *(const f16x8*)&xt[w * 16 + l15][kt * 32 + lq * 8];

    f32x4 acc[8];
#pragma unroll
    for (int n = 0; n < 8; n++) {
        float bc = b[n * 16 + l15];
        acc[n] = (f32x4){bc, bc, bc, bc};
#pragma unroll
        for (int kt = 0; kt < 4; kt++) {
            f16x8 bfrag = *(const f16x8*)&Wt[n * 16 + l15][kt * 32 + lq * 8];
            acc[n] = __builtin_amdgcn_mfma_f32_16x16x32_f16(afrag[kt], bfrag, acc[n], 0, 0, 0);
        }
    }

    // store h as fp16
#pragma unroll
    for (int r = 0; r < 4; r++) {
        int row = row0 + w * 16 + lq * 4 + r;
        if (row < NTX) {
#pragma unroll
            for (int n = 0; n < 8; n++)
                h[(size_t)row * 128 + n * 16 + l15] = (f16)acc[n][r];
        }
    }

    // attention-logit dots: al[row][head] = sum_c h[row][c]*a[c], head = c>>5
    auto do_dot = [&](const float* __restrict__ a, float* __restrict__ al) {
        float av[8];
#pragma unroll
        for (int n = 0; n < 8; n++) av[n] = a[n * 16 + l15];
#pragma unroll
        for (int r = 0; r < 4; r++) {
            float p0 = acc[0][r] * av[0] + acc[1][r] * av[1];
            float p1 = acc[2][r] * av[2] + acc[3][r] * av[3];
            float p2 = acc[4][r] * av[4] + acc[5][r] * av[5];
            float p3 = acc[6][r] * av[6] + acc[7][r] * av[7];
#pragma unroll
            for (int o = 1; o < 16; o <<= 1) {
                p0 += __shfl_xor(p0, o); p1 += __shfl_xor(p1, o);
                p2 += __shfl_xor(p2, o); p3 += __shfl_xor(p3, o);
            }
            int row = row0 + w * 16 + lq * 4 + r;
            if (l15 == 0 && row < NTX) {
                float4 v = make_float4(p0, p1, p2, p3);
                *(float4*)&al[(size_t)row * 4] = v;
            }
        }
    };
    if (is_tx) { do_dot(a_dat, al_dat); do_dot(a_stt, al_stt); do_dot(a_dtt, al_dtt); }
    else       { do_dot(a_sat, al_sat); }
}

// ---------------------------------------------------------------------------
// CSR build: degree -> (chunksum, chunkscan, scanwrite) -> fill(+exp)
// ---------------------------------------------------------------------------
__global__ __launch_bounds__(256) void deg2_kernel(
    const int* __restrict__ ei0, const int* __restrict__ ei1,
    int* __restrict__ deg0, int* __restrict__ deg1)
{
    int idx = blockIdx.x * 256 + threadIdx.x;
    if (idx < NE) atomicAdd(&deg0[ei0[NE + idx]], 1);
    else if (idx < 2 * NE) atomicAdd(&deg1[ei1[NE + (idx - NE)]], 1);
}

__global__ __launch_bounds__(256) void chunksum_kernel(
    const int* __restrict__ deg0, const int* __restrict__ deg1,
    int* __restrict__ csum)   // [2][NCHUNK]
{
    const int* deg = blockIdx.y == 0 ? deg0 : deg1;
    __shared__ int s[256];
    const int t = threadIdx.x;
    int idx = blockIdx.x * 256 + t;
    s[t] = idx < NTX ? deg[idx] : 0;
    __syncthreads();
    for (int o = 128; o > 0; o >>= 1) {
        if (t < o) s[t] += s[t + o];
        __syncthreads();
    }
    if (t == 0) csum[blockIdx.y * NCHUNK + blockIdx.x] = s[0];
}

__global__ __launch_bounds__(256) void chunkscan_kernel(int* __restrict__ csum)
{
    __shared__ int s[256];
    const int t = threadIdx.x;
    int* base = csum + blockIdx.x * NCHUNK;
    int v = t < NCHUNK ? base[t] : 0;
    s[t] = v;
    __syncthreads();
    for (int o = 1; o < 256; o <<= 1) {
        int u = (t >= o) ? s[t - o] : 0;
        __syncthreads();
        s[t] += u;
        __syncthreads();
    }
    if (t < NCHUNK) base[t] = s[t] - v;   // exclusive
}

__global__ __launch_bounds__(256) void scanwrite_kernel(
    const int* __restrict__ deg0, const int* __restrict__ deg1,
    const int* __restrict__ csum,
    int* __restrict__ row0, int* __restrict__ row1)
{
    const int* deg = blockIdx.y == 0 ? deg0 : deg1;
    int* row       = blockIdx.y == 0 ? row0 : row1;
    __shared__ int s[256];
    const int t = threadIdx.x;
    int idx = blockIdx.x * 256 + t;
    int v = idx < NTX ? deg[idx] : 0;
    s[t] = v;
    __syncthreads();
    for (int o = 1; o < 256; o <<= 1) {
        int u = (t >= o) ? s[t - o] : 0;
        __syncthreads();
        s[t] += u;
        __syncthreads();
    }
    if (idx < NTX)
        row[idx] = s[t] - v + csum[blockIdx.y * NCHUNK + blockIdx.x];
}

// fill CSR slots AND compute edge softmax numerators (4 heads) in CSR order.
__global__ __launch_bounds__(256) void fill2_kernel(
    const int* __restrict__ ei0, const int* __restrict__ row0,
    int* __restrict__ cur0, int* __restrict__ csr0,
    const float* __restrict__ als0, const float* __restrict__ ald0,
    float* __restrict__ ex0,
    const int* __restrict__ ei1, const int* __restrict__ row1,
    int* __restrict__ cur1, int* __restrict__ csr1,
    const float* __restrict__ als1, const float* __restrict__ ald1,
    float* __restrict__ ex1)
{
    int idx = blockIdx.x * 256 + threadIdx.x;
    const int* ei; const int* row; int* cur; int* csr;
    const float* als; const float* ald; float* ex;
    int e;
    if (idx < NE) {
        ei = ei0; row = row0; cur = cur0; csr = csr0;
        als = als0; ald = ald0; ex = ex0; e = idx;
    } else if (idx < 2 * NE) {
        ei = ei1; row = row1; cur = cur1; csr = csr1;
        als = als1; ald = ald1; ex = ex1; e = idx - NE;
    } else return;
    int s = ei[e];
    int d = ei[NE + e];
    int pos = row[d] + atomicAdd(&cur[d], 1);
    csr[pos] = s;
    float4 as = *(const float4*)(als + (size_t)s * 4);
    float4 ad = *(const float4*)(ald + (size_t)d * 4);
    float4 exv;
    exv.x = __expf(lrelu(as.x + ad.x));
    exv.y = __expf(lrelu(as.y + ad.y));
    exv.z = __expf(lrelu(as.z + ad.z));
    exv.w = __expf(lrelu(as.w + ad.w));
    *(float4*)&ex[(size_t)pos * 4] = exv;
}

// ---------------------------------------------------------------------------
// Gather GAT (both edge types via blockIdx.y). One block (128 thr) per dst.
// Weights precomputed in CSR order; h fp16; out fp16.
// ---------------------------------------------------------------------------
__global__ __launch_bounds__(128) void gat_gather2_kernel(
    const int* __restrict__ row_at, const int* __restrict__ deg_at,
    const int* __restrict__ csr_at, const float* __restrict__ ex_at,
    const f16* __restrict__ h_at, f16* __restrict__ out_at,
    const int* __restrict__ row_tt, const int* __restrict__ deg_tt,
    const int* __restrict__ csr_tt, const float* __restrict__ ex_tt,
    const f16* __restrict__ h_tt, f16* __restrict__ out_tt)
{
    const bool at = (blockIdx.y == 0);
    const int* rs = at ? row_at : row_tt;
    const int* dg = at ? deg_at : deg_tt;
    const int* cs = at ? csr_at : csr_tt;
    const float* ex = at ? ex_at : ex_tt;
    const f16* hsrc = at ? h_at : h_tt;
    f16* out = at ? out_at : out_tt;

    const int d = blockIdx.x;
    const int c = threadIdx.x;
    const int head = c >> 5;
    const int beg = rs[d];
    const int n = dg[d];
    float acc = 0.f, den = 0.f;
    int i = 0;
    for (; i + 4 <= n; i += 4) {
        int s0 = cs[beg + i], s1 = cs[beg + i + 1];
        int s2 = cs[beg + i + 2], s3 = cs[beg + i + 3];
        float w0 = ex[(size_t)(beg + i) * 4 + head];
        float w1 = ex[(size_t)(beg + i + 1) * 4 + head];
        float w2 = ex[(size_t)(beg + i + 2) * 4 + head];
        float w3 = ex[(size_t)(beg + i + 3) * 4 + head];
        float h0 = (float)hsrc[(size_t)s0 * 128 + c];
        float h1 = (float)hsrc[(size_t)s1 * 128 + c];
        float h2 = (float)hsrc[(size_t)s2 * 128 + c];
        float h3 = (float)hsrc[(size_t)s3 * 128 + c];
        den += (w0 + w1) + (w2 + w3);
        acc = fmaf(w0, h0, fmaf(w1, h1, fmaf(w2, h2, fmaf(w3, h3, acc))));
    }
    for (; i < n; i++) {
        int s0 = cs[beg + i];
        float w0 = ex[(size_t)(beg + i) * 4 + head];
        den += w0;
        acc = fmaf(w0, (float)hsrc[(size_t)s0 * 128 + c], acc);
    }
    float v = acc / (den + 1e-16f);
    out[(size_t)d * 128 + c] = (f16)(v > 0.f ? v : 0.f);
}

// ---------------------------------------------------------------------------
// tanh GEMM (MFMA, both metapaths via blockIdx.y):
// part[k][blk][c] = sum over 64-row tile of tanh((out_k @ Wk + bk))[.,c]
// ---------------------------------------------------------------------------
__global__ __launch_bounds__(256) void tanh_gemm_kernel(
    const f16* __restrict__ out_at, const f16* __restrict__ out_tt,
    const float* __restrict__ Wk, const float* __restrict__ bk,
    float* __restrict__ part)    // [2][PBM][128]
{
    __shared__ f16 Wt[128][136];
    __shared__ f16 xt[MBLK][136];
    const f16* src = (blockIdx.y == 0) ? out_at : out_tt;
    const int row0 = blockIdx.x * MBLK;
    const int t = threadIdx.x;

    for (int i = t; i < 128 * 128; i += 256) {
        int j = i >> 7, c = i & 127;
        Wt[c][j] = (f16)Wk[i];
    }
    for (int i = t; i < MBLK * 16; i += 256) {
        int r = i >> 4, q = i & 15;
        int gr = row0 + r; if (gr >= NTX) gr = NTX - 1;
        *(f16x8*)&xt[r][q * 8] = ((const f16x8*)src)[(size_t)gr * 16 + q];
    }
    __syncthreads();

    const int l = t & 63, w = t >> 6;
    const int l15 = l & 15, lq = l >> 4;

    f16x8 afrag[4];
#pragma unroll
    for (int kt = 0; kt < 4; kt++)
        afrag[kt] = *(const f16x8*)&xt[w * 16 + l15][kt * 32 + lq * 8];

    float pn[8];
#pragma unroll
    for (int n = 0; n < 8; n++) {
        float bc = bk[n * 16 + l15];
        f32x4 acc = (f32x4){bc, bc, bc, bc};
#pragma unroll
        for (int kt = 0; kt < 4; kt++) {
            f16x8 bfrag = *(const f16x8*)&Wt[n * 16 + l15][kt * 32 + lq * 8];
            acc = __builtin_amdgcn_mfma_f32_16x16x32_f16(afrag[kt], bfrag, acc, 0, 0, 0);
        }
        float s = 0.f;
#pragma unroll
        for (int r = 0; r < 4; r++) {
            int row = row0 + w * 16 + lq * 4 + r;
            if (row < NTX) s += tanhf(acc[r]);
        }
        s += __shfl_xor(s, 16);
        s += __shfl_xor(s, 32);
        pn[n] = s;                    // lanes 0-15 hold col sums for this wave
    }

    __syncthreads();                  // all waves done reading xt
    float* Sblk = (float*)&xt[0][0];  // reuse xt as [4][128] float
    if (l < 16) {
#pragma unroll
        for (int n = 0; n < 8; n++)
            Sblk[w * 128 + n * 16 + l15] = pn[n];
    }
    __syncthreads();
    if (t < 128)
        part[((size_t)blockIdx.y * PBM + blockIdx.x) * 128 + t] =
            Sblk[t] + Sblk[128 + t] + Sblk[256 + t] + Sblk[384 + t];
}

// ---------------------------------------------------------------------------
// reduce partials -> S_k[c]
// ---------------------------------------------------------------------------
__global__ __launch_bounds__(128) void reduceS_kernel(
    const float* __restrict__ part, float* __restrict__ S_at, float* __restrict__ S_tt)
{
    const int k = blockIdx.y;
    const int c = threadIdx.x;
    float* S = (k == 0) ? S_at : S_tt;
    const int b0 = blockIdx.x * 25;
    const int b1 = min(b0 + 25, PBM);
    float s = 0.f;
    for (int b = b0; b < b1; b++)
        s += part[((size_t)k * PBM + b) * 128 + c];
    atomicAdd(&S[c], s);
}

// ---------------------------------------------------------------------------
// attn: score_k = (q . S_k) / NTX; attn = softmax over k=2
// ---------------------------------------------------------------------------
__global__ __launch_bounds__(128) void attn_kernel(
    const float* __restrict__ S0, const float* __restrict__ S1,
    const float* __restrict__ q, float* __restrict__ attn)
{
    __shared__ float r0[128], r1[128];
    int c = threadIdx.x;
    r0[c] = q[c] * S0[c];
    r1[c] = q[c] * S1[c];
    __syncthreads();
    for (int s = 64; s > 0; s >>= 1) {
        if (c < s) { r0[c] += r0[c + s]; r1[c] += r1[c + s]; }
        __syncthreads();
    }
    if (c == 0) {
        float s0 = r0[0] / (float)NTX, s1 = r1[0] / (float)NTX;
        float m = fmaxf(s0, s1);
        float e0 = expf(s0 - m), e1 = expf(s1 - m);
        float inv = 1.f / (e0 + e1);
        attn[0] = e0 * inv;
        attn[1] = e1 * inv;
    }
}

// ---------------------------------------------------------------------------
// final_pool: batch is SORTED -> group g is a contiguous run [lo,hi).
// ---------------------------------------------------------------------------
__device__ __forceinline__ int lower_bound_g(const int* __restrict__ batch, int val)
{
    int lo = 0, hi = NTX;
    while (lo < hi) {
        int mid = (lo + hi) >> 1;
        if (batch[mid] < val) lo = mid + 1; else hi = mid;
    }
    return lo;
}

__global__ __launch_bounds__(128) void final_pool_kernel(
    const f16* __restrict__ out_at, const f16* __restrict__ out_tt,
    const int* __restrict__ batch, const float* __restrict__ attn,
    const float* __restrict__ Wl, const float* __restrict__ bl,
    float* __restrict__ out)
{
    __shared__ float r0[128], r1[128];
    const int g = blockIdx.x, c = threadIdx.x;
    const int lo = lower_bound_g(batch, g);
    const int hi = lower_bound_g(batch, g + 1);
    float s0 = 0.f, s1 = 0.f;
    for (int n = lo; n < hi; n++) {
        s0 += (float)out_at[(size_t)n * 128 + c];
        s1 += (float)out_tt[(size_t)n * 128 + c];
    }
    float pooled = (attn[0] * s0 + attn[1] * s1) / fmaxf((float)(hi - lo), 1.f);
    r0[c] = pooled * Wl[c * 2 + 0];
    r1[c] = pooled * Wl[c * 2 + 1];
    __syncthreads();
    for (int s = 64; s > 0; s >>= 1) {
        if (c < s) { r0[c] += r0[c + s]; r1[c] += r1[c + s]; }
        __syncthreads();
    }
    if (c == 0) {
        out[g * 2 + 0] = r0[0] + bl[0];
        out[g * 2 + 1] = r1[0] + bl[1];
    }
}

// ---------------------------------------------------------------------------
extern "C" void kernel_launch(void* const* d_in, const int* in_sizes, int n_in,
                              void* d_out, int out_size, void* d_ws, size_t ws_size,
                              hipStream_t stream)
{
    const float* x_tx     = (const float*)d_in[0];
    const float* x_ad     = (const float*)d_in[1];
    // d_in[2] = ei_ta (dead: out_ta never consumed)
    const int*   ei_at    = (const int*)d_in[3];
    const int*   ei_tt    = (const int*)d_in[4];
    const int*   batch    = (const int*)d_in[5];
    const float* W_tx     = (const float*)d_in[6];
    const float* b_tx     = (const float*)d_in[7];
    const float* W_ad     = (const float*)d_in[8];
    const float* b_ad     = (const float*)d_in[9];
    // d_in[10], d_in[11] = a_src_ta, a_dst_ta (dead)
    const float* a_src_at = (const float*)d_in[12];
    const float* a_dst_at = (const float*)d_in[13];
    const float* a_src_tt = (const float*)d_in[14];
    const float* a_dst_tt = (const float*)d_in[15];
    const float* Wk       = (const float*)d_in[16];
    const float* bk       = (const float*)d_in[17];
    const float* q        = (const float*)d_in[18];
    const float* Wl       = (const float*)d_in[19];
    const float* bl       = (const float*)d_in[20];
    float* out = (float*)d_out;

    char* ws = (char*)d_ws;
    size_t off = 0;
    auto alloc = [&](size_t bytes) -> void* {
        void* p = ws + off;
        off += (bytes + 255) & ~(size_t)255;
        return p;
    };
    f16* h_tx      = (f16*)alloc((size_t)NTX * 128 * 2);
    f16* h_ad      = (f16*)alloc((size_t)NADDR * 128 * 2);
    float* al_sat  = (float*)alloc((size_t)NADDR * 4 * 4);
    float* al_dat  = (float*)alloc((size_t)NTX * 4 * 4);
    float* al_stt  = (float*)alloc((size_t)NTX * 4 * 4);
    float* al_dtt  = (float*)alloc((size_t)NTX * 4 * 4);
    f16* out_at    = (f16*)alloc((size_t)NTX * 128 * 2);   // fully written by gather
    f16* out_tt    = (f16*)alloc((size_t)NTX * 128 * 2);
    int* csr_at    = (int*)alloc((size_t)NE * 4);
    int* csr_tt    = (int*)alloc((size_t)NE * 4);
    float* ex_at   = (float*)alloc((size_t)NE * 4 * 4);    // CSR-ordered, 4 heads
    float* ex_tt   = (float*)alloc((size_t)NE * 4 * 4);
    int* row_at    = (int*)alloc((size_t)NTX * 4);
    int* row_tt    = (int*)alloc((size_t)NTX * 4);
    int* csum      = (int*)alloc((size_t)2 * NCHUNK * 4);
    float* part    = (float*)alloc((size_t)2 * PBM * 128 * 4);
    // ---- zeroed region (counters / S accumulators) ----
    char* zero0 = ws + off;
    int* deg_at    = (int*)alloc((size_t)NTX * 4);
    int* deg_tt    = (int*)alloc((size_t)NTX * 4);
    int* cur_at    = (int*)alloc((size_t)NTX * 4);
    int* cur_tt    = (int*)alloc((size_t)NTX * 4);
    float* S_at    = (float*)alloc(128 * 4);
    float* S_tt    = (float*)alloc(128 * 4);
    size_t zbytes = (size_t)((ws + off) - zero0);
    float* attnw   = (float*)alloc(2 * 4);

    hipMemsetAsync(zero0, 0, zbytes, stream);

    // projections + attention-logit dots (MFMA, both node types, one dispatch)
    proj2_kernel<<<2 * PBM, 256, 0, stream>>>(
        x_tx, W_tx, b_tx, h_tx, x_ad, W_ad, b_ad, h_ad,
        a_dst_at, al_dat, a_src_tt, al_stt, a_dst_tt, al_dtt,
        a_src_at, al_sat);

    // CSR build (dst-major), both edge types per dispatch
    int eb2 = (2 * NE + 255) / 256;
    deg2_kernel<<<eb2, 256, 0, stream>>>(ei_at, ei_tt, deg_at, deg_tt);
    dim3 sgrid(NCHUNK, 2);
    chunksum_kernel<<<sgrid, 256, 0, stream>>>(deg_at, deg_tt, csum);
    chunkscan_kernel<<<2, 256, 0, stream>>>(csum);
    scanwrite_kernel<<<sgrid, 256, 0, stream>>>(deg_at, deg_tt, csum, row_at, row_tt);
    fill2_kernel<<<eb2, 256, 0, stream>>>(
        ei_at, row_at, cur_at, csr_at, al_sat, al_dat, ex_at,
        ei_tt, row_tt, cur_tt, csr_tt, al_stt, al_dtt, ex_tt);

    // gather-style GAT (no atomics, precomputed weights, fp16 h/out)
    dim3 ggrid(NTX, 2);
    gat_gather2_kernel<<<ggrid, 128, 0, stream>>>(
        row_at, deg_at, csr_at, ex_at, h_ad, out_at,
        row_tt, deg_tt, csr_tt, ex_tt, h_tx, out_tt);

    // semantic attention: MFMA tanh GEMM partials -> reduce -> softmax over 2
    dim3 tgrid(PBM, 2);
    tanh_gemm_kernel<<<tgrid, 256, 0, stream>>>(out_at, out_tt, Wk, bk, part);
    dim3 rgrid(32, 2);
    reduceS_kernel<<<rgrid, 128, 0, stream>>>(part, S_at, S_tt);
    attn_kernel<<<1, 128, 0, stream>>>(S_at, S_tt, q, attnw);

    // fused pooling (sorted batch -> contiguous runs) + final linear
    final_pool_kernel<<<GG, 128, 0, stream>>>(out_at, out_tt, batch, attnw, Wl, bl, out);
}

// Round 8
// 283.218 us; speedup vs baseline: 7.9222x; 1.0287x over previous
//
#include <hip/hip_runtime.h>

#define NTX   50000
#define NADDR 50000
#define NE    500000
#define GG    512
#define NEG   0.2f
#define MBLK  64
#define PBM   782    // ceil(50000/64)
#define NCHUNK 196   // ceil(50000/256)

typedef _Float16 f16;
typedef f16 f16x2 __attribute__((ext_vector_type(2)));
typedef f16 f16x4 __attribute__((ext_vector_type(4)));
typedef f16 f16x8 __attribute__((ext_vector_type(8)));
typedef float f32x4 __attribute__((ext_vector_type(4)));

__device__ __forceinline__ float lrelu(float x) { return x > 0.f ? x : NEG * x; }

// branch-free component select (head uniform per 16-lane group)
__device__ __forceinline__ float sel4(float4 v, int head) {
    float lo = (head & 1) ? v.y : v.x;
    float hi = (head & 1) ? v.w : v.z;
    return (head & 2) ? hi : lo;
}

// ---------------------------------------------------------------------------
// proj2 (MFMA): h = fp16(x @ W + b), fused attention-logit dots (fp32).
// 64 rows/block, 4 waves; A = x rows (fp16 LDS, row-major), B = W^T (fp16 LDS).
// mfma_f32_16x16x32_f16; C col=l&15, row=(l>>4)*4+reg (m89-verified layout).
// blocks [0,PBM) = tx, [PBM,2*PBM) = addr.
// ---------------------------------------------------------------------------
__global__ __launch_bounds__(256) void proj2_kernel(
    const float* __restrict__ x_tx, const float* __restrict__ W_tx,
    const float* __restrict__ b_tx, f16* __restrict__ h_tx,
    const float* __restrict__ x_ad, const float* __restrict__ W_ad,
    const float* __restrict__ b_ad, f16* __restrict__ h_ad,
    const float* __restrict__ a_dat, float* __restrict__ al_dat,
    const float* __restrict__ a_stt, float* __restrict__ al_stt,
    const float* __restrict__ a_dtt, float* __restrict__ al_dtt,
    const float* __restrict__ a_sat, float* __restrict__ al_sat)
{
    __shared__ f16 Wt[128][136];   // W^T, padded: 272 B row stride (16B-aligned)
    __shared__ f16 xt[MBLK][136];
    const bool is_tx = blockIdx.x < PBM;
    const float* x = is_tx ? x_tx : x_ad;
    const float* W = is_tx ? W_tx : W_ad;
    const float* b = is_tx ? b_tx : b_ad;
    f16* h         = is_tx ? h_tx : h_ad;
    const int row0 = (is_tx ? blockIdx.x : blockIdx.x - PBM) * MBLK;
    const int t = threadIdx.x;

    // stage W^T as fp16 (transpose during store, f16x4 vector stores)
    for (int i = t; i < 128 * 32; i += 256) {
        int jq = i >> 7, c = i & 127;
        f16x4 p = { (f16)W[(4 * jq + 0) * 128 + c], (f16)W[(4 * jq + 1) * 128 + c],
                    (f16)W[(4 * jq + 2) * 128 + c], (f16)W[(4 * jq + 3) * 128 + c] };
        *(f16x4*)&Wt[c][4 * jq] = p;
    }
    // stage x rows as fp16 (no transpose needed for A fragments)
    for (int i = t; i < MBLK * 32; i += 256) {
        int r = i >> 5, q = i & 31;
        int gr = row0 + r; if (gr >= NTX) gr = NTX - 1;
        float4 v = ((const float4*)x)[(size_t)gr * 32 + q];
        f16x4 p = {(f16)v.x, (f16)v.y, (f16)v.z, (f16)v.w};
        *(f16x4*)&xt[r][q * 4] = p;
    }
    __syncthreads();

    const int l = t & 63, w = t >> 6;
    const int l15 = l & 15, lq = l >> 4;

    f16x8 afrag[4];
#pragma unroll
    for (int kt = 0; kt < 4; kt++)
        afrag[kt] = *(const f16x8*)&xt[w * 16 + l15][kt * 32 + lq * 8];

    f32x4 acc[8];
#pragma unroll
    for (int n = 0; n < 8; n++) {
        float bc = b[n * 16 + l15];
        acc[n] = (f32x4){bc, bc, bc, bc};
#pragma unroll
        for (int kt = 0; kt < 4; kt++) {
            f16x8 bfrag = *(const f16x8*)&Wt[n * 16 + l15][kt * 32 + lq * 8];
            acc[n] = __builtin_amdgcn_mfma_f32_16x16x32_f16(afrag[kt], bfrag, acc[n], 0, 0, 0);
        }
    }

    // store h as fp16
#pragma unroll
    for (int r = 0; r < 4; r++) {
        int row = row0 + w * 16 + lq * 4 + r;
        if (row < NTX) {
#pragma unroll
            for (int n = 0; n < 8; n++)
                h[(size_t)row * 128 + n * 16 + l15] = (f16)acc[n][r];
        }
    }

    // attention-logit dots: al[row][head] = sum_c h[row][c]*a[c], head = c>>5
    auto do_dot = [&](const float* __restrict__ a, float* __restrict__ al) {
        float av[8];
#pragma unroll
        for (int n = 0; n < 8; n++) av[n] = a[n * 16 + l15];
#pragma unroll
        for (int r = 0; r < 4; r++) {
            float p0 = acc[0][r] * av[0] + acc[1][r] * av[1];
            float p1 = acc[2][r] * av[2] + acc[3][r] * av[3];
            float p2 = acc[4][r] * av[4] + acc[5][r] * av[5];
            float p3 = acc[6][r] * av[6] + acc[7][r] * av[7];
#pragma unroll
            for (int o = 1; o < 16; o <<= 1) {
                p0 += __shfl_xor(p0, o); p1 += __shfl_xor(p1, o);
                p2 += __shfl_xor(p2, o); p3 += __shfl_xor(p3, o);
            }
            int row = row0 + w * 16 + lq * 4 + r;
            if (l15 == 0 && row < NTX) {
                float4 v = make_float4(p0, p1, p2, p3);
                *(float4*)&al[(size_t)row * 4] = v;
            }
        }
    };
    if (is_tx) { do_dot(a_dat, al_dat); do_dot(a_stt, al_stt); do_dot(a_dtt, al_dtt); }
    else       { do_dot(a_sat, al_sat); }
}

// ---------------------------------------------------------------------------
// CSR build: degree -> (chunksum, chunkscan, scanwrite) -> fill(+exp)
// ---------------------------------------------------------------------------
__global__ __launch_bounds__(256) void deg2_kernel(
    const int* __restrict__ ei0, const int* __restrict__ ei1,
    int* __restrict__ deg0, int* __restrict__ deg1)
{
    int idx = blockIdx.x * 256 + threadIdx.x;
    if (idx < NE) atomicAdd(&deg0[ei0[NE + idx]], 1);
    else if (idx < 2 * NE) atomicAdd(&deg1[ei1[NE + (idx - NE)]], 1);
}

__global__ __launch_bounds__(256) void chunksum_kernel(
    const int* __restrict__ deg0, const int* __restrict__ deg1,
    int* __restrict__ csum)   // [2][NCHUNK]
{
    const int* deg = blockIdx.y == 0 ? deg0 : deg1;
    __shared__ int s[256];
    const int t = threadIdx.x;
    int idx = blockIdx.x * 256 + t;
    s[t] = idx < NTX ? deg[idx] : 0;
    __syncthreads();
    for (int o = 128; o > 0; o >>= 1) {
        if (t < o) s[t] += s[t + o];
        __syncthreads();
    }
    if (t == 0) csum[blockIdx.y * NCHUNK + blockIdx.x] = s[0];
}

__global__ __launch_bounds__(256) void chunkscan_kernel(int* __restrict__ csum)
{
    __shared__ int s[256];
    const int t = threadIdx.x;
    int* base = csum + blockIdx.x * NCHUNK;
    int v = t < NCHUNK ? base[t] : 0;
    s[t] = v;
    __syncthreads();
    for (int o = 1; o < 256; o <<= 1) {
        int u = (t >= o) ? s[t - o] : 0;
        __syncthreads();
        s[t] += u;
        __syncthreads();
    }
    if (t < NCHUNK) base[t] = s[t] - v;   // exclusive
}

__global__ __launch_bounds__(256) void scanwrite_kernel(
    const int* __restrict__ deg0, const int* __restrict__ deg1,
    const int* __restrict__ csum,
    int* __restrict__ row0, int* __restrict__ row1)
{
    const int* deg = blockIdx.y == 0 ? deg0 : deg1;
    int* row       = blockIdx.y == 0 ? row0 : row1;
    __shared__ int s[256];
    const int t = threadIdx.x;
    int idx = blockIdx.x * 256 + t;
    int v = idx < NTX ? deg[idx] : 0;
    s[t] = v;
    __syncthreads();
    for (int o = 1; o < 256; o <<= 1) {
        int u = (t >= o) ? s[t - o] : 0;
        __syncthreads();
        s[t] += u;
        __syncthreads();
    }
    if (idx < NTX)
        row[idx] = s[t] - v + csum[blockIdx.y * NCHUNK + blockIdx.x];
}

// fill CSR slots AND compute edge softmax numerators (4 heads) in CSR order.
__global__ __launch_bounds__(256) void fill2_kernel(
    const int* __restrict__ ei0, const int* __restrict__ row0,
    int* __restrict__ cur0, int* __restrict__ csr0,
    const float* __restrict__ als0, const float* __restrict__ ald0,
    float* __restrict__ ex0,
    const int* __restrict__ ei1, const int* __restrict__ row1,
    int* __restrict__ cur1, int* __restrict__ csr1,
    const float* __restrict__ als1, const float* __restrict__ ald1,
    float* __restrict__ ex1)
{
    int idx = blockIdx.x * 256 + threadIdx.x;
    const int* ei; const int* row; int* cur; int* csr;
    const float* als; const float* ald; float* ex;
    int e;
    if (idx < NE) {
        ei = ei0; row = row0; cur = cur0; csr = csr0;
        als = als0; ald = ald0; ex = ex0; e = idx;
    } else if (idx < 2 * NE) {
        ei = ei1; row = row1; cur = cur1; csr = csr1;
        als = als1; ald = ald1; ex = ex1; e = idx - NE;
    } else return;
    int s = ei[e];
    int d = ei[NE + e];
    int pos = row[d] + atomicAdd(&cur[d], 1);
    csr[pos] = s;
    float4 as = *(const float4*)(als + (size_t)s * 4);
    float4 ad = *(const float4*)(ald + (size_t)d * 4);
    float4 exv;
    exv.x = __expf(lrelu(as.x + ad.x));
    exv.y = __expf(lrelu(as.y + ad.y));
    exv.z = __expf(lrelu(as.z + ad.z));
    exv.w = __expf(lrelu(as.w + ad.w));
    *(float4*)&ex[(size_t)pos * 4] = exv;
}

// ---------------------------------------------------------------------------
// Gather GAT: ONE WAVE per dst (64 lanes x f16x2 = full 256B row / instr),
// 4 dsts per 256-thr block; both edge types via blockIdx.y.
// ex: one broadcast float4 load per edge + branch-free head select.
// ---------------------------------------------------------------------------
__global__ __launch_bounds__(256) void gat_gather2_kernel(
    const int* __restrict__ row_at, const int* __restrict__ deg_at,
    const int* __restrict__ csr_at, const float* __restrict__ ex_at,
    const f16* __restrict__ h_at, f16* __restrict__ out_at,
    const int* __restrict__ row_tt, const int* __restrict__ deg_tt,
    const int* __restrict__ csr_tt, const float* __restrict__ ex_tt,
    const f16* __restrict__ h_tt, f16* __restrict__ out_tt)
{
    const bool at = (blockIdx.y == 0);
    const int* rs = at ? row_at : row_tt;
    const int* dg = at ? deg_at : deg_tt;
    const int* cs = at ? csr_at : csr_tt;
    const float* ex = at ? ex_at : ex_tt;
    const f16* hsrc = at ? h_at : h_tt;
    f16* out = at ? out_at : out_tt;

    const int t = threadIdx.x;
    const int d = blockIdx.x * 4 + (t >> 6);
    if (d >= NTX) return;
    const int ln = t & 63;
    const int head = ln >> 4;          // channels 2ln, 2ln+1 share a head
    const int beg = rs[d];
    const int n = dg[d];

    float ax = 0.f, ay = 0.f, den = 0.f;
    int i = 0;
    for (; i + 4 <= n; i += 4) {
        int s0 = cs[beg + i], s1 = cs[beg + i + 1];
        int s2 = cs[beg + i + 2], s3 = cs[beg + i + 3];
        float4 e0 = *(const float4*)&ex[(size_t)(beg + i) * 4];
        float4 e1 = *(const float4*)&ex[(size_t)(beg + i + 1) * 4];
        float4 e2 = *(const float4*)&ex[(size_t)(beg + i + 2) * 4];
        float4 e3 = *(const float4*)&ex[(size_t)(beg + i + 3) * 4];
        f16x2 h0 = *(const f16x2*)&hsrc[(size_t)s0 * 128 + ln * 2];
        f16x2 h1 = *(const f16x2*)&hsrc[(size_t)s1 * 128 + ln * 2];
        f16x2 h2 = *(const f16x2*)&hsrc[(size_t)s2 * 128 + ln * 2];
        f16x2 h3 = *(const f16x2*)&hsrc[(size_t)s3 * 128 + ln * 2];
        float w0 = sel4(e0, head), w1 = sel4(e1, head);
        float w2 = sel4(e2, head), w3 = sel4(e3, head);
        den += (w0 + w1) + (w2 + w3);
        ax = fmaf(w0, (float)h0[0], fmaf(w1, (float)h1[0],
             fmaf(w2, (float)h2[0], fmaf(w3, (float)h3[0], ax))));
        ay = fmaf(w0, (float)h0[1], fmaf(w1, (float)h1[1],
             fmaf(w2, (float)h2[1], fmaf(w3, (float)h3[1], ay))));
    }
    for (; i < n; i++) {
        int s0 = cs[beg + i];
        float4 e0 = *(const float4*)&ex[(size_t)(beg + i) * 4];
        float w0 = sel4(e0, head);
        f16x2 h0 = *(const f16x2*)&hsrc[(size_t)s0 * 128 + ln * 2];
        den += w0;
        ax = fmaf(w0, (float)h0[0], ax);
        ay = fmaf(w0, (float)h0[1], ay);
    }
    float inv = 1.f / (den + 1e-16f);
    float vx = ax * inv, vy = ay * inv;
    f16x2 o = { (f16)(vx > 0.f ? vx : 0.f), (f16)(vy > 0.f ? vy : 0.f) };
    *(f16x2*)&out[(size_t)d * 128 + ln * 2] = o;
}

// ---------------------------------------------------------------------------
// tanh GEMM (MFMA, both metapaths via blockIdx.y):
// part[k][blk][c] = sum over 64-row tile of tanh((out_k @ Wk + bk))[.,c]
// ---------------------------------------------------------------------------
__global__ __launch_bounds__(256) void tanh_gemm_kernel(
    const f16* __restrict__ out_at, const f16* __restrict__ out_tt,
    const float* __restrict__ Wk, const float* __restrict__ bk,
    float* __restrict__ part)    // [2][PBM][128]
{
    __shared__ f16 Wt[128][136];
    __shared__ f16 xt[MBLK][136];
    const f16* src = (blockIdx.y == 0) ? out_at : out_tt;
    const int row0 = blockIdx.x * MBLK;
    const int t = threadIdx.x;

    for (int i = t; i < 128 * 32; i += 256) {
        int jq = i >> 7, c = i & 127;
        f16x4 p = { (f16)Wk[(4 * jq + 0) * 128 + c], (f16)Wk[(4 * jq + 1) * 128 + c],
                    (f16)Wk[(4 * jq + 2) * 128 + c], (f16)Wk[(4 * jq + 3) * 128 + c] };
        *(f16x4*)&Wt[c][4 * jq] = p;
    }
    for (int i = t; i < MBLK * 16; i += 256) {
        int r = i >> 4, q = i & 15;
        int gr = row0 + r; if (gr >= NTX) gr = NTX - 1;
        *(f16x8*)&xt[r][q * 8] = ((const f16x8*)src)[(size_t)gr * 16 + q];
    }
    __syncthreads();

    const int l = t & 63, w = t >> 6;
    const int l15 = l & 15, lq = l >> 4;

    f16x8 afrag[4];
#pragma unroll
    for (int kt = 0; kt < 4; kt++)
        afrag[kt] = *(const f16x8*)&xt[w * 16 + l15][kt * 32 + lq * 8];

    float pn[8];
#pragma unroll
    for (int n = 0; n < 8; n++) {
        float bc = bk[n * 16 + l15];
        f32x4 acc = (f32x4){bc, bc, bc, bc};
#pragma unroll
        for (int kt = 0; kt < 4; kt++) {
            f16x8 bfrag = *(const f16x8*)&Wt[n * 16 + l15][kt * 32 + lq * 8];
            acc = __builtin_amdgcn_mfma_f32_16x16x32_f16(afrag[kt], bfrag, acc, 0, 0, 0);
        }
        float s = 0.f;
#pragma unroll
        for (int r = 0; r < 4; r++) {
            int row = row0 + w * 16 + lq * 4 + r;
            if (row < NTX) s += tanhf(acc[r]);
        }
        s += __shfl_xor(s, 16);
        s += __shfl_xor(s, 32);
        pn[n] = s;                    // lanes 0-15 hold col sums for this wave
    }

    __syncthreads();                  // all waves done reading xt
    float* Sblk = (float*)&xt[0][0];  // reuse xt as [4][128] float
    if (l < 16) {
#pragma unroll
        for (int n = 0; n < 8; n++)
            Sblk[w * 128 + n * 16 + l15] = pn[n];
    }
    __syncthreads();
    if (t < 128)
        part[((size_t)blockIdx.y * PBM + blockIdx.x) * 128 + t] =
            Sblk[t] + Sblk[128 + t] + Sblk[256 + t] + Sblk[384 + t];
}

// ---------------------------------------------------------------------------
// reduce partials -> S_k[c]
// ---------------------------------------------------------------------------
__global__ __launch_bounds__(128) void reduceS_kernel(
    const float* __restrict__ part, float* __restrict__ S_at, float* __restrict__ S_tt)
{
    const int k = blockIdx.y;
    const int c = threadIdx.x;
    float* S = (k == 0) ? S_at : S_tt;
    const int b0 = blockIdx.x * 25;
    const int b1 = min(b0 + 25, PBM);
    float s = 0.f;
    for (int b = b0; b < b1; b++)
        s += part[((size_t)k * PBM + b) * 128 + c];
    atomicAdd(&S[c], s);
}

// ---------------------------------------------------------------------------
// attn: score_k = (q . S_k) / NTX; attn = softmax over k=2
// ---------------------------------------------------------------------------
__global__ __launch_bounds__(128) void attn_kernel(
    const float* __restrict__ S0, const float* __restrict__ S1,
    const float* __restrict__ q, float* __restrict__ attn)
{
    __shared__ float r0[128], r1[128];
    int c = threadIdx.x;
    r0[c] = q[c] * S0[c];
    r1[c] = q[c] * S1[c];
    __syncthreads();
    for (int s = 64; s > 0; s >>= 1) {
        if (c < s) { r0[c] += r0[c + s]; r1[c] += r1[c + s]; }
        __syncthreads();
    }
    if (c == 0) {
        float s0 = r0[0] / (float)NTX, s1 = r1[0] / (float)NTX;
        float m = fmaxf(s0, s1);
        float e0 = expf(s0 - m), e1 = expf(s1 - m);
        float inv = 1.f / (e0 + e1);
        attn[0] = e0 * inv;
        attn[1] = e1 * inv;
    }
}

// ---------------------------------------------------------------------------
// final_pool: batch is SORTED -> group g is a contiguous run [lo,hi).
// ---------------------------------------------------------------------------
__device__ __forceinline__ int lower_bound_g(const int* __restrict__ batch, int val)
{
    int lo = 0, hi = NTX;
    while (lo < hi) {
        int mid = (lo + hi) >> 1;
        if (batch[mid] < val) lo = mid + 1; else hi = mid;
    }
    return lo;
}

__global__ __launch_bounds__(128) void final_pool_kernel(
    const f16* __restrict__ out_at, const f16* __restrict__ out_tt,
    const int* __restrict__ batch, const float* __restrict__ attn,
    const float* __restrict__ Wl, const float* __restrict__ bl,
    float* __restrict__ out)
{
    __shared__ float r0[128], r1[128];
    const int g = blockIdx.x, c = threadIdx.x;
    const int lo = lower_bound_g(batch, g);
    const int hi = lower_bound_g(batch, g + 1);
    float s0 = 0.f, s1 = 0.f;
    for (int n = lo; n < hi; n++) {
        s0 += (float)out_at[(size_t)n * 128 + c];
        s1 += (float)out_tt[(size_t)n * 128 + c];
    }
    float pooled = (attn[0] * s0 + attn[1] * s1) / fmaxf((float)(hi - lo), 1.f);
    r0[c] = pooled * Wl[c * 2 + 0];
    r1[c] = pooled * Wl[c * 2 + 1];
    __syncthreads();
    for (int s = 64; s > 0; s >>= 1) {
        if (c < s) { r0[c] += r0[c + s]; r1[c] += r1[c + s]; }
        __syncthreads();
    }
    if (c == 0) {
        out[g * 2 + 0] = r0[0] + bl[0];
        out[g * 2 + 1] = r1[0] + bl[1];
    }
}

// ---------------------------------------------------------------------------
extern "C" void kernel_launch(void* const* d_in, const int* in_sizes, int n_in,
                              void* d_out, int out_size, void* d_ws, size_t ws_size,
                              hipStream_t stream)
{
    const float* x_tx     = (const float*)d_in[0];
    const float* x_ad     = (const float*)d_in[1];
    // d_in[2] = ei_ta (dead: out_ta never consumed)
    const int*   ei_at    = (const int*)d_in[3];
    const int*   ei_tt    = (const int*)d_in[4];
    const int*   batch    = (const int*)d_in[5];
    const float* W_tx     = (const float*)d_in[6];
    const float* b_tx     = (const float*)d_in[7];
    const float* W_ad     = (const float*)d_in[8];
    const float* b_ad     = (const float*)d_in[9];
    // d_in[10], d_in[11] = a_src_ta, a_dst_ta (dead)
    const float* a_src_at = (const float*)d_in[12];
    const float* a_dst_at = (const float*)d_in[13];
    const float* a_src_tt = (const float*)d_in[14];
    const float* a_dst_tt = (const float*)d_in[15];
    const float* Wk       = (const float*)d_in[16];
    const float* bk       = (const float*)d_in[17];
    const float* q        = (const float*)d_in[18];
    const float* Wl       = (const float*)d_in[19];
    const float* bl       = (const float*)d_in[20];
    float* out = (float*)d_out;

    char* ws = (char*)d_ws;
    size_t off = 0;
    auto alloc = [&](size_t bytes) -> void* {
        void* p = ws + off;
        off += (bytes + 255) & ~(size_t)255;
        return p;
    };
    f16* h_tx      = (f16*)alloc((size_t)NTX * 128 * 2);
    f16* h_ad      = (f16*)alloc((size_t)NADDR * 128 * 2);
    float* al_sat  = (float*)alloc((size_t)NADDR * 4 * 4);
    float* al_dat  = (float*)alloc((size_t)NTX * 4 * 4);
    float* al_stt  = (float*)alloc((size_t)NTX * 4 * 4);
    float* al_dtt  = (float*)alloc((size_t)NTX * 4 * 4);
    f16* out_at    = (f16*)alloc((size_t)NTX * 128 * 2);   // fully written by gather
    f16* out_tt    = (f16*)alloc((size_t)NTX * 128 * 2);
    int* csr_at    = (int*)alloc((size_t)NE * 4);
    int* csr_tt    = (int*)alloc((size_t)NE * 4);
    float* ex_at   = (float*)alloc((size_t)NE * 4 * 4);    // CSR-ordered, 4 heads
    float* ex_tt   = (float*)alloc((size_t)NE * 4 * 4);
    int* row_at    = (int*)alloc((size_t)NTX * 4);
    int* row_tt    = (int*)alloc((size_t)NTX * 4);
    int* csum      = (int*)alloc((size_t)2 * NCHUNK * 4);
    float* part    = (float*)alloc((size_t)2 * PBM * 128 * 4);
    // ---- zeroed region (counters / S accumulators) ----
    char* zero0 = ws + off;
    int* deg_at    = (int*)alloc((size_t)NTX * 4);
    int* deg_tt    = (int*)alloc((size_t)NTX * 4);
    int* cur_at    = (int*)alloc((size_t)NTX * 4);
    int* cur_tt    = (int*)alloc((size_t)NTX * 4);
    float* S_at    = (float*)alloc(128 * 4);
    float* S_tt    = (float*)alloc(128 * 4);
    size_t zbytes = (size_t)((ws + off) - zero0);
    float* attnw   = (float*)alloc(2 * 4);

    hipMemsetAsync(zero0, 0, zbytes, stream);

    // projections + attention-logit dots (MFMA, both node types, one dispatch)
    proj2_kernel<<<2 * PBM, 256, 0, stream>>>(
        x_tx, W_tx, b_tx, h_tx, x_ad, W_ad, b_ad, h_ad,
        a_dst_at, al_dat, a_src_tt, al_stt, a_dst_tt, al_dtt,
        a_src_at, al_sat);

    // CSR build (dst-major), both edge types per dispatch
    int eb2 = (2 * NE + 255) / 256;
    deg2_kernel<<<eb2, 256, 0, stream>>>(ei_at, ei_tt, deg_at, deg_tt);
    dim3 sgrid(NCHUNK, 2);
    chunksum_kernel<<<sgrid, 256, 0, stream>>>(deg_at, deg_tt, csum);
    chunkscan_kernel<<<2, 256, 0, stream>>>(csum);
    scanwrite_kernel<<<sgrid, 256, 0, stream>>>(deg_at, deg_tt, csum, row_at, row_tt);
    fill2_kernel<<<eb2, 256, 0, stream>>>(
        ei_at, row_at, cur_at, csr_at, al_sat, al_dat, ex_at,
        ei_tt, row_tt, cur_tt, csr_tt, al_stt, al_dtt, ex_tt);

    // gather-style GAT: 1 wave/dst, 4 dsts per block
    dim3 ggrid((NTX + 3) / 4, 2);
    gat_gather2_kernel<<<ggrid, 256, 0, stream>>>(
        row_at, deg_at, csr_at, ex_at, h_ad, out_at,
        row_tt, deg_tt, csr_tt, ex_tt, h_tx, out_tt);

    // semantic attention: MFMA tanh GEMM partials -> reduce -> softmax over 2
    dim3 tgrid(PBM, 2);
    tanh_gemm_kernel<<<tgrid, 256, 0, stream>>>(out_at, out_tt, Wk, bk, part);
    dim3 rgrid(32, 2);
    reduceS_kernel<<<rgrid, 128, 0, stream>>>(part, S_at, S_tt);
    attn_kernel<<<1, 128, 0, stream>>>(S_at, S_tt, q, attnw);

    // fused pooling (sorted batch -> contiguous runs) + final linear
    final_pool_kernel<<<GG, 128, 0, stream>>>(out_at, out_tt, batch, attnw, Wl, bl, out);
}

// Round 9
// 272.044 us; speedup vs baseline: 8.2476x; 1.0411x over previous
//
#include <hip/hip_runtime.h>

#define NTX   50000
#define NADDR 50000
#define NE    500000
#define GG    512
#define NEG   0.2f
#define MBLK  64
#define PBM   782    // ceil(50000/64)
#define NCHUNK 196   // ceil(50000/256)

typedef _Float16 f16;
typedef f16 f16x4 __attribute__((ext_vector_type(4)));
typedef f16 f16x8 __attribute__((ext_vector_type(8)));
typedef float f32x4 __attribute__((ext_vector_type(4)));

__device__ __forceinline__ float lrelu(float x) { return x > 0.f ? x : NEG * x; }

// branch-free component select (head uniform per lane)
__device__ __forceinline__ float sel4(float4 v, int head) {
    float lo = (head & 1) ? v.y : v.x;
    float hi = (head & 1) ? v.w : v.z;
    return (head & 2) ? hi : lo;
}

// ---------------------------------------------------------------------------
// proj2 (MFMA): h = fp16(x @ W + b), fused attention-logit dots (fp32).
// 64 rows/block, 4 waves; A = x rows (fp16 LDS), B = W^T (fp16 LDS).
// mfma_f32_16x16x32_f16; C col=l&15, row=(l>>4)*4+reg (m89-verified layout).
// blocks [0,PBM) = tx, [PBM,2*PBM) = addr.
// ---------------------------------------------------------------------------
__global__ __launch_bounds__(256) void proj2_kernel(
    const float* __restrict__ x_tx, const float* __restrict__ W_tx,
    const float* __restrict__ b_tx, f16* __restrict__ h_tx,
    const float* __restrict__ x_ad, const float* __restrict__ W_ad,
    const float* __restrict__ b_ad, f16* __restrict__ h_ad,
    const float* __restrict__ a_dat, float* __restrict__ al_dat,
    const float* __restrict__ a_stt, float* __restrict__ al_stt,
    const float* __restrict__ a_dtt, float* __restrict__ al_dtt,
    const float* __restrict__ a_sat, float* __restrict__ al_sat)
{
    __shared__ f16 Wt[128][136];   // W^T, padded: 272 B row stride (16B-aligned)
    __shared__ f16 xt[MBLK][136];
    const bool is_tx = blockIdx.x < PBM;
    const float* x = is_tx ? x_tx : x_ad;
    const float* W = is_tx ? W_tx : W_ad;
    const float* b = is_tx ? b_tx : b_ad;
    f16* h         = is_tx ? h_tx : h_ad;
    const int row0 = (is_tx ? blockIdx.x : blockIdx.x - PBM) * MBLK;
    const int t = threadIdx.x;

    // stage W^T as fp16 (transpose during store, f16x4 vector stores)
    for (int i = t; i < 128 * 32; i += 256) {
        int jq = i >> 7, c = i & 127;
        f16x4 p = { (f16)W[(4 * jq + 0) * 128 + c], (f16)W[(4 * jq + 1) * 128 + c],
                    (f16)W[(4 * jq + 2) * 128 + c], (f16)W[(4 * jq + 3) * 128 + c] };
        *(f16x4*)&Wt[c][4 * jq] = p;
    }
    // stage x rows as fp16 (no transpose needed for A fragments)
    for (int i = t; i < MBLK * 32; i += 256) {
        int r = i >> 5, q = i & 31;
        int gr = row0 + r; if (gr >= NTX) gr = NTX - 1;
        float4 v = ((const float4*)x)[(size_t)gr * 32 + q];
        f16x4 p = {(f16)v.x, (f16)v.y, (f16)v.z, (f16)v.w};
        *(f16x4*)&xt[r][q * 4] = p;
    }
    __syncthreads();

    const int l = t & 63, w = t >> 6;
    const int l15 = l & 15, lq = l >> 4;

    f16x8 afrag[4];
#pragma unroll
    for (int kt = 0; kt < 4; kt++)
        afrag[kt] = *(const f16x8*)&xt[w * 16 + l15][kt * 32 + lq * 8];

    f32x4 acc[8];
#pragma unroll
    for (int n = 0; n < 8; n++) {
        float bc = b[n * 16 + l15];
        acc[n] = (f32x4){bc, bc, bc, bc};
#pragma unroll
        for (int kt = 0; kt < 4; kt++) {
            f16x8 bfrag = *(const f16x8*)&Wt[n * 16 + l15][kt * 32 + lq * 8];
            acc[n] = __builtin_amdgcn_mfma_f32_16x16x32_f16(afrag[kt], bfrag, acc[n], 0, 0, 0);
        }
    }

    // store h as fp16
#pragma unroll
    for (int r = 0; r < 4; r++) {
        int row = row0 + w * 16 + lq * 4 + r;
        if (row < NTX) {
#pragma unroll
            for (int n = 0; n < 8; n++)
                h[(size_t)row * 128 + n * 16 + l15] = (f16)acc[n][r];
        }
    }

    // attention-logit dots: al[row][head] = sum_c h[row][c]*a[c], head = c>>5
    auto do_dot = [&](const float* __restrict__ a, float* __restrict__ al) {
        float av[8];
#pragma unroll
        for (int n = 0; n < 8; n++) av[n] = a[n * 16 + l15];
#pragma unroll
        for (int r = 0; r < 4; r++) {
            float p0 = acc[0][r] * av[0] + acc[1][r] * av[1];
            float p1 = acc[2][r] * av[2] + acc[3][r] * av[3];
            float p2 = acc[4][r] * av[4] + acc[5][r] * av[5];
            float p3 = acc[6][r] * av[6] + acc[7][r] * av[7];
#pragma unroll
            for (int o = 1; o < 16; o <<= 1) {
                p0 += __shfl_xor(p0, o); p1 += __shfl_xor(p1, o);
                p2 += __shfl_xor(p2, o); p3 += __shfl_xor(p3, o);
            }
            int row = row0 + w * 16 + lq * 4 + r;
            if (l15 == 0 && row < NTX) {
                float4 v = make_float4(p0, p1, p2, p3);
                *(float4*)&al[(size_t)row * 4] = v;
            }
        }
    };
    if (is_tx) { do_dot(a_dat, al_dat); do_dot(a_stt, al_stt); do_dot(a_dtt, al_dtt); }
    else       { do_dot(a_sat, al_sat); }
}

// ---------------------------------------------------------------------------
// CSR build: degree -> (chunksum, chunkscan, scanwrite) -> fill(+exp)
// ---------------------------------------------------------------------------
__global__ __launch_bounds__(256) void deg2_kernel(
    const int* __restrict__ ei0, const int* __restrict__ ei1,
    int* __restrict__ deg0, int* __restrict__ deg1)
{
    int idx = blockIdx.x * 256 + threadIdx.x;
    if (idx < NE) atomicAdd(&deg0[ei0[NE + idx]], 1);
    else if (idx < 2 * NE) atomicAdd(&deg1[ei1[NE + (idx - NE)]], 1);
}

__global__ __launch_bounds__(256) void chunksum_kernel(
    const int* __restrict__ deg0, const int* __restrict__ deg1,
    int* __restrict__ csum)   // [2][NCHUNK]
{
    const int* deg = blockIdx.y == 0 ? deg0 : deg1;
    __shared__ int s[256];
    const int t = threadIdx.x;
    int idx = blockIdx.x * 256 + t;
    s[t] = idx < NTX ? deg[idx] : 0;
    __syncthreads();
    for (int o = 128; o > 0; o >>= 1) {
        if (t < o) s[t] += s[t + o];
        __syncthreads();
    }
    if (t == 0) csum[blockIdx.y * NCHUNK + blockIdx.x] = s[0];
}

__global__ __launch_bounds__(256) void chunkscan_kernel(int* __restrict__ csum)
{
    __shared__ int s[256];
    const int t = threadIdx.x;
    int* base = csum + blockIdx.x * NCHUNK;
    int v = t < NCHUNK ? base[t] : 0;
    s[t] = v;
    __syncthreads();
    for (int o = 1; o < 256; o <<= 1) {
        int u = (t >= o) ? s[t - o] : 0;
        __syncthreads();
        s[t] += u;
        __syncthreads();
    }
    if (t < NCHUNK) base[t] = s[t] - v;   // exclusive
}

__global__ __launch_bounds__(256) void scanwrite_kernel(
    const int* __restrict__ deg0, const int* __restrict__ deg1,
    const int* __restrict__ csum,
    int* __restrict__ row0, int* __restrict__ row1)
{
    const int* deg = blockIdx.y == 0 ? deg0 : deg1;
    int* row       = blockIdx.y == 0 ? row0 : row1;
    __shared__ int s[256];
    const int t = threadIdx.x;
    int idx = blockIdx.x * 256 + t;
    int v = idx < NTX ? deg[idx] : 0;
    s[t] = v;
    __syncthreads();
    for (int o = 1; o < 256; o <<= 1) {
        int u = (t >= o) ? s[t - o] : 0;
        __syncthreads();
        s[t] += u;
        __syncthreads();
    }
    if (idx < NTX)
        row[idx] = s[t] - v + csum[blockIdx.y * NCHUNK + blockIdx.x];
}

// fill CSR slots AND compute edge softmax numerators (4 heads) in CSR order.
__global__ __launch_bounds__(256) void fill2_kernel(
    const int* __restrict__ ei0, const int* __restrict__ row0,
    int* __restrict__ cur0, int* __restrict__ csr0,
    const float* __restrict__ als0, const float* __restrict__ ald0,
    float* __restrict__ ex0,
    const int* __restrict__ ei1, const int* __restrict__ row1,
    int* __restrict__ cur1, int* __restrict__ csr1,
    const float* __restrict__ als1, const float* __restrict__ ald1,
    float* __restrict__ ex1)
{
    int idx = blockIdx.x * 256 + threadIdx.x;
    const int* ei; const int* row; int* cur; int* csr;
    const float* als; const float* ald; float* ex;
    int e;
    if (idx < NE) {
        ei = ei0; row = row0; cur = cur0; csr = csr0;
        als = als0; ald = ald0; ex = ex0; e = idx;
    } else if (idx < 2 * NE) {
        ei = ei1; row = row1; cur = cur1; csr = csr1;
        als = als1; ald = ald1; ex = ex1; e = idx - NE;
    } else return;
    int s = ei[e];
    int d = ei[NE + e];
    int pos = row[d] + atomicAdd(&cur[d], 1);
    csr[pos] = s;
    float4 as = *(const float4*)(als + (size_t)s * 4);
    float4 ad = *(const float4*)(ald + (size_t)d * 4);
    float4 exv;
    exv.x = __expf(lrelu(as.x + ad.x));
    exv.y = __expf(lrelu(as.y + ad.y));
    exv.z = __expf(lrelu(as.z + ad.z));
    exv.w = __expf(lrelu(as.w + ad.w));
    *(float4*)&ex[(size_t)pos * 4] = exv;
}

// ---------------------------------------------------------------------------
// Gather GAT: 16 lanes per dst (f16x8/lane = 256B row per group), 4 dsts/wave,
// 16 dsts per 256-thr block; both edge types via blockIdx.y.
// One VMEM h-load instruction serves 4 edges (4 groups in parallel).
// ---------------------------------------------------------------------------
__global__ __launch_bounds__(256) void gat_gather2_kernel(
    const int* __restrict__ row_at, const int* __restrict__ deg_at,
    const int* __restrict__ csr_at, const float* __restrict__ ex_at,
    const f16* __restrict__ h_at, f16* __restrict__ out_at,
    const int* __restrict__ row_tt, const int* __restrict__ deg_tt,
    const int* __restrict__ csr_tt, const float* __restrict__ ex_tt,
    const f16* __restrict__ h_tt, f16* __restrict__ out_tt)
{
    const bool at = (blockIdx.y == 0);
    const int* rs = at ? row_at : row_tt;
    const int* dg = at ? deg_at : deg_tt;
    const int* cs = at ? csr_at : csr_tt;
    const float* ex = at ? ex_at : ex_tt;
    const f16* hsrc = at ? h_at : h_tt;
    f16* out = at ? out_at : out_tt;

    const int t = threadIdx.x;
    const int d = blockIdx.x * 16 + (t >> 4);   // 16 dsts/block, uniform per 16-lane grp
    const int ln8 = t & 15;                     // chunk: channels [ln8*8, ln8*8+8)
    const int head = ln8 >> 2;
    const int beg = rs[d];
    const int n = dg[d];
    const f16x8* H = (const f16x8*)hsrc;

    float acc[8] = {0.f, 0.f, 0.f, 0.f, 0.f, 0.f, 0.f, 0.f};
    float den = 0.f;
    int i = 0;
    for (; i + 2 <= n; i += 2) {
        int s0 = cs[beg + i], s1 = cs[beg + i + 1];
        float4 e0 = *(const float4*)&ex[(size_t)(beg + i) * 4];
        float4 e1 = *(const float4*)&ex[(size_t)(beg + i + 1) * 4];
        f16x8 h0 = H[(size_t)s0 * 16 + ln8];
        f16x8 h1 = H[(size_t)s1 * 16 + ln8];
        float w0 = sel4(e0, head), w1 = sel4(e1, head);
        den += w0 + w1;
#pragma unroll
        for (int j = 0; j < 8; j++)
            acc[j] = fmaf(w0, (float)h0[j], fmaf(w1, (float)h1[j], acc[j]));
    }
    if (i < n) {
        int s0 = cs[beg + i];
        float4 e0 = *(const float4*)&ex[(size_t)(beg + i) * 4];
        f16x8 h0 = H[(size_t)s0 * 16 + ln8];
        float w0 = sel4(e0, head);
        den += w0;
#pragma unroll
        for (int j = 0; j < 8; j++)
            acc[j] = fmaf(w0, (float)h0[j], acc[j]);
    }
    float inv = 1.f / (den + 1e-16f);
    f16x8 o;
#pragma unroll
    for (int j = 0; j < 8; j++) {
        float v = acc[j] * inv;
        o[j] = (f16)(v > 0.f ? v : 0.f);
    }
    ((f16x8*)out)[(size_t)d * 16 + ln8] = o;
}

// ---------------------------------------------------------------------------
// tanh GEMM (MFMA): BOTH metapaths per block -- Wk^T staged once.
// part[y][blk][c] = sum over 64-row tile of tanh((out_y @ Wk + bk))[.,c]
// ---------------------------------------------------------------------------
__global__ __launch_bounds__(256) void tanh_gemm_kernel(
    const f16* __restrict__ out_at, const f16* __restrict__ out_tt,
    const float* __restrict__ Wk, const float* __restrict__ bk,
    float* __restrict__ part)    // [2][PBM][128]
{
    __shared__ f16 Wt[128][136];
    __shared__ f16 xt[MBLK][136];
    const int row0 = blockIdx.x * MBLK;
    const int t = threadIdx.x;

    for (int i = t; i < 128 * 32; i += 256) {
        int jq = i >> 7, c = i & 127;
        f16x4 p = { (f16)Wk[(4 * jq + 0) * 128 + c], (f16)Wk[(4 * jq + 1) * 128 + c],
                    (f16)Wk[(4 * jq + 2) * 128 + c], (f16)Wk[(4 * jq + 3) * 128 + c] };
        *(f16x4*)&Wt[c][4 * jq] = p;
    }

    const int l = t & 63, w = t >> 6;
    const int l15 = l & 15, lq = l >> 4;

    for (int y = 0; y < 2; y++) {
        const f16* src = (y == 0) ? out_at : out_tt;
        __syncthreads();   // y=0: Wt ready later; y=1: Sblk reads done
        for (int i = t; i < MBLK * 16; i += 256) {
            int r = i >> 4, q = i & 15;
            int gr = row0 + r; if (gr >= NTX) gr = NTX - 1;
            *(f16x8*)&xt[r][q * 8] = ((const f16x8*)src)[(size_t)gr * 16 + q];
        }
        __syncthreads();   // xt (and Wt, first pass) staged

        f16x8 afrag[4];
#pragma unroll
        for (int kt = 0; kt < 4; kt++)
            afrag[kt] = *(const f16x8*)&xt[w * 16 + l15][kt * 32 + lq * 8];

        float pn[8];
#pragma unroll
        for (int n = 0; n < 8; n++) {
            float bc = bk[n * 16 + l15];
            f32x4 acc = (f32x4){bc, bc, bc, bc};
#pragma unroll
            for (int kt = 0; kt < 4; kt++) {
                f16x8 bfrag = *(const f16x8*)&Wt[n * 16 + l15][kt * 32 + lq * 8];
                acc = __builtin_amdgcn_mfma_f32_16x16x32_f16(afrag[kt], bfrag, acc, 0, 0, 0);
            }
            float s = 0.f;
#pragma unroll
            for (int r = 0; r < 4; r++) {
                int row = row0 + w * 16 + lq * 4 + r;
                if (row < NTX) s += tanhf(acc[r]);
            }
            s += __shfl_xor(s, 16);
            s += __shfl_xor(s, 32);
            pn[n] = s;
        }

        __syncthreads();                  // all waves done reading xt
        float* Sblk = (float*)&xt[0][0];  // reuse xt as [4][128] float
        if (l < 16) {
#pragma unroll
            for (int n = 0; n < 8; n++)
                Sblk[w * 128 + n * 16 + l15] = pn[n];
        }
        __syncthreads();
        if (t < 128)
            part[((size_t)y * PBM + blockIdx.x) * 128 + t] =
                Sblk[t] + Sblk[128 + t] + Sblk[256 + t] + Sblk[384 + t];
    }
}

// ---------------------------------------------------------------------------
// reduce partials -> S_k[c]
// ---------------------------------------------------------------------------
__global__ __launch_bounds__(128) void reduceS_kernel(
    const float* __restrict__ part, float* __restrict__ S_at, float* __restrict__ S_tt)
{
    const int k = blockIdx.y;
    const int c = threadIdx.x;
    float* S = (k == 0) ? S_at : S_tt;
    const int b0 = blockIdx.x * 25;
    const int b1 = min(b0 + 25, PBM);
    float s = 0.f;
    for (int b = b0; b < b1; b++)
        s += part[((size_t)k * PBM + b) * 128 + c];
    atomicAdd(&S[c], s);
}

// ---------------------------------------------------------------------------
// attn: score_k = (q . S_k) / NTX; attn = softmax over k=2
// ---------------------------------------------------------------------------
__global__ __launch_bounds__(128) void attn_kernel(
    const float* __restrict__ S0, const float* __restrict__ S1,
    const float* __restrict__ q, float* __restrict__ attn)
{
    __shared__ float r0[128], r1[128];
    int c = threadIdx.x;
    r0[c] = q[c] * S0[c];
    r1[c] = q[c] * S1[c];
    __syncthreads();
    for (int s = 64; s > 0; s >>= 1) {
        if (c < s) { r0[c] += r0[c + s]; r1[c] += r1[c + s]; }
        __syncthreads();
    }
    if (c == 0) {
        float s0 = r0[0] / (float)NTX, s1 = r1[0] / (float)NTX;
        float m = fmaxf(s0, s1);
        float e0 = expf(s0 - m), e1 = expf(s1 - m);
        float inv = 1.f / (e0 + e1);
        attn[0] = e0 * inv;
        attn[1] = e1 * inv;
    }
}

// ---------------------------------------------------------------------------
// final_pool: batch is SORTED -> group g is a contiguous run [lo,hi).
// ---------------------------------------------------------------------------
__device__ __forceinline__ int lower_bound_g(const int* __restrict__ batch, int val)
{
    int lo = 0, hi = NTX;
    while (lo < hi) {
        int mid = (lo + hi) >> 1;
        if (batch[mid] < val) lo = mid + 1; else hi = mid;
    }
    return lo;
}

__global__ __launch_bounds__(128) void final_pool_kernel(
    const f16* __restrict__ out_at, const f16* __restrict__ out_tt,
    const int* __restrict__ batch, const float* __restrict__ attn,
    const float* __restrict__ Wl, const float* __restrict__ bl,
    float* __restrict__ out)
{
    __shared__ float r0[128], r1[128];
    const int g = blockIdx.x, c = threadIdx.x;
    const int lo = lower_bound_g(batch, g);
    const int hi = lower_bound_g(batch, g + 1);
    float s0 = 0.f, s1 = 0.f;
    for (int n = lo; n < hi; n++) {
        s0 += (float)out_at[(size_t)n * 128 + c];
        s1 += (float)out_tt[(size_t)n * 128 + c];
    }
    float pooled = (attn[0] * s0 + attn[1] * s1) / fmaxf((float)(hi - lo), 1.f);
    r0[c] = pooled * Wl[c * 2 + 0];
    r1[c] = pooled * Wl[c * 2 + 1];
    __syncthreads();
    for (int s = 64; s > 0; s >>= 1) {
        if (c < s) { r0[c] += r0[c + s]; r1[c] += r1[c + s]; }
        __syncthreads();
    }
    if (c == 0) {
        out[g * 2 + 0] = r0[0] + bl[0];
        out[g * 2 + 1] = r1[0] + bl[1];
    }
}

// ---------------------------------------------------------------------------
extern "C" void kernel_launch(void* const* d_in, const int* in_sizes, int n_in,
                              void* d_out, int out_size, void* d_ws, size_t ws_size,
                              hipStream_t stream)
{
    const float* x_tx     = (const float*)d_in[0];
    const float* x_ad     = (const float*)d_in[1];
    // d_in[2] = ei_ta (dead: out_ta never consumed)
    const int*   ei_at    = (const int*)d_in[3];
    const int*   ei_tt    = (const int*)d_in[4];
    const int*   batch    = (const int*)d_in[5];
    const float* W_tx     = (const float*)d_in[6];
    const float* b_tx     = (const float*)d_in[7];
    const float* W_ad     = (const float*)d_in[8];
    const float* b_ad     = (const float*)d_in[9];
    // d_in[10], d_in[11] = a_src_ta, a_dst_ta (dead)
    const float* a_src_at = (const float*)d_in[12];
    const float* a_dst_at = (const float*)d_in[13];
    const float* a_src_tt = (const float*)d_in[14];
    const float* a_dst_tt = (const float*)d_in[15];
    const float* Wk       = (const float*)d_in[16];
    const float* bk       = (const float*)d_in[17];
    const float* q        = (const float*)d_in[18];
    const float* Wl       = (const float*)d_in[19];
    const float* bl       = (const float*)d_in[20];
    float* out = (float*)d_out;

    char* ws = (char*)d_ws;
    size_t off = 0;
    auto alloc = [&](size_t bytes) -> void* {
        void* p = ws + off;
        off += (bytes + 255) & ~(size_t)255;
        return p;
    };
    f16* h_tx      = (f16*)alloc((size_t)NTX * 128 * 2);
    f16* h_ad      = (f16*)alloc((size_t)NADDR * 128 * 2);
    float* al_sat  = (float*)alloc((size_t)NADDR * 4 * 4);
    float* al_dat  = (float*)alloc((size_t)NTX * 4 * 4);
    float* al_stt  = (float*)alloc((size_t)NTX * 4 * 4);
    float* al_dtt  = (float*)alloc((size_t)NTX * 4 * 4);
    f16* out_at    = (f16*)alloc((size_t)NTX * 128 * 2);   // fully written by gather
    f16* out_tt    = (f16*)alloc((size_t)NTX * 128 * 2);
    int* csr_at    = (int*)alloc((size_t)NE * 4);
    int* csr_tt    = (int*)alloc((size_t)NE * 4);
    float* ex_at   = (float*)alloc((size_t)NE * 4 * 4);    // CSR-ordered, 4 heads
    float* ex_tt   = (float*)alloc((size_t)NE * 4 * 4);
    int* row_at    = (int*)alloc((size_t)NTX * 4);
    int* row_tt    = (int*)alloc((size_t)NTX * 4);
    int* csum      = (int*)alloc((size_t)2 * NCHUNK * 4);
    float* part    = (float*)alloc((size_t)2 * PBM * 128 * 4);
    // ---- zeroed region (counters / S accumulators) ----
    char* zero0 = ws + off;
    int* deg_at    = (int*)alloc((size_t)NTX * 4);
    int* deg_tt    = (int*)alloc((size_t)NTX * 4);
    int* cur_at    = (int*)alloc((size_t)NTX * 4);
    int* cur_tt    = (int*)alloc((size_t)NTX * 4);
    float* S_at    = (float*)alloc(128 * 4);
    float* S_tt    = (float*)alloc(128 * 4);
    size_t zbytes = (size_t)((ws + off) - zero0);
    float* attnw   = (float*)alloc(2 * 4);

    hipMemsetAsync(zero0, 0, zbytes, stream);

    // projections + attention-logit dots (MFMA, both node types, one dispatch)
    proj2_kernel<<<2 * PBM, 256, 0, stream>>>(
        x_tx, W_tx, b_tx, h_tx, x_ad, W_ad, b_ad, h_ad,
        a_dst_at, al_dat, a_src_tt, al_stt, a_dst_tt, al_dtt,
        a_src_at, al_sat);

    // CSR build (dst-major), both edge types per dispatch
    int eb2 = (2 * NE + 255) / 256;
    deg2_kernel<<<eb2, 256, 0, stream>>>(ei_at, ei_tt, deg_at, deg_tt);
    dim3 sgrid(NCHUNK, 2);
    chunksum_kernel<<<sgrid, 256, 0, stream>>>(deg_at, deg_tt, csum);
    chunkscan_kernel<<<2, 256, 0, stream>>>(csum);
    scanwrite_kernel<<<sgrid, 256, 0, stream>>>(deg_at, deg_tt, csum, row_at, row_tt);
    fill2_kernel<<<eb2, 256, 0, stream>>>(
        ei_at, row_at, cur_at, csr_at, al_sat, al_dat, ex_at,
        ei_tt, row_tt, cur_tt, csr_tt, al_stt, al_dtt, ex_tt);

    // gather-style GAT: 16 lanes/dst, 16 dsts per block (50000 = 3125*16)
    dim3 ggrid(NTX / 16, 2);
    gat_gather2_kernel<<<ggrid, 256, 0, stream>>>(
        row_at, deg_at, csr_at, ex_at, h_ad, out_at,
        row_tt, deg_tt, csr_tt, ex_tt, h_tx, out_tt);

    // semantic attention: MFMA tanh GEMM (both metapaths/block) -> reduce -> softmax
    tanh_gemm_kernel<<<PBM, 256, 0, stream>>>(out_at, out_tt, Wk, bk, part);
    dim3 rgrid(32, 2);
    reduceS_kernel<<<rgrid, 128, 0, stream>>>(part, S_at, S_tt);
    attn_kernel<<<1, 128, 0, stream>>>(S_at, S_tt, q, attnw);

    // fused pooling (sorted batch -> contiguous runs) + final linear
    final_pool_kernel<<<GG, 128, 0, stream>>>(out_at, out_tt, batch, attnw, Wl, bl, out);
}

// Round 10
// 266.358 us; speedup vs baseline: 8.4237x; 1.0213x over previous
//
#include <hip/hip_runtime.h>

#define NTX   50000
#define NADDR 50000
#define NE    500000
#define GG    512
#define NEG   0.2f
#define MBLK  64
#define PBM   782    // ceil(50000/64)
#define NCHUNK 196   // ceil(50000/256)

typedef _Float16 f16;
typedef f16 f16x4 __attribute__((ext_vector_type(4)));
typedef f16 f16x8 __attribute__((ext_vector_type(8)));
typedef float f32x4 __attribute__((ext_vector_type(4)));

__device__ __forceinline__ float lrelu(float x) { return x > 0.f ? x : NEG * x; }

// ---------------------------------------------------------------------------
// proj2 (MFMA): h = fp16(x @ W + b), fused attention-logit dots (fp32).
// 64 rows/block, 4 waves; A = x rows (fp16 LDS), B = W^T (fp16 LDS).
// mfma_f32_16x16x32_f16; C col=l&15, row=(l>>4)*4+reg (m89-verified layout).
// blocks [0,PBM) = tx, [PBM,2*PBM) = addr.
// ---------------------------------------------------------------------------
__global__ __launch_bounds__(256) void proj2_kernel(
    const float* __restrict__ x_tx, const float* __restrict__ W_tx,
    const float* __restrict__ b_tx, f16* __restrict__ h_tx,
    const float* __restrict__ x_ad, const float* __restrict__ W_ad,
    const float* __restrict__ b_ad, f16* __restrict__ h_ad,
    const float* __restrict__ a_dat, float* __restrict__ al_dat,
    const float* __restrict__ a_stt, float* __restrict__ al_stt,
    const float* __restrict__ a_dtt, float* __restrict__ al_dtt,
    const float* __restrict__ a_sat, float* __restrict__ al_sat)
{
    __shared__ f16 Wt[128][136];   // W^T, padded: 272 B row stride (16B-aligned)
    __shared__ f16 xt[MBLK][136];
    const bool is_tx = blockIdx.x < PBM;
    const float* x = is_tx ? x_tx : x_ad;
    const float* W = is_tx ? W_tx : W_ad;
    const float* b = is_tx ? b_tx : b_ad;
    f16* h         = is_tx ? h_tx : h_ad;
    const int row0 = (is_tx ? blockIdx.x : blockIdx.x - PBM) * MBLK;
    const int t = threadIdx.x;

    // stage W^T as fp16 (transpose during store, f16x4 vector stores)
    for (int i = t; i < 128 * 32; i += 256) {
        int jq = i >> 7, c = i & 127;
        f16x4 p = { (f16)W[(4 * jq + 0) * 128 + c], (f16)W[(4 * jq + 1) * 128 + c],
                    (f16)W[(4 * jq + 2) * 128 + c], (f16)W[(4 * jq + 3) * 128 + c] };
        *(f16x4*)&Wt[c][4 * jq] = p;
    }
    // stage x rows as fp16 (no transpose needed for A fragments)
    for (int i = t; i < MBLK * 32; i += 256) {
        int r = i >> 5, q = i & 31;
        int gr = row0 + r; if (gr >= NTX) gr = NTX - 1;
        float4 v = ((const float4*)x)[(size_t)gr * 32 + q];
        f16x4 p = {(f16)v.x, (f16)v.y, (f16)v.z, (f16)v.w};
        *(f16x4*)&xt[r][q * 4] = p;
    }
    __syncthreads();

    const int l = t & 63, w = t >> 6;
    const int l15 = l & 15, lq = l >> 4;

    f16x8 afrag[4];
#pragma unroll
    for (int kt = 0; kt < 4; kt++)
        afrag[kt] = *(const f16x8*)&xt[w * 16 + l15][kt * 32 + lq * 8];

    f32x4 acc[8];
#pragma unroll
    for (int n = 0; n < 8; n++) {
        float bc = b[n * 16 + l15];
        acc[n] = (f32x4){bc, bc, bc, bc};
#pragma unroll
        for (int kt = 0; kt < 4; kt++) {
            f16x8 bfrag = *(const f16x8*)&Wt[n * 16 + l15][kt * 32 + lq * 8];
            acc[n] = __builtin_amdgcn_mfma_f32_16x16x32_f16(afrag[kt], bfrag, acc[n], 0, 0, 0);
        }
    }

    // store h as fp16
#pragma unroll
    for (int r = 0; r < 4; r++) {
        int row = row0 + w * 16 + lq * 4 + r;
        if (row < NTX) {
#pragma unroll
            for (int n = 0; n < 8; n++)
                h[(size_t)row * 128 + n * 16 + l15] = (f16)acc[n][r];
        }
    }

    // attention-logit dots: al[row][head] = sum_c h[row][c]*a[c], head = c>>5
    auto do_dot = [&](const float* __restrict__ a, float* __restrict__ al) {
        float av[8];
#pragma unroll
        for (int n = 0; n < 8; n++) av[n] = a[n * 16 + l15];
#pragma unroll
        for (int r = 0; r < 4; r++) {
            float p0 = acc[0][r] * av[0] + acc[1][r] * av[1];
            float p1 = acc[2][r] * av[2] + acc[3][r] * av[3];
            float p2 = acc[4][r] * av[4] + acc[5][r] * av[5];
            float p3 = acc[6][r] * av[6] + acc[7][r] * av[7];
#pragma unroll
            for (int o = 1; o < 16; o <<= 1) {
                p0 += __shfl_xor(p0, o); p1 += __shfl_xor(p1, o);
                p2 += __shfl_xor(p2, o); p3 += __shfl_xor(p3, o);
            }
            int row = row0 + w * 16 + lq * 4 + r;
            if (l15 == 0 && row < NTX) {
                float4 v = make_float4(p0, p1, p2, p3);
                *(float4*)&al[(size_t)row * 4] = v;
            }
        }
    };
    if (is_tx) { do_dot(a_dat, al_dat); do_dot(a_stt, al_stt); do_dot(a_dtt, al_dtt); }
    else       { do_dot(a_sat, al_sat); }
}

// ---------------------------------------------------------------------------
// CSR build: degree -> (chunksum, chunkscan, scanwrite) -> fill(+exp)
// ---------------------------------------------------------------------------
__global__ __launch_bounds__(256) void deg2_kernel(
    const int* __restrict__ ei0, const int* __restrict__ ei1,
    int* __restrict__ deg0, int* __restrict__ deg1)
{
    int idx = blockIdx.x * 256 + threadIdx.x;
    if (idx < NE) atomicAdd(&deg0[ei0[NE + idx]], 1);
    else if (idx < 2 * NE) atomicAdd(&deg1[ei1[NE + (idx - NE)]], 1);
}

__global__ __launch_bounds__(256) void chunksum_kernel(
    const int* __restrict__ deg0, const int* __restrict__ deg1,
    int* __restrict__ csum)   // [2][NCHUNK]
{
    const int* deg = blockIdx.y == 0 ? deg0 : deg1;
    __shared__ int s[256];
    const int t = threadIdx.x;
    int idx = blockIdx.x * 256 + t;
    s[t] = idx < NTX ? deg[idx] : 0;
    __syncthreads();
    for (int o = 128; o > 0; o >>= 1) {
        if (t < o) s[t] += s[t + o];
        __syncthreads();
    }
    if (t == 0) csum[blockIdx.y * NCHUNK + blockIdx.x] = s[0];
}

__global__ __launch_bounds__(256) void chunkscan_kernel(int* __restrict__ csum)
{
    __shared__ int s[256];
    const int t = threadIdx.x;
    int* base = csum + blockIdx.x * NCHUNK;
    int v = t < NCHUNK ? base[t] : 0;
    s[t] = v;
    __syncthreads();
    for (int o = 1; o < 256; o <<= 1) {
        int u = (t >= o) ? s[t - o] : 0;
        __syncthreads();
        s[t] += u;
        __syncthreads();
    }
    if (t < NCHUNK) base[t] = s[t] - v;   // exclusive
}

// per-element exclusive scan + chunk offset; writes BOTH row (for gather)
// and cur (running cursor for fill) = same value.
__global__ __launch_bounds__(256) void scanwrite_kernel(
    const int* __restrict__ deg0, const int* __restrict__ deg1,
    const int* __restrict__ csum,
    int* __restrict__ row0, int* __restrict__ row1,
    int* __restrict__ cur0, int* __restrict__ cur1)
{
    const int* deg = blockIdx.y == 0 ? deg0 : deg1;
    int* row       = blockIdx.y == 0 ? row0 : row1;
    int* cur       = blockIdx.y == 0 ? cur0 : cur1;
    __shared__ int s[256];
    const int t = threadIdx.x;
    int idx = blockIdx.x * 256 + t;
    int v = idx < NTX ? deg[idx] : 0;
    s[t] = v;
    __syncthreads();
    for (int o = 1; o < 256; o <<= 1) {
        int u = (t >= o) ? s[t - o] : 0;
        __syncthreads();
        s[t] += u;
        __syncthreads();
    }
    if (idx < NTX) {
        int r = s[t] - v + csum[blockIdx.y * NCHUNK + blockIdx.x];
        row[idx] = r;
        cur[idx] = r;
    }
}

// fill: per edge, one atomic cursor bump + ONE unified 32B record write:
// rec[pos*8] = { as_float(src), ex0, ex1, ex2, ex3, ... }  (single dirty line)
__global__ __launch_bounds__(256) void fill2_kernel(
    const int* __restrict__ ei0, int* __restrict__ cur0, float* __restrict__ rec0,
    const float* __restrict__ als0, const float* __restrict__ ald0,
    const int* __restrict__ ei1, int* __restrict__ cur1, float* __restrict__ rec1,
    const float* __restrict__ als1, const float* __restrict__ ald1)
{
    int idx = blockIdx.x * 256 + threadIdx.x;
    const int* ei; int* cur; float* rec;
    const float* als; const float* ald;
    int e;
    if (idx < NE) {
        ei = ei0; cur = cur0; rec = rec0; als = als0; ald = ald0; e = idx;
    } else if (idx < 2 * NE) {
        ei = ei1; cur = cur1; rec = rec1; als = als1; ald = ald1; e = idx - NE;
    } else return;
    int s = ei[e];
    int d = ei[NE + e];
    int pos = atomicAdd(&cur[d], 1);
    float4 as = *(const float4*)(als + (size_t)s * 4);
    float4 ad = *(const float4*)(ald + (size_t)d * 4);
    float e0 = __expf(lrelu(as.x + ad.x));
    float e1 = __expf(lrelu(as.y + ad.y));
    float e2 = __expf(lrelu(as.z + ad.z));
    float e3 = __expf(lrelu(as.w + ad.w));
    float* r = rec + (size_t)pos * 8;
    *(float4*)r = make_float4(__int_as_float(s), e0, e1, e2);
    r[4] = e3;
}

// ---------------------------------------------------------------------------
// Gather GAT: 16 lanes per dst (f16x8/lane = 256B row per group), 4 dsts/wave,
// 16 dsts per 256-thr block; both edge types via blockIdx.y.
// Edge data from unified records: src @ rec[pos*8], weight @ rec[pos*8+1+head].
// ---------------------------------------------------------------------------
__global__ __launch_bounds__(256) void gat_gather2_kernel(
    const int* __restrict__ row_at, const int* __restrict__ deg_at,
    const float* __restrict__ rec_at, const f16* __restrict__ h_at,
    f16* __restrict__ out_at,
    const int* __restrict__ row_tt, const int* __restrict__ deg_tt,
    const float* __restrict__ rec_tt, const f16* __restrict__ h_tt,
    f16* __restrict__ out_tt)
{
    const bool at = (blockIdx.y == 0);
    const int* rs = at ? row_at : row_tt;
    const int* dg = at ? deg_at : deg_tt;
    const float* rec = at ? rec_at : rec_tt;
    const f16* hsrc = at ? h_at : h_tt;
    f16* out = at ? out_at : out_tt;

    const int t = threadIdx.x;
    const int d = blockIdx.x * 16 + (t >> 4);   // 16 dsts/block, uniform per 16-lane grp
    const int ln8 = t & 15;                     // chunk: channels [ln8*8, ln8*8+8)
    const int head = ln8 >> 2;
    const int beg = rs[d];
    const int n = dg[d];
    const f16x8* H = (const f16x8*)hsrc;

    float acc[8] = {0.f, 0.f, 0.f, 0.f, 0.f, 0.f, 0.f, 0.f};
    float den = 0.f;
    int i = 0;
    for (; i + 2 <= n; i += 2) {
        const float* r0 = rec + (size_t)(beg + i) * 8;
        const float* r1 = rec + (size_t)(beg + i + 1) * 8;
        int s0 = __float_as_int(r0[0]);
        int s1 = __float_as_int(r1[0]);
        float w0 = r0[1 + head];
        float w1 = r1[1 + head];
        f16x8 h0 = H[(size_t)s0 * 16 + ln8];
        f16x8 h1 = H[(size_t)s1 * 16 + ln8];
        den += w0 + w1;
#pragma unroll
        for (int j = 0; j < 8; j++)
            acc[j] = fmaf(w0, (float)h0[j], fmaf(w1, (float)h1[j], acc[j]));
    }
    if (i < n) {
        const float* r0 = rec + (size_t)(beg + i) * 8;
        int s0 = __float_as_int(r0[0]);
        float w0 = r0[1 + head];
        f16x8 h0 = H[(size_t)s0 * 16 + ln8];
        den += w0;
#pragma unroll
        for (int j = 0; j < 8; j++)
            acc[j] = fmaf(w0, (float)h0[j], acc[j]);
    }
    float inv = 1.f / (den + 1e-16f);
    f16x8 o;
#pragma unroll
    for (int j = 0; j < 8; j++) {
        float v = acc[j] * inv;
        o[j] = (f16)(v > 0.f ? v : 0.f);
    }
    ((f16x8*)out)[(size_t)d * 16 + ln8] = o;
}

// ---------------------------------------------------------------------------
// tanh GEMM (MFMA): BOTH metapaths per block -- Wk^T staged once.
// part[y][blk][c] = sum over 64-row tile of tanh((out_y @ Wk + bk))[.,c]
// ---------------------------------------------------------------------------
__global__ __launch_bounds__(256) void tanh_gemm_kernel(
    const f16* __restrict__ out_at, const f16* __restrict__ out_tt,
    const float* __restrict__ Wk, const float* __restrict__ bk,
    float* __restrict__ part)    // [2][PBM][128]
{
    __shared__ f16 Wt[128][136];
    __shared__ f16 xt[MBLK][136];
    const int row0 = blockIdx.x * MBLK;
    const int t = threadIdx.x;

    for (int i = t; i < 128 * 32; i += 256) {
        int jq = i >> 7, c = i & 127;
        f16x4 p = { (f16)Wk[(4 * jq + 0) * 128 + c], (f16)Wk[(4 * jq + 1) * 128 + c],
                    (f16)Wk[(4 * jq + 2) * 128 + c], (f16)Wk[(4 * jq + 3) * 128 + c] };
        *(f16x4*)&Wt[c][4 * jq] = p;
    }

    const int l = t & 63, w = t >> 6;
    const int l15 = l & 15, lq = l >> 4;

    for (int y = 0; y < 2; y++) {
        const f16* src = (y == 0) ? out_at : out_tt;
        __syncthreads();   // y=0: nothing yet; y=1: Sblk reads done
        for (int i = t; i < MBLK * 16; i += 256) {
            int r = i >> 4, q = i & 15;
            int gr = row0 + r; if (gr >= NTX) gr = NTX - 1;
            *(f16x8*)&xt[r][q * 8] = ((const f16x8*)src)[(size_t)gr * 16 + q];
        }
        __syncthreads();   // xt (and Wt, first pass) staged

        f16x8 afrag[4];
#pragma unroll
        for (int kt = 0; kt < 4; kt++)
            afrag[kt] = *(const f16x8*)&xt[w * 16 + l15][kt * 32 + lq * 8];

        float pn[8];
#pragma unroll
        for (int n = 0; n < 8; n++) {
            float bc = bk[n * 16 + l15];
            f32x4 acc = (f32x4){bc, bc, bc, bc};
#pragma unroll
            for (int kt = 0; kt < 4; kt++) {
                f16x8 bfrag = *(const f16x8*)&Wt[n * 16 + l15][kt * 32 + lq * 8];
                acc = __builtin_amdgcn_mfma_f32_16x16x32_f16(afrag[kt], bfrag, acc, 0, 0, 0);
            }
            float s = 0.f;
#pragma unroll
            for (int r = 0; r < 4; r++) {
                int row = row0 + w * 16 + lq * 4 + r;
                if (row < NTX) s += tanhf(acc[r]);
            }
            s += __shfl_xor(s, 16);
            s += __shfl_xor(s, 32);
            pn[n] = s;
        }

        __syncthreads();                  // all waves done reading xt
        float* Sblk = (float*)&xt[0][0];  // reuse xt as [4][128] float
        if (l < 16) {
#pragma unroll
            for (int n = 0; n < 8; n++)
                Sblk[w * 128 + n * 16 + l15] = pn[n];
        }
        __syncthreads();
        if (t < 128)
            part[((size_t)y * PBM + blockIdx.x) * 128 + t] =
                Sblk[t] + Sblk[128 + t] + Sblk[256 + t] + Sblk[384 + t];
    }
}

// ---------------------------------------------------------------------------
// reduce partials -> S_k[c]
// ---------------------------------------------------------------------------
__global__ __launch_bounds__(128) void reduceS_kernel(
    const float* __restrict__ part, float* __restrict__ S_at, float* __restrict__ S_tt)
{
    const int k = blockIdx.y;
    const int c = threadIdx.x;
    float* S = (k == 0) ? S_at : S_tt;
    const int b0 = blockIdx.x * 25;
    const int b1 = min(b0 + 25, PBM);
    float s = 0.f;
    for (int b = b0; b < b1; b++)
        s += part[((size_t)k * PBM + b) * 128 + c];
    atomicAdd(&S[c], s);
}

// ---------------------------------------------------------------------------
// attn: score_k = (q . S_k) / NTX; attn = softmax over k=2
// ---------------------------------------------------------------------------
__global__ __launch_bounds__(128) void attn_kernel(
    const float* __restrict__ S0, const float* __restrict__ S1,
    const float* __restrict__ q, float* __restrict__ attn)
{
    __shared__ float r0[128], r1[128];
    int c = threadIdx.x;
    r0[c] = q[c] * S0[c];
    r1[c] = q[c] * S1[c];
    __syncthreads();
    for (int s = 64; s > 0; s >>= 1) {
        if (c < s) { r0[c] += r0[c + s]; r1[c] += r1[c + s]; }
        __syncthreads();
    }
    if (c == 0) {
        float s0 = r0[0] / (float)NTX, s1 = r1[0] / (float)NTX;
        float m = fmaxf(s0, s1);
        float e0 = expf(s0 - m), e1 = expf(s1 - m);
        float inv = 1.f / (e0 + e1);
        attn[0] = e0 * inv;
        attn[1] = e1 * inv;
    }
}

// ---------------------------------------------------------------------------
// final_pool: batch is SORTED -> group g is a contiguous run [lo,hi).
// ---------------------------------------------------------------------------
__device__ __forceinline__ int lower_bound_g(const int* __restrict__ batch, int val)
{
    int lo = 0, hi = NTX;
    while (lo < hi) {
        int mid = (lo + hi) >> 1;
        if (batch[mid] < val) lo = mid + 1; else hi = mid;
    }
    return lo;
}

__global__ __launch_bounds__(128) void final_pool_kernel(
    const f16* __restrict__ out_at, const f16* __restrict__ out_tt,
    const int* __restrict__ batch, const float* __restrict__ attn,
    const float* __restrict__ Wl, const float* __restrict__ bl,
    float* __restrict__ out)
{
    __shared__ float r0[128], r1[128];
    const int g = blockIdx.x, c = threadIdx.x;
    const int lo = lower_bound_g(batch, g);
    const int hi = lower_bound_g(batch, g + 1);
    float s0 = 0.f, s1 = 0.f;
    for (int n = lo; n < hi; n++) {
        s0 += (float)out_at[(size_t)n * 128 + c];
        s1 += (float)out_tt[(size_t)n * 128 + c];
    }
    float pooled = (attn[0] * s0 + attn[1] * s1) / fmaxf((float)(hi - lo), 1.f);
    r0[c] = pooled * Wl[c * 2 + 0];
    r1[c] = pooled * Wl[c * 2 + 1];
    __syncthreads();
    for (int s = 64; s > 0; s >>= 1) {
        if (c < s) { r0[c] += r0[c + s]; r1[c] += r1[c + s]; }
        __syncthreads();
    }
    if (c == 0) {
        out[g * 2 + 0] = r0[0] + bl[0];
        out[g * 2 + 1] = r1[0] + bl[1];
    }
}

// ---------------------------------------------------------------------------
extern "C" void kernel_launch(void* const* d_in, const int* in_sizes, int n_in,
                              void* d_out, int out_size, void* d_ws, size_t ws_size,
                              hipStream_t stream)
{
    const float* x_tx     = (const float*)d_in[0];
    const float* x_ad     = (const float*)d_in[1];
    // d_in[2] = ei_ta (dead: out_ta never consumed)
    const int*   ei_at    = (const int*)d_in[3];
    const int*   ei_tt    = (const int*)d_in[4];
    const int*   batch    = (const int*)d_in[5];
    const float* W_tx     = (const float*)d_in[6];
    const float* b_tx     = (const float*)d_in[7];
    const float* W_ad     = (const float*)d_in[8];
    const float* b_ad     = (const float*)d_in[9];
    // d_in[10], d_in[11] = a_src_ta, a_dst_ta (dead)
    const float* a_src_at = (const float*)d_in[12];
    const float* a_dst_at = (const float*)d_in[13];
    const float* a_src_tt = (const float*)d_in[14];
    const float* a_dst_tt = (const float*)d_in[15];
    const float* Wk       = (const float*)d_in[16];
    const float* bk       = (const float*)d_in[17];
    const float* q        = (const float*)d_in[18];
    const float* Wl       = (const float*)d_in[19];
    const float* bl       = (const float*)d_in[20];
    float* out = (float*)d_out;

    char* ws = (char*)d_ws;
    size_t off = 0;
    auto alloc = [&](size_t bytes) -> void* {
        void* p = ws + off;
        off += (bytes + 255) & ~(size_t)255;
        return p;
    };
    f16* h_tx      = (f16*)alloc((size_t)NTX * 128 * 2);
    f16* h_ad      = (f16*)alloc((size_t)NADDR * 128 * 2);
    float* al_sat  = (float*)alloc((size_t)NADDR * 4 * 4);
    float* al_dat  = (float*)alloc((size_t)NTX * 4 * 4);
    float* al_stt  = (float*)alloc((size_t)NTX * 4 * 4);
    float* al_dtt  = (float*)alloc((size_t)NTX * 4 * 4);
    f16* out_at    = (f16*)alloc((size_t)NTX * 128 * 2);   // fully written by gather
    f16* out_tt    = (f16*)alloc((size_t)NTX * 128 * 2);
    float* rec_at  = (float*)alloc((size_t)NE * 8 * 4);    // 32B records: src + 4 ex
    float* rec_tt  = (float*)alloc((size_t)NE * 8 * 4);
    int* row_at    = (int*)alloc((size_t)NTX * 4);
    int* row_tt    = (int*)alloc((size_t)NTX * 4);
    int* cur_at    = (int*)alloc((size_t)NTX * 4);         // init'd by scanwrite
    int* cur_tt    = (int*)alloc((size_t)NTX * 4);
    int* csum      = (int*)alloc((size_t)2 * NCHUNK * 4);
    float* part    = (float*)alloc((size_t)2 * PBM * 128 * 4);
    // ---- zeroed region (counters / S accumulators) ----
    char* zero0 = ws + off;
    int* deg_at    = (int*)alloc((size_t)NTX * 4);
    int* deg_tt    = (int*)alloc((size_t)NTX * 4);
    float* S_at    = (float*)alloc(128 * 4);
    float* S_tt    = (float*)alloc(128 * 4);
    size_t zbytes = (size_t)((ws + off) - zero0);
    float* attnw   = (float*)alloc(2 * 4);

    hipMemsetAsync(zero0, 0, zbytes, stream);

    // projections + attention-logit dots (MFMA, both node types, one dispatch)
    proj2_kernel<<<2 * PBM, 256, 0, stream>>>(
        x_tx, W_tx, b_tx, h_tx, x_ad, W_ad, b_ad, h_ad,
        a_dst_at, al_dat, a_src_tt, al_stt, a_dst_tt, al_dtt,
        a_src_at, al_sat);

    // CSR build (dst-major), both edge types per dispatch
    int eb2 = (2 * NE + 255) / 256;
    deg2_kernel<<<eb2, 256, 0, stream>>>(ei_at, ei_tt, deg_at, deg_tt);
    dim3 sgrid(NCHUNK, 2);
    chunksum_kernel<<<sgrid, 256, 0, stream>>>(deg_at, deg_tt, csum);
    chunkscan_kernel<<<2, 256, 0, stream>>>(csum);
    scanwrite_kernel<<<sgrid, 256, 0, stream>>>(deg_at, deg_tt, csum,
                                                row_at, row_tt, cur_at, cur_tt);
    fill2_kernel<<<eb2, 256, 0, stream>>>(
        ei_at, cur_at, rec_at, al_sat, al_dat,
        ei_tt, cur_tt, rec_tt, al_stt, al_dtt);

    // gather-style GAT: 16 lanes/dst, 16 dsts per block (50000 = 3125*16)
    dim3 ggrid(NTX / 16, 2);
    gat_gather2_kernel<<<ggrid, 256, 0, stream>>>(
        row_at, deg_at, rec_at, h_ad, out_at,
        row_tt, deg_tt, rec_tt, h_tx, out_tt);

    // semantic attention: MFMA tanh GEMM (both metapaths/block) -> reduce -> softmax
    tanh_gemm_kernel<<<PBM, 256, 0, stream>>>(out_at, out_tt, Wk, bk, part);
    dim3 rgrid(32, 2);
    reduceS_kernel<<<rgrid, 128, 0, stream>>>(part, S_at, S_tt);
    attn_kernel<<<1, 128, 0, stream>>>(S_at, S_tt, q, attnw);

    // fused pooling (sorted batch -> contiguous runs) + final linear
    final_pool_kernel<<<GG, 128, 0, stream>>>(out_at, out_tt, batch, attnw, Wl, bl, out);
}

// Round 11
// 257.413 us; speedup vs baseline: 8.7164x; 1.0348x over previous
//
#include <hip/hip_runtime.h>

#define NTX   50000
#define NADDR 50000
#define NE    500000
#define GG    512
#define NEG   0.2f
#define MBLK  64
#define PBM   782    // ceil(50000/64)
#define NCHUNK 196   // ceil(50000/256)

typedef _Float16 f16;
typedef f16 f16x2 __attribute__((ext_vector_type(2)));
typedef f16 f16x4 __attribute__((ext_vector_type(4)));
typedef f16 f16x8 __attribute__((ext_vector_type(8)));
typedef float f32x4 __attribute__((ext_vector_type(4)));

__device__ __forceinline__ float lrelu(float x) { return x > 0.f ? x : NEG * x; }

// ---------------------------------------------------------------------------
// prep: fp16-transpose the three 128x128 weight matrices ONCE.
// Wt[c][j] = (f16)W[j][c].  grid (4, 3): 32 W-rows per block.
// ---------------------------------------------------------------------------
__global__ __launch_bounds__(256) void prep_kernel(
    const float* __restrict__ W_tx, const float* __restrict__ W_ad,
    const float* __restrict__ Wk,
    f16* __restrict__ Wt_tx, f16* __restrict__ Wt_ad, f16* __restrict__ Wkt)
{
    const float* W = (blockIdx.y == 0) ? W_tx : (blockIdx.y == 1) ? W_ad : Wk;
    f16* Wt        = (blockIdx.y == 0) ? Wt_tx : (blockIdx.y == 1) ? Wt_ad : Wkt;
    __shared__ f16 tile[32][136];
    const int t = threadIdx.x;
    const int j0 = blockIdx.x * 32;
    for (int i = t; i < 32 * 128; i += 256) {
        int r = i >> 7, c = i & 127;
        tile[r][c] = (f16)W[(size_t)(j0 + r) * 128 + c];
    }
    __syncthreads();
    for (int i = t; i < 128 * 8; i += 256) {
        int c = i >> 3, q = i & 7;
        f16x4 p = { tile[q * 4 + 0][c], tile[q * 4 + 1][c],
                    tile[q * 4 + 2][c], tile[q * 4 + 3][c] };
        *(f16x4*)&Wt[(size_t)c * 128 + j0 + q * 4] = p;
    }
}

// ---------------------------------------------------------------------------
// proj2 (MFMA): h = fp16(x @ W + b), fused attention-logit dots (fp32).
// 64 rows/block, 4 waves; A = x rows (fp16 LDS), B = W^T (pre-transposed fp16,
// straight f16x8 copy into padded LDS). mfma_f32_16x16x32_f16;
// C col=l&15, row=(l>>4)*4+reg (m89-verified layout).
// blocks [0,PBM) = tx, [PBM,2*PBM) = addr.
// ---------------------------------------------------------------------------
__global__ __launch_bounds__(256) void proj2_kernel(
    const float* __restrict__ x_tx, const f16* __restrict__ Wt_txg,
    const float* __restrict__ b_tx, f16* __restrict__ h_tx,
    const float* __restrict__ x_ad, const f16* __restrict__ Wt_adg,
    const float* __restrict__ b_ad, f16* __restrict__ h_ad,
    const float* __restrict__ a_dat, float* __restrict__ al_dat,
    const float* __restrict__ a_stt, float* __restrict__ al_stt,
    const float* __restrict__ a_dtt, float* __restrict__ al_dtt,
    const float* __restrict__ a_sat, float* __restrict__ al_sat)
{
    __shared__ f16 Wt[128][136];   // padded: 272 B row stride (16B-aligned)
    __shared__ f16 xt[MBLK][136];
    const bool is_tx = blockIdx.x < PBM;
    const float* x  = is_tx ? x_tx : x_ad;
    const f16* Wtg  = is_tx ? Wt_txg : Wt_adg;
    const float* b  = is_tx ? b_tx : b_ad;
    f16* h          = is_tx ? h_tx : h_ad;
    const int row0 = (is_tx ? blockIdx.x : blockIdx.x - PBM) * MBLK;
    const int t = threadIdx.x;

    // stage pre-transposed W^T: straight f16x8 copy, conflict-free
    {
        const f16x8* G = (const f16x8*)Wtg;
        for (int i = t; i < 128 * 16; i += 256) {
            int r = i >> 4, q = i & 15;
            *(f16x8*)&Wt[r][q * 8] = G[i];
        }
    }
    // stage x rows as fp16
    for (int i = t; i < MBLK * 32; i += 256) {
        int r = i >> 5, q = i & 31;
        int gr = row0 + r; if (gr >= NTX) gr = NTX - 1;
        float4 v = ((const float4*)x)[(size_t)gr * 32 + q];
        f16x4 p = {(f16)v.x, (f16)v.y, (f16)v.z, (f16)v.w};
        *(f16x4*)&xt[r][q * 4] = p;
    }
    __syncthreads();

    const int l = t & 63, w = t >> 6;
    const int l15 = l & 15, lq = l >> 4;

    f16x8 afrag[4];
#pragma unroll
    for (int kt = 0; kt < 4; kt++)
        afrag[kt] = *(const f16x8*)&xt[w * 16 + l15][kt * 32 + lq * 8];

    f32x4 acc[8];
#pragma unroll
    for (int n = 0; n < 8; n++) {
        float bc = b[n * 16 + l15];
        acc[n] = (f32x4){bc, bc, bc, bc};
#pragma unroll
        for (int kt = 0; kt < 4; kt++) {
            f16x8 bfrag = *(const f16x8*)&Wt[n * 16 + l15][kt * 32 + lq * 8];
            acc[n] = __builtin_amdgcn_mfma_f32_16x16x32_f16(afrag[kt], bfrag, acc[n], 0, 0, 0);
        }
    }

    // store h as fp16
#pragma unroll
    for (int r = 0; r < 4; r++) {
        int row = row0 + w * 16 + lq * 4 + r;
        if (row < NTX) {
#pragma unroll
            for (int n = 0; n < 8; n++)
                h[(size_t)row * 128 + n * 16 + l15] = (f16)acc[n][r];
        }
    }

    // attention-logit dots: al[row][head] = sum_c h[row][c]*a[c], head = c>>5
    auto do_dot = [&](const float* __restrict__ a, float* __restrict__ al) {
        float av[8];
#pragma unroll
        for (int n = 0; n < 8; n++) av[n] = a[n * 16 + l15];
#pragma unroll
        for (int r = 0; r < 4; r++) {
            float p0 = acc[0][r] * av[0] + acc[1][r] * av[1];
            float p1 = acc[2][r] * av[2] + acc[3][r] * av[3];
            float p2 = acc[4][r] * av[4] + acc[5][r] * av[5];
            float p3 = acc[6][r] * av[6] + acc[7][r] * av[7];
#pragma unroll
            for (int o = 1; o < 16; o <<= 1) {
                p0 += __shfl_xor(p0, o); p1 += __shfl_xor(p1, o);
                p2 += __shfl_xor(p2, o); p3 += __shfl_xor(p3, o);
            }
            int row = row0 + w * 16 + lq * 4 + r;
            if (l15 == 0 && row < NTX) {
                float4 v = make_float4(p0, p1, p2, p3);
                *(float4*)&al[(size_t)row * 4] = v;
            }
        }
    };
    if (is_tx) { do_dot(a_dat, al_dat); do_dot(a_stt, al_stt); do_dot(a_dtt, al_dtt); }
    else       { do_dot(a_sat, al_sat); }
}

// ---------------------------------------------------------------------------
// CSR build: degree -> (chunksum, chunkscan, scanwrite) -> fill(+exp)
// ---------------------------------------------------------------------------
__global__ __launch_bounds__(256) void deg2_kernel(
    const int* __restrict__ ei0, const int* __restrict__ ei1,
    int* __restrict__ deg0, int* __restrict__ deg1)
{
    int idx = blockIdx.x * 256 + threadIdx.x;
    if (idx < NE) atomicAdd(&deg0[ei0[NE + idx]], 1);
    else if (idx < 2 * NE) atomicAdd(&deg1[ei1[NE + (idx - NE)]], 1);
}

__global__ __launch_bounds__(256) void chunksum_kernel(
    const int* __restrict__ deg0, const int* __restrict__ deg1,
    int* __restrict__ csum)   // [2][NCHUNK]
{
    const int* deg = blockIdx.y == 0 ? deg0 : deg1;
    __shared__ int s[256];
    const int t = threadIdx.x;
    int idx = blockIdx.x * 256 + t;
    s[t] = idx < NTX ? deg[idx] : 0;
    __syncthreads();
    for (int o = 128; o > 0; o >>= 1) {
        if (t < o) s[t] += s[t + o];
        __syncthreads();
    }
    if (t == 0) csum[blockIdx.y * NCHUNK + blockIdx.x] = s[0];
}

__global__ __launch_bounds__(256) void chunkscan_kernel(int* __restrict__ csum)
{
    __shared__ int s[256];
    const int t = threadIdx.x;
    int* base = csum + blockIdx.x * NCHUNK;
    int v = t < NCHUNK ? base[t] : 0;
    s[t] = v;
    __syncthreads();
    for (int o = 1; o < 256; o <<= 1) {
        int u = (t >= o) ? s[t - o] : 0;
        __syncthreads();
        s[t] += u;
        __syncthreads();
    }
    if (t < NCHUNK) base[t] = s[t] - v;   // exclusive
}

// per-element exclusive scan + chunk offset; writes BOTH row (for gather)
// and cur (running cursor for fill) = same value.
__global__ __launch_bounds__(256) void scanwrite_kernel(
    const int* __restrict__ deg0, const int* __restrict__ deg1,
    const int* __restrict__ csum,
    int* __restrict__ row0, int* __restrict__ row1,
    int* __restrict__ cur0, int* __restrict__ cur1)
{
    const int* deg = blockIdx.y == 0 ? deg0 : deg1;
    int* row       = blockIdx.y == 0 ? row0 : row1;
    int* cur       = blockIdx.y == 0 ? cur0 : cur1;
    __shared__ int s[256];
    const int t = threadIdx.x;
    int idx = blockIdx.x * 256 + t;
    int v = idx < NTX ? deg[idx] : 0;
    s[t] = v;
    __syncthreads();
    for (int o = 1; o < 256; o <<= 1) {
        int u = (t >= o) ? s[t - o] : 0;
        __syncthreads();
        s[t] += u;
        __syncthreads();
    }
    if (idx < NTX) {
        int r = s[t] - v + csum[blockIdx.y * NCHUNK + blockIdx.x];
        row[idx] = r;
        cur[idx] = r;
    }
}

// fill: per edge, one atomic cursor bump + ONE 16B record:
// rec[pos] = { as_float(src), f16x2(ex0,ex1), f16x2(ex2,ex3), 0 }
__global__ __launch_bounds__(256) void fill2_kernel(
    const int* __restrict__ ei0, int* __restrict__ cur0, float4* __restrict__ rec0,
    const float* __restrict__ als0, const float* __restrict__ ald0,
    const int* __restrict__ ei1, int* __restrict__ cur1, float4* __restrict__ rec1,
    const float* __restrict__ als1, const float* __restrict__ ald1)
{
    int idx = blockIdx.x * 256 + threadIdx.x;
    const int* ei; int* cur; float4* rec;
    const float* als; const float* ald;
    int e;
    if (idx < NE) {
        ei = ei0; cur = cur0; rec = rec0; als = als0; ald = ald0; e = idx;
    } else if (idx < 2 * NE) {
        ei = ei1; cur = cur1; rec = rec1; als = als1; ald = ald1; e = idx - NE;
    } else return;
    int s = ei[e];
    int d = ei[NE + e];
    int pos = atomicAdd(&cur[d], 1);
    float4 as = *(const float4*)(als + (size_t)s * 4);
    float4 ad = *(const float4*)(ald + (size_t)d * 4);
    f16x2 p01 = { (f16)__expf(lrelu(as.x + ad.x)), (f16)__expf(lrelu(as.y + ad.y)) };
    f16x2 p23 = { (f16)__expf(lrelu(as.z + ad.z)), (f16)__expf(lrelu(as.w + ad.w)) };
    rec[pos] = make_float4(__int_as_float(s),
                           __builtin_bit_cast(float, p01),
                           __builtin_bit_cast(float, p23), 0.f);
}

// ---------------------------------------------------------------------------
// Gather GAT: 16 lanes per dst (f16x8/lane = 256B row per group), 4 dsts/wave,
// 16 dsts per 256-thr block; both edge types via blockIdx.y.
// Edge data: one 16B record load per edge (src + 4 fp16 weights).
// ---------------------------------------------------------------------------
__global__ __launch_bounds__(256) void gat_gather2_kernel(
    const int* __restrict__ row_at, const int* __restrict__ deg_at,
    const float4* __restrict__ rec_at, const f16* __restrict__ h_at,
    f16* __restrict__ out_at,
    const int* __restrict__ row_tt, const int* __restrict__ deg_tt,
    const float4* __restrict__ rec_tt, const f16* __restrict__ h_tt,
    f16* __restrict__ out_tt)
{
    const bool at = (blockIdx.y == 0);
    const int* rs = at ? row_at : row_tt;
    const int* dg = at ? deg_at : deg_tt;
    const float4* rec = at ? rec_at : rec_tt;
    const f16* hsrc = at ? h_at : h_tt;
    f16* out = at ? out_at : out_tt;

    const int t = threadIdx.x;
    const int d = blockIdx.x * 16 + (t >> 4);   // 16 dsts/block, uniform per 16-lane grp
    const int ln8 = t & 15;                     // chunk: channels [ln8*8, ln8*8+8)
    const int head = ln8 >> 2;
    const int beg = rs[d];
    const int n = dg[d];
    const f16x8* H = (const f16x8*)hsrc;

    auto wsel = [&](float4 r) -> float {
        f16x2 hh = __builtin_bit_cast(f16x2, (head & 2) ? r.z : r.y);
        return (head & 1) ? (float)hh[1] : (float)hh[0];
    };

    float acc[8] = {0.f, 0.f, 0.f, 0.f, 0.f, 0.f, 0.f, 0.f};
    float den = 0.f;
    int i = 0;
    for (; i + 2 <= n; i += 2) {
        float4 r0 = rec[beg + i];
        float4 r1 = rec[beg + i + 1];
        int s0 = __float_as_int(r0.x);
        int s1 = __float_as_int(r1.x);
        float w0 = wsel(r0), w1 = wsel(r1);
        f16x8 h0 = H[(size_t)s0 * 16 + ln8];
        f16x8 h1 = H[(size_t)s1 * 16 + ln8];
        den += w0 + w1;
#pragma unroll
        for (int j = 0; j < 8; j++)
            acc[j] = fmaf(w0, (float)h0[j], fmaf(w1, (float)h1[j], acc[j]));
    }
    if (i < n) {
        float4 r0 = rec[beg + i];
        int s0 = __float_as_int(r0.x);
        float w0 = wsel(r0);
        f16x8 h0 = H[(size_t)s0 * 16 + ln8];
        den += w0;
#pragma unroll
        for (int j = 0; j < 8; j++)
            acc[j] = fmaf(w0, (float)h0[j], acc[j]);
    }
    float inv = 1.f / (den + 1e-16f);
    f16x8 o;
#pragma unroll
    for (int j = 0; j < 8; j++) {
        float v = acc[j] * inv;
        o[j] = (f16)(v > 0.f ? v : 0.f);
    }
    ((f16x8*)out)[(size_t)d * 16 + ln8] = o;
}

// ---------------------------------------------------------------------------
// tanh GEMM (MFMA): BOTH metapaths per block -- Wk^T staged once (pre-transposed).
// part[y][blk][c] = sum over 64-row tile of tanh((out_y @ Wk + bk))[.,c]
// ---------------------------------------------------------------------------
__global__ __launch_bounds__(256) void tanh_gemm_kernel(
    const f16* __restrict__ out_at, const f16* __restrict__ out_tt,
    const f16* __restrict__ Wktg, const float* __restrict__ bk,
    float* __restrict__ part)    // [2][PBM][128]
{
    __shared__ f16 Wt[128][136];
    __shared__ f16 xt[MBLK][136];
    const int row0 = blockIdx.x * MBLK;
    const int t = threadIdx.x;

    {
        const f16x8* G = (const f16x8*)Wktg;
        for (int i = t; i < 128 * 16; i += 256) {
            int r = i >> 4, q = i & 15;
            *(f16x8*)&Wt[r][q * 8] = G[i];
        }
    }

    const int l = t & 63, w = t >> 6;
    const int l15 = l & 15, lq = l >> 4;

    for (int y = 0; y < 2; y++) {
        const f16* src = (y == 0) ? out_at : out_tt;
        __syncthreads();   // y=0: nothing yet; y=1: Sblk reads done
        for (int i = t; i < MBLK * 16; i += 256) {
            int r = i >> 4, q = i & 15;
            int gr = row0 + r; if (gr >= NTX) gr = NTX - 1;
            *(f16x8*)&xt[r][q * 8] = ((const f16x8*)src)[(size_t)gr * 16 + q];
        }
        __syncthreads();   // xt (and Wt, first pass) staged

        f16x8 afrag[4];
#pragma unroll
        for (int kt = 0; kt < 4; kt++)
            afrag[kt] = *(const f16x8*)&xt[w * 16 + l15][kt * 32 + lq * 8];

        float pn[8];
#pragma unroll
        for (int n = 0; n < 8; n++) {
            float bc = bk[n * 16 + l15];
            f32x4 acc = (f32x4){bc, bc, bc, bc};
#pragma unroll
            for (int kt = 0; kt < 4; kt++) {
                f16x8 bfrag = *(const f16x8*)&Wt[n * 16 + l15][kt * 32 + lq * 8];
                acc = __builtin_amdgcn_mfma_f32_16x16x32_f16(afrag[kt], bfrag, acc, 0, 0, 0);
            }
            float s = 0.f;
#pragma unroll
            for (int r = 0; r < 4; r++) {
                int row = row0 + w * 16 + lq * 4 + r;
                if (row < NTX) s += tanhf(acc[r]);
            }
            s += __shfl_xor(s, 16);
            s += __shfl_xor(s, 32);
            pn[n] = s;
        }

        __syncthreads();                  // all waves done reading xt
        float* Sblk = (float*)&xt[0][0];  // reuse xt as [4][128] float
        if (l < 16) {
#pragma unroll
            for (int n = 0; n < 8; n++)
                Sblk[w * 128 + n * 16 + l15] = pn[n];
        }
        __syncthreads();
        if (t < 128)
            part[((size_t)y * PBM + blockIdx.x) * 128 + t] =
                Sblk[t] + Sblk[128 + t] + Sblk[256 + t] + Sblk[384 + t];
    }
}

// ---------------------------------------------------------------------------
// reduce partials -> S_k[c]
// ---------------------------------------------------------------------------
__global__ __launch_bounds__(128) void reduceS_kernel(
    const float* __restrict__ part, float* __restrict__ S_at, float* __restrict__ S_tt)
{
    const int k = blockIdx.y;
    const int c = threadIdx.x;
    float* S = (k == 0) ? S_at : S_tt;
    const int b0 = blockIdx.x * 25;
    const int b1 = min(b0 + 25, PBM);
    float s = 0.f;
    for (int b = b0; b < b1; b++)
        s += part[((size_t)k * PBM + b) * 128 + c];
    atomicAdd(&S[c], s);
}

// ---------------------------------------------------------------------------
// attn: score_k = (q . S_k) / NTX; attn = softmax over k=2
// ---------------------------------------------------------------------------
__global__ __launch_bounds__(128) void attn_kernel(
    const float* __restrict__ S0, const float* __restrict__ S1,
    const float* __restrict__ q, float* __restrict__ attn)
{
    __shared__ float r0[128], r1[128];
    int c = threadIdx.x;
    r0[c] = q[c] * S0[c];
    r1[c] = q[c] * S1[c];
    __syncthreads();
    for (int s = 64; s > 0; s >>= 1) {
        if (c < s) { r0[c] += r0[c + s]; r1[c] += r1[c + s]; }
        __syncthreads();
    }
    if (c == 0) {
        float s0 = r0[0] / (float)NTX, s1 = r1[0] / (float)NTX;
        float m = fmaxf(s0, s1);
        float e0 = expf(s0 - m), e1 = expf(s1 - m);
        float inv = 1.f / (e0 + e1);
        attn[0] = e0 * inv;
        attn[1] = e1 * inv;
    }
}

// ---------------------------------------------------------------------------
// final_pool: batch is SORTED -> group g is a contiguous run [lo,hi).
// ---------------------------------------------------------------------------
__device__ __forceinline__ int lower_bound_g(const int* __restrict__ batch, int val)
{
    int lo = 0, hi = NTX;
    while (lo < hi) {
        int mid = (lo + hi) >> 1;
        if (batch[mid] < val) lo = mid + 1; else hi = mid;
    }
    return lo;
}

__global__ __launch_bounds__(128) void final_pool_kernel(
    const f16* __restrict__ out_at, const f16* __restrict__ out_tt,
    const int* __restrict__ batch, const float* __restrict__ attn,
    const float* __restrict__ Wl, const float* __restrict__ bl,
    float* __restrict__ out)
{
    __shared__ float r0[128], r1[128];
    const int g = blockIdx.x, c = threadIdx.x;
    const int lo = lower_bound_g(batch, g);
    const int hi = lower_bound_g(batch, g + 1);
    float s0 = 0.f, s1 = 0.f;
    for (int n = lo; n < hi; n++) {
        s0 += (float)out_at[(size_t)n * 128 + c];
        s1 += (float)out_tt[(size_t)n * 128 + c];
    }
    float pooled = (attn[0] * s0 + attn[1] * s1) / fmaxf((float)(hi - lo), 1.f);
    r0[c] = pooled * Wl[c * 2 + 0];
    r1[c] = pooled * Wl[c * 2 + 1];
    __syncthreads();
    for (int s = 64; s > 0; s >>= 1) {
        if (c < s) { r0[c] += r0[c + s]; r1[c] += r1[c + s]; }
        __syncthreads();
    }
    if (c == 0) {
        out[g * 2 + 0] = r0[0] + bl[0];
        out[g * 2 + 1] = r1[0] + bl[1];
    }
}

// ---------------------------------------------------------------------------
extern "C" void kernel_launch(void* const* d_in, const int* in_sizes, int n_in,
                              void* d_out, int out_size, void* d_ws, size_t ws_size,
                              hipStream_t stream)
{
    const float* x_tx     = (const float*)d_in[0];
    const float* x_ad     = (const float*)d_in[1];
    // d_in[2] = ei_ta (dead: out_ta never consumed)
    const int*   ei_at    = (const int*)d_in[3];
    const int*   ei_tt    = (const int*)d_in[4];
    const int*   batch    = (const int*)d_in[5];
    const float* W_tx     = (const float*)d_in[6];
    const float* b_tx     = (const float*)d_in[7];
    const float* W_ad     = (const float*)d_in[8];
    const float* b_ad     = (const float*)d_in[9];
    // d_in[10], d_in[11] = a_src_ta, a_dst_ta (dead)
    const float* a_src_at = (const float*)d_in[12];
    const float* a_dst_at = (const float*)d_in[13];
    const float* a_src_tt = (const float*)d_in[14];
    const float* a_dst_tt = (const float*)d_in[15];
    const float* Wk       = (const float*)d_in[16];
    const float* bk       = (const float*)d_in[17];
    const float* q        = (const float*)d_in[18];
    const float* Wl       = (const float*)d_in[19];
    const float* bl       = (const float*)d_in[20];
    float* out = (float*)d_out;

    char* ws = (char*)d_ws;
    size_t off = 0;
    auto alloc = [&](size_t bytes) -> void* {
        void* p = ws + off;
        off += (bytes + 255) & ~(size_t)255;
        return p;
    };
    f16* h_tx      = (f16*)alloc((size_t)NTX * 128 * 2);
    f16* h_ad      = (f16*)alloc((size_t)NADDR * 128 * 2);
    f16* Wt_txg    = (f16*)alloc((size_t)128 * 128 * 2);   // pre-transposed fp16 weights
    f16* Wt_adg    = (f16*)alloc((size_t)128 * 128 * 2);
    f16* Wktg      = (f16*)alloc((size_t)128 * 128 * 2);
    float* al_sat  = (float*)alloc((size_t)NADDR * 4 * 4);
    float* al_dat  = (float*)alloc((size_t)NTX * 4 * 4);
    float* al_stt  = (float*)alloc((size_t)NTX * 4 * 4);
    float* al_dtt  = (float*)alloc((size_t)NTX * 4 * 4);
    f16* out_at    = (f16*)alloc((size_t)NTX * 128 * 2);   // fully written by gather
    f16* out_tt    = (f16*)alloc((size_t)NTX * 128 * 2);
    float4* rec_at = (float4*)alloc((size_t)NE * 16);      // 16B records: src + 4 fp16 ex
    float4* rec_tt = (float4*)alloc((size_t)NE * 16);
    int* row_at    = (int*)alloc((size_t)NTX * 4);
    int* row_tt    = (int*)alloc((size_t)NTX * 4);
    int* cur_at    = (int*)alloc((size_t)NTX * 4);         // init'd by scanwrite
    int* cur_tt    = (int*)alloc((size_t)NTX * 4);
    int* csum      = (int*)alloc((size_t)2 * NCHUNK * 4);
    float* part    = (float*)alloc((size_t)2 * PBM * 128 * 4);
    // ---- zeroed region (counters / S accumulators) ----
    char* zero0 = ws + off;
    int* deg_at    = (int*)alloc((size_t)NTX * 4);
    int* deg_tt    = (int*)alloc((size_t)NTX * 4);
    float* S_at    = (float*)alloc(128 * 4);
    float* S_tt    = (float*)alloc(128 * 4);
    size_t zbytes = (size_t)((ws + off) - zero0);
    float* attnw   = (float*)alloc(2 * 4);

    hipMemsetAsync(zero0, 0, zbytes, stream);

    // one-shot fp16 weight transposes
    dim3 pgrid(4, 3);
    prep_kernel<<<pgrid, 256, 0, stream>>>(W_tx, W_ad, Wk, Wt_txg, Wt_adg, Wktg);

    // projections + attention-logit dots (MFMA, both node types, one dispatch)
    proj2_kernel<<<2 * PBM, 256, 0, stream>>>(
        x_tx, Wt_txg, b_tx, h_tx, x_ad, Wt_adg, b_ad, h_ad,
        a_dst_at, al_dat, a_src_tt, al_stt, a_dst_tt, al_dtt,
        a_src_at, al_sat);

    // CSR build (dst-major), both edge types per dispatch
    int eb2 = (2 * NE + 255) / 256;
    deg2_kernel<<<eb2, 256, 0, stream>>>(ei_at, ei_tt, deg_at, deg_tt);
    dim3 sgrid(NCHUNK, 2);
    chunksum_kernel<<<sgrid, 256, 0, stream>>>(deg_at, deg_tt, csum);
    chunkscan_kernel<<<2, 256, 0, stream>>>(csum);
    scanwrite_kernel<<<sgrid, 256, 0, stream>>>(deg_at, deg_tt, csum,
                                                row_at, row_tt, cur_at, cur_tt);
    fill2_kernel<<<eb2, 256, 0, stream>>>(
        ei_at, cur_at, rec_at, al_sat, al_dat,
        ei_tt, cur_tt, rec_tt, al_stt, al_dtt);

    // gather-style GAT: 16 lanes/dst, 16 dsts per block (50000 = 3125*16)
    dim3 ggrid(NTX / 16, 2);
    gat_gather2_kernel<<<ggrid, 256, 0, stream>>>(
        row_at, deg_at, rec_at, h_ad, out_at,
        row_tt, deg_tt, rec_tt, h_tx, out_tt);

    // semantic attention: MFMA tanh GEMM (both metapaths/block) -> reduce -> softmax
    tanh_gemm_kernel<<<PBM, 256, 0, stream>>>(out_at, out_tt, Wktg, bk, part);
    dim3 rgrid(32, 2);
    reduceS_kernel<<<rgrid, 128, 0, stream>>>(part, S_at, S_tt);
    attn_kernel<<<1, 128, 0, stream>>>(S_at, S_tt, q, attnw);

    // fused pooling (sorted batch -> contiguous runs) + final linear
    final_pool_kernel<<<GG, 128, 0, stream>>>(out_at, out_tt, batch, attnw, Wl, bl, out);
}

// Round 12
// 226.393 us; speedup vs baseline: 9.9107x; 1.1370x over previous
//
#include <hip/hip_runtime.h>

#define NTX   50000
#define NADDR 50000
#define NE    500000
#define GG    512
#define NEG   0.2f
#define MBLK  64
#define PBM   782    // ceil(50000/64)
#define NCHUNK 196   // ceil(50000/256)

typedef _Float16 f16;
typedef f16 f16x4 __attribute__((ext_vector_type(4)));
typedef f16 f16x8 __attribute__((ext_vector_type(8)));
typedef float f32x4 __attribute__((ext_vector_type(4)));

__device__ __forceinline__ float lrelu(float x) { return x > 0.f ? x : NEG * x; }

// ---------------------------------------------------------------------------
// prep: fp16-transpose the three 128x128 weight matrices ONCE.
// ---------------------------------------------------------------------------
__global__ __launch_bounds__(256) void prep_kernel(
    const float* __restrict__ W_tx, const float* __restrict__ W_ad,
    const float* __restrict__ Wk,
    f16* __restrict__ Wt_tx, f16* __restrict__ Wt_ad, f16* __restrict__ Wkt)
{
    const float* W = (blockIdx.y == 0) ? W_tx : (blockIdx.y == 1) ? W_ad : Wk;
    f16* Wt        = (blockIdx.y == 0) ? Wt_tx : (blockIdx.y == 1) ? Wt_ad : Wkt;
    __shared__ f16 tile[32][136];
    const int t = threadIdx.x;
    const int j0 = blockIdx.x * 32;
    for (int i = t; i < 32 * 128; i += 256) {
        int r = i >> 7, c = i & 127;
        tile[r][c] = (f16)W[(size_t)(j0 + r) * 128 + c];
    }
    __syncthreads();
    for (int i = t; i < 128 * 8; i += 256) {
        int c = i >> 3, q = i & 7;
        f16x4 p = { tile[q * 4 + 0][c], tile[q * 4 + 1][c],
                    tile[q * 4 + 2][c], tile[q * 4 + 3][c] };
        *(f16x4*)&Wt[(size_t)c * 128 + j0 + q * 4] = p;
    }
}

// ---------------------------------------------------------------------------
// proj2 (MFMA): h = fp16(x @ W + b), fused attention-logit dots (fp32).
// ---------------------------------------------------------------------------
__global__ __launch_bounds__(256) void proj2_kernel(
    const float* __restrict__ x_tx, const f16* __restrict__ Wt_txg,
    const float* __restrict__ b_tx, f16* __restrict__ h_tx,
    const float* __restrict__ x_ad, const f16* __restrict__ Wt_adg,
    const float* __restrict__ b_ad, f16* __restrict__ h_ad,
    const float* __restrict__ a_dat, float* __restrict__ al_dat,
    const float* __restrict__ a_stt, float* __restrict__ al_stt,
    const float* __restrict__ a_dtt, float* __restrict__ al_dtt,
    const float* __restrict__ a_sat, float* __restrict__ al_sat)
{
    __shared__ f16 Wt[128][136];   // padded: 272 B row stride (16B-aligned)
    __shared__ f16 xt[MBLK][136];
    const bool is_tx = blockIdx.x < PBM;
    const float* x  = is_tx ? x_tx : x_ad;
    const f16* Wtg  = is_tx ? Wt_txg : Wt_adg;
    const float* b  = is_tx ? b_tx : b_ad;
    f16* h          = is_tx ? h_tx : h_ad;
    const int row0 = (is_tx ? blockIdx.x : blockIdx.x - PBM) * MBLK;
    const int t = threadIdx.x;

    {
        const f16x8* G = (const f16x8*)Wtg;
        for (int i = t; i < 128 * 16; i += 256) {
            int r = i >> 4, q = i & 15;
            *(f16x8*)&Wt[r][q * 8] = G[i];
        }
    }
    for (int i = t; i < MBLK * 32; i += 256) {
        int r = i >> 5, q = i & 31;
        int gr = row0 + r; if (gr >= NTX) gr = NTX - 1;
        float4 v = ((const float4*)x)[(size_t)gr * 32 + q];
        f16x4 p = {(f16)v.x, (f16)v.y, (f16)v.z, (f16)v.w};
        *(f16x4*)&xt[r][q * 4] = p;
    }
    __syncthreads();

    const int l = t & 63, w = t >> 6;
    const int l15 = l & 15, lq = l >> 4;

    f16x8 afrag[4];
#pragma unroll
    for (int kt = 0; kt < 4; kt++)
        afrag[kt] = *(const f16x8*)&xt[w * 16 + l15][kt * 32 + lq * 8];

    f32x4 acc[8];
#pragma unroll
    for (int n = 0; n < 8; n++) {
        float bc = b[n * 16 + l15];
        acc[n] = (f32x4){bc, bc, bc, bc};
#pragma unroll
        for (int kt = 0; kt < 4; kt++) {
            f16x8 bfrag = *(const f16x8*)&Wt[n * 16 + l15][kt * 32 + lq * 8];
            acc[n] = __builtin_amdgcn_mfma_f32_16x16x32_f16(afrag[kt], bfrag, acc[n], 0, 0, 0);
        }
    }

#pragma unroll
    for (int r = 0; r < 4; r++) {
        int row = row0 + w * 16 + lq * 4 + r;
        if (row < NTX) {
#pragma unroll
            for (int n = 0; n < 8; n++)
                h[(size_t)row * 128 + n * 16 + l15] = (f16)acc[n][r];
        }
    }

    auto do_dot = [&](const float* __restrict__ a, float* __restrict__ al) {
        float av[8];
#pragma unroll
        for (int n = 0; n < 8; n++) av[n] = a[n * 16 + l15];
#pragma unroll
        for (int r = 0; r < 4; r++) {
            float p0 = acc[0][r] * av[0] + acc[1][r] * av[1];
            float p1 = acc[2][r] * av[2] + acc[3][r] * av[3];
            float p2 = acc[4][r] * av[4] + acc[5][r] * av[5];
            float p3 = acc[6][r] * av[6] + acc[7][r] * av[7];
#pragma unroll
            for (int o = 1; o < 16; o <<= 1) {
                p0 += __shfl_xor(p0, o); p1 += __shfl_xor(p1, o);
                p2 += __shfl_xor(p2, o); p3 += __shfl_xor(p3, o);
            }
            int row = row0 + w * 16 + lq * 4 + r;
            if (l15 == 0 && row < NTX) {
                float4 v = make_float4(p0, p1, p2, p3);
                *(float4*)&al[(size_t)row * 4] = v;
            }
        }
    };
    if (is_tx) { do_dot(a_dat, al_dat); do_dot(a_stt, al_stt); do_dot(a_dtt, al_dtt); }
    else       { do_dot(a_sat, al_sat); }
}

// ---------------------------------------------------------------------------
// CSR build: deg2 (+rank capture) -> chunksum -> chunkscan -> scanwrite -> fill
// ---------------------------------------------------------------------------
// rank[e] = this edge's arrival index within its dst (atomicAdd return).
__global__ __launch_bounds__(256) void deg2_kernel(
    const int* __restrict__ ei0, const int* __restrict__ ei1,
    int* __restrict__ deg0, int* __restrict__ deg1,
    int* __restrict__ rank0, int* __restrict__ rank1)
{
    int idx = blockIdx.x * 256 + threadIdx.x;
    if (idx < NE) rank0[idx] = atomicAdd(&deg0[ei0[NE + idx]], 1);
    else if (idx < 2 * NE) rank1[idx - NE] = atomicAdd(&deg1[ei1[NE + (idx - NE)]], 1);
}

__global__ __launch_bounds__(256) void chunksum_kernel(
    const int* __restrict__ deg0, const int* __restrict__ deg1,
    int* __restrict__ csum)   // [2][NCHUNK]
{
    const int* deg = blockIdx.y == 0 ? deg0 : deg1;
    __shared__ int s[256];
    const int t = threadIdx.x;
    int idx = blockIdx.x * 256 + t;
    s[t] = idx < NTX ? deg[idx] : 0;
    __syncthreads();
    for (int o = 128; o > 0; o >>= 1) {
        if (t < o) s[t] += s[t + o];
        __syncthreads();
    }
    if (t == 0) csum[blockIdx.y * NCHUNK + blockIdx.x] = s[0];
}

__global__ __launch_bounds__(256) void chunkscan_kernel(int* __restrict__ csum)
{
    __shared__ int s[256];
    const int t = threadIdx.x;
    int* base = csum + blockIdx.x * NCHUNK;
    int v = t < NCHUNK ? base[t] : 0;
    s[t] = v;
    __syncthreads();
    for (int o = 1; o < 256; o <<= 1) {
        int u = (t >= o) ? s[t - o] : 0;
        __syncthreads();
        s[t] += u;
        __syncthreads();
    }
    if (t < NCHUNK) base[t] = s[t] - v;   // exclusive
}

__global__ __launch_bounds__(256) void scanwrite_kernel(
    const int* __restrict__ deg0, const int* __restrict__ deg1,
    const int* __restrict__ csum,
    int* __restrict__ row0, int* __restrict__ row1)
{
    const int* deg = blockIdx.y == 0 ? deg0 : deg1;
    int* row       = blockIdx.y == 0 ? row0 : row1;
    __shared__ int s[256];
    const int t = threadIdx.x;
    int idx = blockIdx.x * 256 + t;
    int v = idx < NTX ? deg[idx] : 0;
    s[t] = v;
    __syncthreads();
    for (int o = 1; o < 256; o <<= 1) {
        int u = (t >= o) ? s[t - o] : 0;
        __syncthreads();
        s[t] += u;
        __syncthreads();
    }
    if (idx < NTX)
        row[idx] = s[t] - v + csum[blockIdx.y * NCHUNK + blockIdx.x];
}

// fill: NO atomics. pos = row[dst] + rank[e]; one scattered 4B store.
__global__ __launch_bounds__(256) void fill2_kernel(
    const int* __restrict__ ei0, const int* __restrict__ rank0,
    const int* __restrict__ row0, int* __restrict__ csr0,
    const int* __restrict__ ei1, const int* __restrict__ rank1,
    const int* __restrict__ row1, int* __restrict__ csr1)
{
    int idx = blockIdx.x * 256 + threadIdx.x;
    const int* ei; const int* rank; const int* row; int* csr;
    int e;
    if (idx < NE)          { ei = ei0; rank = rank0; row = row0; csr = csr0; e = idx; }
    else if (idx < 2 * NE) { ei = ei1; rank = rank1; row = row1; csr = csr1; e = idx - NE; }
    else return;
    int s = ei[e];
    int d = ei[NE + e];
    csr[row[d] + rank[e]] = s;
}

// ---------------------------------------------------------------------------
// Gather GAT: 16 lanes per dst (f16x8/lane = 256B row per group), 4 dsts/wave,
// 16 dsts per 256-thr block; both edge types via blockIdx.y.
// Softmax weights computed INLINE: w = exp(lrelu(als[s,head] + ald[d,head])).
// ---------------------------------------------------------------------------
__global__ __launch_bounds__(256) void gat_gather2_kernel(
    const int* __restrict__ row_at, const int* __restrict__ deg_at,
    const int* __restrict__ csr_at, const float* __restrict__ als_at,
    const float* __restrict__ ald_at, const f16* __restrict__ h_at,
    f16* __restrict__ out_at,
    const int* __restrict__ row_tt, const int* __restrict__ deg_tt,
    const int* __restrict__ csr_tt, const float* __restrict__ als_tt,
    const float* __restrict__ ald_tt, const f16* __restrict__ h_tt,
    f16* __restrict__ out_tt)
{
    const bool at = (blockIdx.y == 0);
    const int* rs = at ? row_at : row_tt;
    const int* dg = at ? deg_at : deg_tt;
    const int* cs = at ? csr_at : csr_tt;
    const float* als = at ? als_at : als_tt;
    const float* ald = at ? ald_at : ald_tt;
    const f16* hsrc = at ? h_at : h_tt;
    f16* out = at ? out_at : out_tt;

    const int t = threadIdx.x;
    const int d = blockIdx.x * 16 + (t >> 4);   // 16 dsts/block, uniform per 16-lane grp
    const int ln8 = t & 15;                     // chunk: channels [ln8*8, ln8*8+8)
    const int head = ln8 >> 2;
    const int beg = rs[d];
    const int n = dg[d];
    const float aldv = ald[d * 4 + head];
    const f16x8* H = (const f16x8*)hsrc;

    float acc[8] = {0.f, 0.f, 0.f, 0.f, 0.f, 0.f, 0.f, 0.f};
    float den = 0.f;
    int i = 0;
    for (; i + 2 <= n; i += 2) {
        int s0 = cs[beg + i], s1 = cs[beg + i + 1];
        float l0 = als[s0 * 4 + head], l1 = als[s1 * 4 + head];
        f16x8 h0 = H[(size_t)s0 * 16 + ln8];
        f16x8 h1 = H[(size_t)s1 * 16 + ln8];
        float w0 = __expf(lrelu(l0 + aldv));
        float w1 = __expf(lrelu(l1 + aldv));
        den += w0 + w1;
#pragma unroll
        for (int j = 0; j < 8; j++)
            acc[j] = fmaf(w0, (float)h0[j], fmaf(w1, (float)h1[j], acc[j]));
    }
    if (i < n) {
        int s0 = cs[beg + i];
        float l0 = als[s0 * 4 + head];
        f16x8 h0 = H[(size_t)s0 * 16 + ln8];
        float w0 = __expf(lrelu(l0 + aldv));
        den += w0;
#pragma unroll
        for (int j = 0; j < 8; j++)
            acc[j] = fmaf(w0, (float)h0[j], acc[j]);
    }
    float inv = 1.f / (den + 1e-16f);
    f16x8 o;
#pragma unroll
    for (int j = 0; j < 8; j++) {
        float v = acc[j] * inv;
        o[j] = (f16)(v > 0.f ? v : 0.f);
    }
    ((f16x8*)out)[(size_t)d * 16 + ln8] = o;
}

// ---------------------------------------------------------------------------
// tanh GEMM (MFMA): BOTH metapaths per block -- Wk^T staged once (pre-transposed).
// ---------------------------------------------------------------------------
__global__ __launch_bounds__(256) void tanh_gemm_kernel(
    const f16* __restrict__ out_at, const f16* __restrict__ out_tt,
    const f16* __restrict__ Wktg, const float* __restrict__ bk,
    float* __restrict__ part)    // [2][PBM][128]
{
    __shared__ f16 Wt[128][136];
    __shared__ f16 xt[MBLK][136];
    const int row0 = blockIdx.x * MBLK;
    const int t = threadIdx.x;

    {
        const f16x8* G = (const f16x8*)Wktg;
        for (int i = t; i < 128 * 16; i += 256) {
            int r = i >> 4, q = i & 15;
            *(f16x8*)&Wt[r][q * 8] = G[i];
        }
    }

    const int l = t & 63, w = t >> 6;
    const int l15 = l & 15, lq = l >> 4;

    for (int y = 0; y < 2; y++) {
        const f16* src = (y == 0) ? out_at : out_tt;
        __syncthreads();   // y=0: nothing yet; y=1: Sblk reads done
        for (int i = t; i < MBLK * 16; i += 256) {
            int r = i >> 4, q = i & 15;
            int gr = row0 + r; if (gr >= NTX) gr = NTX - 1;
            *(f16x8*)&xt[r][q * 8] = ((const f16x8*)src)[(size_t)gr * 16 + q];
        }
        __syncthreads();   // xt (and Wt, first pass) staged

        f16x8 afrag[4];
#pragma unroll
        for (int kt = 0; kt < 4; kt++)
            afrag[kt] = *(const f16x8*)&xt[w * 16 + l15][kt * 32 + lq * 8];

        float pn[8];
#pragma unroll
        for (int n = 0; n < 8; n++) {
            float bc = bk[n * 16 + l15];
            f32x4 acc = (f32x4){bc, bc, bc, bc};
#pragma unroll
            for (int kt = 0; kt < 4; kt++) {
                f16x8 bfrag = *(const f16x8*)&Wt[n * 16 + l15][kt * 32 + lq * 8];
                acc = __builtin_amdgcn_mfma_f32_16x16x32_f16(afrag[kt], bfrag, acc, 0, 0, 0);
            }
            float s = 0.f;
#pragma unroll
            for (int r = 0; r < 4; r++) {
                int row = row0 + w * 16 + lq * 4 + r;
                if (row < NTX) s += tanhf(acc[r]);
            }
            s += __shfl_xor(s, 16);
            s += __shfl_xor(s, 32);
            pn[n] = s;
        }

        __syncthreads();                  // all waves done reading xt
        float* Sblk = (float*)&xt[0][0];  // reuse xt as [4][128] float
        if (l < 16) {
#pragma unroll
            for (int n = 0; n < 8; n++)
                Sblk[w * 128 + n * 16 + l15] = pn[n];
        }
        __syncthreads();
        if (t < 128)
            part[((size_t)y * PBM + blockIdx.x) * 128 + t] =
                Sblk[t] + Sblk[128 + t] + Sblk[256 + t] + Sblk[384 + t];
    }
}

// ---------------------------------------------------------------------------
// reduce partials -> S_k[c]
// ---------------------------------------------------------------------------
__global__ __launch_bounds__(128) void reduceS_kernel(
    const float* __restrict__ part, float* __restrict__ S_at, float* __restrict__ S_tt)
{
    const int k = blockIdx.y;
    const int c = threadIdx.x;
    float* S = (k == 0) ? S_at : S_tt;
    const int b0 = blockIdx.x * 25;
    const int b1 = min(b0 + 25, PBM);
    float s = 0.f;
    for (int b = b0; b < b1; b++)
        s += part[((size_t)k * PBM + b) * 128 + c];
    atomicAdd(&S[c], s);
}

// ---------------------------------------------------------------------------
// attn: score_k = (q . S_k) / NTX; attn = softmax over k=2
// ---------------------------------------------------------------------------
__global__ __launch_bounds__(128) void attn_kernel(
    const float* __restrict__ S0, const float* __restrict__ S1,
    const float* __restrict__ q, float* __restrict__ attn)
{
    __shared__ float r0[128], r1[128];
    int c = threadIdx.x;
    r0[c] = q[c] * S0[c];
    r1[c] = q[c] * S1[c];
    __syncthreads();
    for (int s = 64; s > 0; s >>= 1) {
        if (c < s) { r0[c] += r0[c + s]; r1[c] += r1[c + s]; }
        __syncthreads();
    }
    if (c == 0) {
        float s0 = r0[0] / (float)NTX, s1 = r1[0] / (float)NTX;
        float m = fmaxf(s0, s1);
        float e0 = expf(s0 - m), e1 = expf(s1 - m);
        float inv = 1.f / (e0 + e1);
        attn[0] = e0 * inv;
        attn[1] = e1 * inv;
    }
}

// ---------------------------------------------------------------------------
// final_pool: batch is SORTED -> group g is a contiguous run [lo,hi).
// ---------------------------------------------------------------------------
__device__ __forceinline__ int lower_bound_g(const int* __restrict__ batch, int val)
{
    int lo = 0, hi = NTX;
    while (lo < hi) {
        int mid = (lo + hi) >> 1;
        if (batch[mid] < val) lo = mid + 1; else hi = mid;
    }
    return lo;
}

__global__ __launch_bounds__(128) void final_pool_kernel(
    const f16* __restrict__ out_at, const f16* __restrict__ out_tt,
    const int* __restrict__ batch, const float* __restrict__ attn,
    const float* __restrict__ Wl, const float* __restrict__ bl,
    float* __restrict__ out)
{
    __shared__ float r0[128], r1[128];
    const int g = blockIdx.x, c = threadIdx.x;
    const int lo = lower_bound_g(batch, g);
    const int hi = lower_bound_g(batch, g + 1);
    float s0 = 0.f, s1 = 0.f;
    for (int n = lo; n < hi; n++) {
        s0 += (float)out_at[(size_t)n * 128 + c];
        s1 += (float)out_tt[(size_t)n * 128 + c];
    }
    float pooled = (attn[0] * s0 + attn[1] * s1) / fmaxf((float)(hi - lo), 1.f);
    r0[c] = pooled * Wl[c * 2 + 0];
    r1[c] = pooled * Wl[c * 2 + 1];
    __syncthreads();
    for (int s = 64; s > 0; s >>= 1) {
        if (c < s) { r0[c] += r0[c + s]; r1[c] += r1[c + s]; }
        __syncthreads();
    }
    if (c == 0) {
        out[g * 2 + 0] = r0[0] + bl[0];
        out[g * 2 + 1] = r1[0] + bl[1];
    }
}

// ---------------------------------------------------------------------------
extern "C" void kernel_launch(void* const* d_in, const int* in_sizes, int n_in,
                              void* d_out, int out_size, void* d_ws, size_t ws_size,
                              hipStream_t stream)
{
    const float* x_tx     = (const float*)d_in[0];
    const float* x_ad     = (const float*)d_in[1];
    // d_in[2] = ei_ta (dead: out_ta never consumed)
    const int*   ei_at    = (const int*)d_in[3];
    const int*   ei_tt    = (const int*)d_in[4];
    const int*   batch    = (const int*)d_in[5];
    const float* W_tx     = (const float*)d_in[6];
    const float* b_tx     = (const float*)d_in[7];
    const float* W_ad     = (const float*)d_in[8];
    const float* b_ad     = (const float*)d_in[9];
    // d_in[10], d_in[11] = a_src_ta, a_dst_ta (dead)
    const float* a_src_at = (const float*)d_in[12];
    const float* a_dst_at = (const float*)d_in[13];
    const float* a_src_tt = (const float*)d_in[14];
    const float* a_dst_tt = (const float*)d_in[15];
    const float* Wk       = (const float*)d_in[16];
    const float* bk       = (const float*)d_in[17];
    const float* q        = (const float*)d_in[18];
    const float* Wl       = (const float*)d_in[19];
    const float* bl       = (const float*)d_in[20];
    float* out = (float*)d_out;

    char* ws = (char*)d_ws;
    size_t off = 0;
    auto alloc = [&](size_t bytes) -> void* {
        void* p = ws + off;
        off += (bytes + 255) & ~(size_t)255;
        return p;
    };
    f16* h_tx      = (f16*)alloc((size_t)NTX * 128 * 2);
    f16* h_ad      = (f16*)alloc((size_t)NADDR * 128 * 2);
    f16* Wt_txg    = (f16*)alloc((size_t)128 * 128 * 2);   // pre-transposed fp16 weights
    f16* Wt_adg    = (f16*)alloc((size_t)128 * 128 * 2);
    f16* Wktg      = (f16*)alloc((size_t)128 * 128 * 2);
    float* al_sat  = (float*)alloc((size_t)NADDR * 4 * 4);
    float* al_dat  = (float*)alloc((size_t)NTX * 4 * 4);
    float* al_stt  = (float*)alloc((size_t)NTX * 4 * 4);
    float* al_dtt  = (float*)alloc((size_t)NTX * 4 * 4);
    f16* out_at    = (f16*)alloc((size_t)NTX * 128 * 2);   // fully written by gather
    f16* out_tt    = (f16*)alloc((size_t)NTX * 128 * 2);
    int* csr_at    = (int*)alloc((size_t)NE * 4);
    int* csr_tt    = (int*)alloc((size_t)NE * 4);
    int* rank_at   = (int*)alloc((size_t)NE * 4);
    int* rank_tt   = (int*)alloc((size_t)NE * 4);
    int* row_at    = (int*)alloc((size_t)NTX * 4);
    int* row_tt    = (int*)alloc((size_t)NTX * 4);
    int* csum      = (int*)alloc((size_t)2 * NCHUNK * 4);
    float* part    = (float*)alloc((size_t)2 * PBM * 128 * 4);
    // ---- zeroed region (counters / S accumulators) ----
    char* zero0 = ws + off;
    int* deg_at    = (int*)alloc((size_t)NTX * 4);
    int* deg_tt    = (int*)alloc((size_t)NTX * 4);
    float* S_at    = (float*)alloc(128 * 4);
    float* S_tt    = (float*)alloc(128 * 4);
    size_t zbytes = (size_t)((ws + off) - zero0);
    float* attnw   = (float*)alloc(2 * 4);

    hipMemsetAsync(zero0, 0, zbytes, stream);

    // one-shot fp16 weight transposes
    dim3 pgrid(4, 3);
    prep_kernel<<<pgrid, 256, 0, stream>>>(W_tx, W_ad, Wk, Wt_txg, Wt_adg, Wktg);

    // projections + attention-logit dots (MFMA, both node types, one dispatch)
    proj2_kernel<<<2 * PBM, 256, 0, stream>>>(
        x_tx, Wt_txg, b_tx, h_tx, x_ad, Wt_adg, b_ad, h_ad,
        a_dst_at, al_dat, a_src_tt, al_stt, a_dst_tt, al_dtt,
        a_src_at, al_sat);

    // CSR build (dst-major), both edge types per dispatch
    int eb2 = (2 * NE + 255) / 256;
    deg2_kernel<<<eb2, 256, 0, stream>>>(ei_at, ei_tt, deg_at, deg_tt,
                                         rank_at, rank_tt);
    dim3 sgrid(NCHUNK, 2);
    chunksum_kernel<<<sgrid, 256, 0, stream>>>(deg_at, deg_tt, csum);
    chunkscan_kernel<<<2, 256, 0, stream>>>(csum);
    scanwrite_kernel<<<sgrid, 256, 0, stream>>>(deg_at, deg_tt, csum, row_at, row_tt);
    fill2_kernel<<<eb2, 256, 0, stream>>>(
        ei_at, rank_at, row_at, csr_at,
        ei_tt, rank_tt, row_tt, csr_tt);

    // gather-style GAT: 16 lanes/dst, 16 dsts per block (50000 = 3125*16)
    dim3 ggrid(NTX / 16, 2);
    gat_gather2_kernel<<<ggrid, 256, 0, stream>>>(
        row_at, deg_at, csr_at, al_sat, al_dat, h_ad, out_at,
        row_tt, deg_tt, csr_tt, al_stt, al_dtt, h_tx, out_tt);

    // semantic attention: MFMA tanh GEMM (both metapaths/block) -> reduce -> softmax
    tanh_gemm_kernel<<<PBM, 256, 0, stream>>>(out_at, out_tt, Wktg, bk, part);
    dim3 rgrid(32, 2);
    reduceS_kernel<<<rgrid, 128, 0, stream>>>(part, S_at, S_tt);
    attn_kernel<<<1, 128, 0, stream>>>(S_at, S_tt, q, attnw);

    // fused pooling (sorted batch -> contiguous runs) + final linear
    final_pool_kernel<<<GG, 128, 0, stream>>>(out_at, out_tt, batch, attnw, Wl, bl, out);
}

// Round 13
// 196.683 us; speedup vs baseline: 11.4078x; 1.1511x over previous
//
#include <hip/hip_runtime.h>

#define NTX   50000
#define NADDR 50000
#define NE    500000
#define GG    512
#define NEG   0.2f
#define MBLK  64
#define PBM   782    // ceil(50000/64)
#define NCHUNK 196   // ceil(50000/256)

typedef _Float16 f16;
typedef f16 f16x4 __attribute__((ext_vector_type(4)));
typedef f16 f16x8 __attribute__((ext_vector_type(8)));
typedef float f32x4 __attribute__((ext_vector_type(4)));

__device__ __forceinline__ float lrelu(float x) { return x > 0.f ? x : NEG * x; }

// ---------------------------------------------------------------------------
// prep: fp16-transpose the three 128x128 weight matrices ONCE.
// ---------------------------------------------------------------------------
__global__ __launch_bounds__(256) void prep_kernel(
    const float* __restrict__ W_tx, const float* __restrict__ W_ad,
    const float* __restrict__ Wk,
    f16* __restrict__ Wt_tx, f16* __restrict__ Wt_ad, f16* __restrict__ Wkt)
{
    const float* W = (blockIdx.y == 0) ? W_tx : (blockIdx.y == 1) ? W_ad : Wk;
    f16* Wt        = (blockIdx.y == 0) ? Wt_tx : (blockIdx.y == 1) ? Wt_ad : Wkt;
    __shared__ f16 tile[32][136];
    const int t = threadIdx.x;
    const int j0 = blockIdx.x * 32;
    for (int i = t; i < 32 * 128; i += 256) {
        int r = i >> 7, c = i & 127;
        tile[r][c] = (f16)W[(size_t)(j0 + r) * 128 + c];
    }
    __syncthreads();
    for (int i = t; i < 128 * 8; i += 256) {
        int c = i >> 3, q = i & 7;
        f16x4 p = { tile[q * 4 + 0][c], tile[q * 4 + 1][c],
                    tile[q * 4 + 2][c], tile[q * 4 + 3][c] };
        *(f16x4*)&Wt[(size_t)c * 128 + j0 + q * 4] = p;
    }
}

// ---------------------------------------------------------------------------
// proj2 (MFMA): h = fp16(x @ W + b), fused attention-logit dots (fp32).
// ---------------------------------------------------------------------------
__global__ __launch_bounds__(256) void proj2_kernel(
    const float* __restrict__ x_tx, const f16* __restrict__ Wt_txg,
    const float* __restrict__ b_tx, f16* __restrict__ h_tx,
    const float* __restrict__ x_ad, const f16* __restrict__ Wt_adg,
    const float* __restrict__ b_ad, f16* __restrict__ h_ad,
    const float* __restrict__ a_dat, float* __restrict__ al_dat,
    const float* __restrict__ a_stt, float* __restrict__ al_stt,
    const float* __restrict__ a_dtt, float* __restrict__ al_dtt,
    const float* __restrict__ a_sat, float* __restrict__ al_sat)
{
    __shared__ f16 Wt[128][136];   // padded: 272 B row stride (16B-aligned)
    __shared__ f16 xt[MBLK][136];
    const bool is_tx = blockIdx.x < PBM;
    const float* x  = is_tx ? x_tx : x_ad;
    const f16* Wtg  = is_tx ? Wt_txg : Wt_adg;
    const float* b  = is_tx ? b_tx : b_ad;
    f16* h          = is_tx ? h_tx : h_ad;
    const int row0 = (is_tx ? blockIdx.x : blockIdx.x - PBM) * MBLK;
    const int t = threadIdx.x;

    {
        const f16x8* G = (const f16x8*)Wtg;
        for (int i = t; i < 128 * 16; i += 256) {
            int r = i >> 4, q = i & 15;
            *(f16x8*)&Wt[r][q * 8] = G[i];
        }
    }
    for (int i = t; i < MBLK * 32; i += 256) {
        int r = i >> 5, q = i & 31;
        int gr = row0 + r; if (gr >= NTX) gr = NTX - 1;
        float4 v = ((const float4*)x)[(size_t)gr * 32 + q];
        f16x4 p = {(f16)v.x, (f16)v.y, (f16)v.z, (f16)v.w};
        *(f16x4*)&xt[r][q * 4] = p;
    }
    __syncthreads();

    const int l = t & 63, w = t >> 6;
    const int l15 = l & 15, lq = l >> 4;

    f16x8 afrag[4];
#pragma unroll
    for (int kt = 0; kt < 4; kt++)
        afrag[kt] = *(const f16x8*)&xt[w * 16 + l15][kt * 32 + lq * 8];

    f32x4 acc[8];
#pragma unroll
    for (int n = 0; n < 8; n++) {
        float bc = b[n * 16 + l15];
        acc[n] = (f32x4){bc, bc, bc, bc};
#pragma unroll
        for (int kt = 0; kt < 4; kt++) {
            f16x8 bfrag = *(const f16x8*)&Wt[n * 16 + l15][kt * 32 + lq * 8];
            acc[n] = __builtin_amdgcn_mfma_f32_16x16x32_f16(afrag[kt], bfrag, acc[n], 0, 0, 0);
        }
    }

#pragma unroll
    for (int r = 0; r < 4; r++) {
        int row = row0 + w * 16 + lq * 4 + r;
        if (row < NTX) {
#pragma unroll
            for (int n = 0; n < 8; n++)
                h[(size_t)row * 128 + n * 16 + l15] = (f16)acc[n][r];
        }
    }

    auto do_dot = [&](const float* __restrict__ a, float* __restrict__ al) {
        float av[8];
#pragma unroll
        for (int n = 0; n < 8; n++) av[n] = a[n * 16 + l15];
#pragma unroll
        for (int r = 0; r < 4; r++) {
            float p0 = acc[0][r] * av[0] + acc[1][r] * av[1];
            float p1 = acc[2][r] * av[2] + acc[3][r] * av[3];
            float p2 = acc[4][r] * av[4] + acc[5][r] * av[5];
            float p3 = acc[6][r] * av[6] + acc[7][r] * av[7];
#pragma unroll
            for (int o = 1; o < 16; o <<= 1) {
                p0 += __shfl_xor(p0, o); p1 += __shfl_xor(p1, o);
                p2 += __shfl_xor(p2, o); p3 += __shfl_xor(p3, o);
            }
            int row = row0 + w * 16 + lq * 4 + r;
            if (l15 == 0 && row < NTX) {
                float4 v = make_float4(p0, p1, p2, p3);
                *(float4*)&al[(size_t)row * 4] = v;
            }
        }
    };
    if (is_tx) { do_dot(a_dat, al_dat); do_dot(a_stt, al_stt); do_dot(a_dtt, al_dtt); }
    else       { do_dot(a_sat, al_sat); }
}

// ---------------------------------------------------------------------------
// CSR build: deg2 (+rank capture) -> chunksum -> chunkscan -> scanwrite -> fill
// ---------------------------------------------------------------------------
__global__ __launch_bounds__(256) void deg2_kernel(
    const int* __restrict__ ei0, const int* __restrict__ ei1,
    int* __restrict__ deg0, int* __restrict__ deg1,
    int* __restrict__ rank0, int* __restrict__ rank1)
{
    int idx = blockIdx.x * 256 + threadIdx.x;
    if (idx < NE) rank0[idx] = atomicAdd(&deg0[ei0[NE + idx]], 1);
    else if (idx < 2 * NE) rank1[idx - NE] = atomicAdd(&deg1[ei1[NE + (idx - NE)]], 1);
}

__global__ __launch_bounds__(256) void chunksum_kernel(
    const int* __restrict__ deg0, const int* __restrict__ deg1,
    int* __restrict__ csum)   // [2][NCHUNK]
{
    const int* deg = blockIdx.y == 0 ? deg0 : deg1;
    __shared__ int s[256];
    const int t = threadIdx.x;
    int idx = blockIdx.x * 256 + t;
    s[t] = idx < NTX ? deg[idx] : 0;
    __syncthreads();
    for (int o = 128; o > 0; o >>= 1) {
        if (t < o) s[t] += s[t + o];
        __syncthreads();
    }
    if (t == 0) csum[blockIdx.y * NCHUNK + blockIdx.x] = s[0];
}

__global__ __launch_bounds__(256) void chunkscan_kernel(int* __restrict__ csum)
{
    __shared__ int s[256];
    const int t = threadIdx.x;
    int* base = csum + blockIdx.x * NCHUNK;
    int v = t < NCHUNK ? base[t] : 0;
    s[t] = v;
    __syncthreads();
    for (int o = 1; o < 256; o <<= 1) {
        int u = (t >= o) ? s[t - o] : 0;
        __syncthreads();
        s[t] += u;
        __syncthreads();
    }
    if (t < NCHUNK) base[t] = s[t] - v;   // exclusive
}

__global__ __launch_bounds__(256) void scanwrite_kernel(
    const int* __restrict__ deg0, const int* __restrict__ deg1,
    const int* __restrict__ csum,
    int* __restrict__ row0, int* __restrict__ row1)
{
    const int* deg = blockIdx.y == 0 ? deg0 : deg1;
    int* row       = blockIdx.y == 0 ? row0 : row1;
    __shared__ int s[256];
    const int t = threadIdx.x;
    int idx = blockIdx.x * 256 + t;
    int v = idx < NTX ? deg[idx] : 0;
    s[t] = v;
    __syncthreads();
    for (int o = 1; o < 256; o <<= 1) {
        int u = (t >= o) ? s[t - o] : 0;
        __syncthreads();
        s[t] += u;
        __syncthreads();
    }
    if (idx < NTX)
        row[idx] = s[t] - v + csum[blockIdx.y * NCHUNK + blockIdx.x];
}

// fill: NO atomics. pos = row[dst] + rank[e]; one scattered 4B store.
__global__ __launch_bounds__(256) void fill2_kernel(
    const int* __restrict__ ei0, const int* __restrict__ rank0,
    const int* __restrict__ row0, int* __restrict__ csr0,
    const int* __restrict__ ei1, const int* __restrict__ rank1,
    const int* __restrict__ row1, int* __restrict__ csr1)
{
    int idx = blockIdx.x * 256 + threadIdx.x;
    const int* ei; const int* rank; const int* row; int* csr;
    int e;
    if (idx < NE)          { ei = ei0; rank = rank0; row = row0; csr = csr0; e = idx; }
    else if (idx < 2 * NE) { ei = ei1; rank = rank1; row = row1; csr = csr1; e = idx - NE; }
    else return;
    int s = ei[e];
    int d = ei[NE + e];
    csr[row[d] + rank[e]] = s;
}

// ---------------------------------------------------------------------------
// Gather GAT: 16 lanes per dst (f16x8/lane = 256B row per group), 4 dsts/wave,
// 16 dsts per 256-thr block; both edge types via blockIdx.y.
// Softmax weights computed INLINE: w = exp(lrelu(als[s,head] + ald[d,head])).
// ---------------------------------------------------------------------------
__global__ __launch_bounds__(256) void gat_gather2_kernel(
    const int* __restrict__ row_at, const int* __restrict__ deg_at,
    const int* __restrict__ csr_at, const float* __restrict__ als_at,
    const float* __restrict__ ald_at, const f16* __restrict__ h_at,
    f16* __restrict__ out_at,
    const int* __restrict__ row_tt, const int* __restrict__ deg_tt,
    const int* __restrict__ csr_tt, const float* __restrict__ als_tt,
    const float* __restrict__ ald_tt, const f16* __restrict__ h_tt,
    f16* __restrict__ out_tt)
{
    const bool at = (blockIdx.y == 0);
    const int* rs = at ? row_at : row_tt;
    const int* dg = at ? deg_at : deg_tt;
    const int* cs = at ? csr_at : csr_tt;
    const float* als = at ? als_at : als_tt;
    const float* ald = at ? ald_at : ald_tt;
    const f16* hsrc = at ? h_at : h_tt;
    f16* out = at ? out_at : out_tt;

    const int t = threadIdx.x;
    const int d = blockIdx.x * 16 + (t >> 4);   // 16 dsts/block, uniform per 16-lane grp
    const int ln8 = t & 15;                     // chunk: channels [ln8*8, ln8*8+8)
    const int head = ln8 >> 2;
    const int beg = rs[d];
    const int n = dg[d];
    const float aldv = ald[d * 4 + head];
    const f16x8* H = (const f16x8*)hsrc;

    float acc[8] = {0.f, 0.f, 0.f, 0.f, 0.f, 0.f, 0.f, 0.f};
    float den = 0.f;
    int i = 0;
    for (; i + 2 <= n; i += 2) {
        int s0 = cs[beg + i], s1 = cs[beg + i + 1];
        float l0 = als[s0 * 4 + head], l1 = als[s1 * 4 + head];
        f16x8 h0 = H[(size_t)s0 * 16 + ln8];
        f16x8 h1 = H[(size_t)s1 * 16 + ln8];
        float w0 = __expf(lrelu(l0 + aldv));
        float w1 = __expf(lrelu(l1 + aldv));
        den += w0 + w1;
#pragma unroll
        for (int j = 0; j < 8; j++)
            acc[j] = fmaf(w0, (float)h0[j], fmaf(w1, (float)h1[j], acc[j]));
    }
    if (i < n) {
        int s0 = cs[beg + i];
        float l0 = als[s0 * 4 + head];
        f16x8 h0 = H[(size_t)s0 * 16 + ln8];
        float w0 = __expf(lrelu(l0 + aldv));
        den += w0;
#pragma unroll
        for (int j = 0; j < 8; j++)
            acc[j] = fmaf(w0, (float)h0[j], acc[j]);
    }
    float inv = 1.f / (den + 1e-16f);
    f16x8 o;
#pragma unroll
    for (int j = 0; j < 8; j++) {
        float v = acc[j] * inv;
        o[j] = (f16)(v > 0.f ? v : 0.f);
    }
    ((f16x8*)out)[(size_t)d * 16 + ln8] = o;
}

// ---------------------------------------------------------------------------
// tanh GEMM (MFMA): BOTH metapaths per block -- Wk^T staged once (pre-transposed).
// ---------------------------------------------------------------------------
__global__ __launch_bounds__(256) void tanh_gemm_kernel(
    const f16* __restrict__ out_at, const f16* __restrict__ out_tt,
    const f16* __restrict__ Wktg, const float* __restrict__ bk,
    float* __restrict__ part)    // [2][PBM][128]
{
    __shared__ f16 Wt[128][136];
    __shared__ f16 xt[MBLK][136];
    const int row0 = blockIdx.x * MBLK;
    const int t = threadIdx.x;

    {
        const f16x8* G = (const f16x8*)Wktg;
        for (int i = t; i < 128 * 16; i += 256) {
            int r = i >> 4, q = i & 15;
            *(f16x8*)&Wt[r][q * 8] = G[i];
        }
    }

    const int l = t & 63, w = t >> 6;
    const int l15 = l & 15, lq = l >> 4;

    for (int y = 0; y < 2; y++) {
        const f16* src = (y == 0) ? out_at : out_tt;
        __syncthreads();   // y=0: nothing yet; y=1: Sblk reads done
        for (int i = t; i < MBLK * 16; i += 256) {
            int r = i >> 4, q = i & 15;
            int gr = row0 + r; if (gr >= NTX) gr = NTX - 1;
            *(f16x8*)&xt[r][q * 8] = ((const f16x8*)src)[(size_t)gr * 16 + q];
        }
        __syncthreads();   // xt (and Wt, first pass) staged

        f16x8 afrag[4];
#pragma unroll
        for (int kt = 0; kt < 4; kt++)
            afrag[kt] = *(const f16x8*)&xt[w * 16 + l15][kt * 32 + lq * 8];

        float pn[8];
#pragma unroll
        for (int n = 0; n < 8; n++) {
            float bc = bk[n * 16 + l15];
            f32x4 acc = (f32x4){bc, bc, bc, bc};
#pragma unroll
            for (int kt = 0; kt < 4; kt++) {
                f16x8 bfrag = *(const f16x8*)&Wt[n * 16 + l15][kt * 32 + lq * 8];
                acc = __builtin_amdgcn_mfma_f32_16x16x32_f16(afrag[kt], bfrag, acc, 0, 0, 0);
            }
            float s = 0.f;
#pragma unroll
            for (int r = 0; r < 4; r++) {
                int row = row0 + w * 16 + lq * 4 + r;
                if (row < NTX) s += tanhf(acc[r]);
            }
            s += __shfl_xor(s, 16);
            s += __shfl_xor(s, 32);
            pn[n] = s;
        }

        __syncthreads();                  // all waves done reading xt
        float* Sblk = (float*)&xt[0][0];  // reuse xt as [4][128] float
        if (l < 16) {
#pragma unroll
            for (int n = 0; n < 8; n++)
                Sblk[w * 128 + n * 16 + l15] = pn[n];
        }
        __syncthreads();
        if (t < 128)
            part[((size_t)y * PBM + blockIdx.x) * 128 + t] =
                Sblk[t] + Sblk[128 + t] + Sblk[256 + t] + Sblk[384 + t];
    }
}

// ---------------------------------------------------------------------------
// reduce partials -> S_k[c]
// ---------------------------------------------------------------------------
__global__ __launch_bounds__(128) void reduceS_kernel(
    const float* __restrict__ part, float* __restrict__ S_at, float* __restrict__ S_tt)
{
    const int k = blockIdx.y;
    const int c = threadIdx.x;
    float* S = (k == 0) ? S_at : S_tt;
    const int b0 = blockIdx.x * 25;
    const int b1 = min(b0 + 25, PBM);
    float s = 0.f;
    for (int b = b0; b < b1; b++)
        s += part[((size_t)k * PBM + b) * 128 + c];
    atomicAdd(&S[c], s);
}

// ---------------------------------------------------------------------------
// attn: score_k = (q . S_k) / NTX; attn = softmax over k=2
// ---------------------------------------------------------------------------
__global__ __launch_bounds__(128) void attn_kernel(
    const float* __restrict__ S0, const float* __restrict__ S1,
    const float* __restrict__ q, float* __restrict__ attn)
{
    __shared__ float r0[128], r1[128];
    int c = threadIdx.x;
    r0[c] = q[c] * S0[c];
    r1[c] = q[c] * S1[c];
    __syncthreads();
    for (int s = 64; s > 0; s >>= 1) {
        if (c < s) { r0[c] += r0[c + s]; r1[c] += r1[c + s]; }
        __syncthreads();
    }
    if (c == 0) {
        float s0 = r0[0] / (float)NTX, s1 = r1[0] / (float)NTX;
        float m = fmaxf(s0, s1);
        float e0 = expf(s0 - m), e1 = expf(s1 - m);
        float inv = 1.f / (e0 + e1);
        attn[0] = e0 * inv;
        attn[1] = e1 * inv;
    }
}

// ---------------------------------------------------------------------------
// final_pool: batch is SORTED -> group g is a contiguous run [lo,hi).
// 1024 threads = 8 row-slices x 128 channels; LDS tree over slices,
// then fused 128->2 linear.
// ---------------------------------------------------------------------------
__device__ __forceinline__ int lower_bound_g(const int* __restrict__ batch, int val)
{
    int lo = 0, hi = NTX;
    while (lo < hi) {
        int mid = (lo + hi) >> 1;
        if (batch[mid] < val) lo = mid + 1; else hi = mid;
    }
    return lo;
}

__global__ __launch_bounds__(1024) void final_pool_kernel(
    const f16* __restrict__ out_at, const f16* __restrict__ out_tt,
    const int* __restrict__ batch, const float* __restrict__ attn,
    const float* __restrict__ Wl, const float* __restrict__ bl,
    float* __restrict__ out)
{
    __shared__ float r0s[8][128], r1s[8][128];
    const int g = blockIdx.x;
    const int t = threadIdx.x;
    const int sub = t >> 7, c = t & 127;
    const int lo = lower_bound_g(batch, g);
    const int hi = lower_bound_g(batch, g + 1);
    float s0 = 0.f, s1 = 0.f;
    for (int n = lo + sub; n < hi; n += 8) {
        s0 += (float)out_at[(size_t)n * 128 + c];
        s1 += (float)out_tt[(size_t)n * 128 + c];
    }
    r0s[sub][c] = s0;
    r1s[sub][c] = s1;
    __syncthreads();
    for (int o = 4; o > 0; o >>= 1) {
        if (sub < o) {
            r0s[sub][c] += r0s[sub + o][c];
            r1s[sub][c] += r1s[sub + o][c];
        }
        __syncthreads();
    }
    if (t < 128) {
        float pooled = (attn[0] * r0s[0][t] + attn[1] * r1s[0][t])
                     / fmaxf((float)(hi - lo), 1.f);
        r0s[1][t] = pooled * Wl[t * 2 + 0];
        r1s[1][t] = pooled * Wl[t * 2 + 1];
    }
    __syncthreads();
    for (int s = 64; s > 0; s >>= 1) {
        if (t < s) { r0s[1][t] += r0s[1][t + s]; r1s[1][t] += r1s[1][t + s]; }
        __syncthreads();
    }
    if (t == 0) {
        out[g * 2 + 0] = r0s[1][0] + bl[0];
        out[g * 2 + 1] = r1s[1][0] + bl[1];
    }
}

// ---------------------------------------------------------------------------
extern "C" void kernel_launch(void* const* d_in, const int* in_sizes, int n_in,
                              void* d_out, int out_size, void* d_ws, size_t ws_size,
                              hipStream_t stream)
{
    const float* x_tx     = (const float*)d_in[0];
    const float* x_ad     = (const float*)d_in[1];
    // d_in[2] = ei_ta (dead: out_ta never consumed)
    const int*   ei_at    = (const int*)d_in[3];
    const int*   ei_tt    = (const int*)d_in[4];
    const int*   batch    = (const int*)d_in[5];
    const float* W_tx     = (const float*)d_in[6];
    const float* b_tx     = (const float*)d_in[7];
    const float* W_ad     = (const float*)d_in[8];
    const float* b_ad     = (const float*)d_in[9];
    // d_in[10], d_in[11] = a_src_ta, a_dst_ta (dead)
    const float* a_src_at = (const float*)d_in[12];
    const float* a_dst_at = (const float*)d_in[13];
    const float* a_src_tt = (const float*)d_in[14];
    const float* a_dst_tt = (const float*)d_in[15];
    const float* Wk       = (const float*)d_in[16];
    const float* bk       = (const float*)d_in[17];
    const float* q        = (const float*)d_in[18];
    const float* Wl       = (const float*)d_in[19];
    const float* bl       = (const float*)d_in[20];
    float* out = (float*)d_out;

    char* ws = (char*)d_ws;
    size_t off = 0;
    auto alloc = [&](size_t bytes) -> void* {
        void* p = ws + off;
        off += (bytes + 255) & ~(size_t)255;
        return p;
    };
    f16* h_tx      = (f16*)alloc((size_t)NTX * 128 * 2);
    f16* h_ad      = (f16*)alloc((size_t)NADDR * 128 * 2);
    f16* Wt_txg    = (f16*)alloc((size_t)128 * 128 * 2);   // pre-transposed fp16 weights
    f16* Wt_adg    = (f16*)alloc((size_t)128 * 128 * 2);
    f16* Wktg      = (f16*)alloc((size_t)128 * 128 * 2);
    float* al_sat  = (float*)alloc((size_t)NADDR * 4 * 4);
    float* al_dat  = (float*)alloc((size_t)NTX * 4 * 4);
    float* al_stt  = (float*)alloc((size_t)NTX * 4 * 4);
    float* al_dtt  = (float*)alloc((size_t)NTX * 4 * 4);
    f16* out_at    = (f16*)alloc((size_t)NTX * 128 * 2);   // fully written by gather
    f16* out_tt    = (f16*)alloc((size_t)NTX * 128 * 2);
    int* csr_at    = (int*)alloc((size_t)NE * 4);
    int* csr_tt    = (int*)alloc((size_t)NE * 4);
    int* rank_at   = (int*)alloc((size_t)NE * 4);
    int* rank_tt   = (int*)alloc((size_t)NE * 4);
    int* row_at    = (int*)alloc((size_t)NTX * 4);
    int* row_tt    = (int*)alloc((size_t)NTX * 4);
    int* csum      = (int*)alloc((size_t)2 * NCHUNK * 4);
    float* part    = (float*)alloc((size_t)2 * PBM * 128 * 4);
    // ---- zeroed region (counters / S accumulators) ----
    char* zero0 = ws + off;
    int* deg_at    = (int*)alloc((size_t)NTX * 4);
    int* deg_tt    = (int*)alloc((size_t)NTX * 4);
    float* S_at    = (float*)alloc(128 * 4);
    float* S_tt    = (float*)alloc(128 * 4);
    size_t zbytes = (size_t)((ws + off) - zero0);
    float* attnw   = (float*)alloc(2 * 4);

    hipMemsetAsync(zero0, 0, zbytes, stream);

    // one-shot fp16 weight transposes
    dim3 pgrid(4, 3);
    prep_kernel<<<pgrid, 256, 0, stream>>>(W_tx, W_ad, Wk, Wt_txg, Wt_adg, Wktg);

    // projections + attention-logit dots (MFMA, both node types, one dispatch)
    proj2_kernel<<<2 * PBM, 256, 0, stream>>>(
        x_tx, Wt_txg, b_tx, h_tx, x_ad, Wt_adg, b_ad, h_ad,
        a_dst_at, al_dat, a_src_tt, al_stt, a_dst_tt, al_dtt,
        a_src_at, al_sat);

    // CSR build (dst-major), both edge types per dispatch
    int eb2 = (2 * NE + 255) / 256;
    deg2_kernel<<<eb2, 256, 0, stream>>>(ei_at, ei_tt, deg_at, deg_tt,
                                         rank_at, rank_tt);
    dim3 sgrid(NCHUNK, 2);
    chunksum_kernel<<<sgrid, 256, 0, stream>>>(deg_at, deg_tt, csum);
    chunkscan_kernel<<<2, 256, 0, stream>>>(csum);
    scanwrite_kernel<<<sgrid, 256, 0, stream>>>(deg_at, deg_tt, csum, row_at, row_tt);
    fill2_kernel<<<eb2, 256, 0, stream>>>(
        ei_at, rank_at, row_at, csr_at,
        ei_tt, rank_tt, row_tt, csr_tt);

    // gather-style GAT: 16 lanes/dst, 16 dsts per block (50000 = 3125*16)
    dim3 ggrid(NTX / 16, 2);
    gat_gather2_kernel<<<ggrid, 256, 0, stream>>>(
        row_at, deg_at, csr_at, al_sat, al_dat, h_ad, out_at,
        row_tt, deg_tt, csr_tt, al_stt, al_dtt, h_tx, out_tt);

    // semantic attention: MFMA tanh GEMM (both metapaths/block) -> reduce -> softmax
    tanh_gemm_kernel<<<PBM, 256, 0, stream>>>(out_at, out_tt, Wktg, bk, part);
    dim3 rgrid(32, 2);
    reduceS_kernel<<<rgrid, 128, 0, stream>>>(part, S_at, S_tt);
    attn_kernel<<<1, 128, 0, stream>>>(S_at, S_tt, q, attnw);

    // fused pooling (sorted batch -> contiguous runs) + final linear
    final_pool_kernel<<<GG, 1024, 0, stream>>>(out_at, out_tt, batch, attnw, Wl, bl, out);
}

// Round 14
// 193.005 us; speedup vs baseline: 11.6252x; 1.0191x over previous
//
#include <hip/hip_runtime.h>

#define NTX   50000
#define NADDR 50000
#define NE    500000
#define GG    512
#define NEG   0.2f
#define MBLK  64
#define PBM   782    // ceil(50000/64)
#define NCHUNK 196   // ceil(50000/256)
#define GBLK  3125   // NTX/16 dst-blocks per edge type

typedef _Float16 f16;
typedef f16 f16x4 __attribute__((ext_vector_type(4)));
typedef f16 f16x8 __attribute__((ext_vector_type(8)));
typedef float f32x2 __attribute__((ext_vector_type(2)));
typedef float f32x4 __attribute__((ext_vector_type(4)));

__device__ __forceinline__ float lrelu(float x) { return x > 0.f ? x : NEG * x; }

// ---------------------------------------------------------------------------
// prep: fp16-transpose the three 128x128 weight matrices ONCE.
// ---------------------------------------------------------------------------
__global__ __launch_bounds__(256) void prep_kernel(
    const float* __restrict__ W_tx, const float* __restrict__ W_ad,
    const float* __restrict__ Wk,
    f16* __restrict__ Wt_tx, f16* __restrict__ Wt_ad, f16* __restrict__ Wkt)
{
    const float* W = (blockIdx.y == 0) ? W_tx : (blockIdx.y == 1) ? W_ad : Wk;
    f16* Wt        = (blockIdx.y == 0) ? Wt_tx : (blockIdx.y == 1) ? Wt_ad : Wkt;
    __shared__ f16 tile[32][136];
    const int t = threadIdx.x;
    const int j0 = blockIdx.x * 32;
    for (int i = t; i < 32 * 128; i += 256) {
        int r = i >> 7, c = i & 127;
        tile[r][c] = (f16)W[(size_t)(j0 + r) * 128 + c];
    }
    __syncthreads();
    for (int i = t; i < 128 * 8; i += 256) {
        int c = i >> 3, q = i & 7;
        f16x4 p = { tile[q * 4 + 0][c], tile[q * 4 + 1][c],
                    tile[q * 4 + 2][c], tile[q * 4 + 3][c] };
        *(f16x4*)&Wt[(size_t)c * 128 + j0 + q * 4] = p;
    }
}

// ---------------------------------------------------------------------------
// proj2 (MFMA): h = fp16(x @ W + b), fused attention-logit dots (fp32).
// ---------------------------------------------------------------------------
__global__ __launch_bounds__(256) void proj2_kernel(
    const float* __restrict__ x_tx, const f16* __restrict__ Wt_txg,
    const float* __restrict__ b_tx, f16* __restrict__ h_tx,
    const float* __restrict__ x_ad, const f16* __restrict__ Wt_adg,
    const float* __restrict__ b_ad, f16* __restrict__ h_ad,
    const float* __restrict__ a_dat, float* __restrict__ al_dat,
    const float* __restrict__ a_stt, float* __restrict__ al_stt,
    const float* __restrict__ a_dtt, float* __restrict__ al_dtt,
    const float* __restrict__ a_sat, float* __restrict__ al_sat)
{
    __shared__ f16 Wt[128][136];   // padded: 272 B row stride (16B-aligned)
    __shared__ f16 xt[MBLK][136];
    const bool is_tx = blockIdx.x < PBM;
    const float* x  = is_tx ? x_tx : x_ad;
    const f16* Wtg  = is_tx ? Wt_txg : Wt_adg;
    const float* b  = is_tx ? b_tx : b_ad;
    f16* h          = is_tx ? h_tx : h_ad;
    const int row0 = (is_tx ? blockIdx.x : blockIdx.x - PBM) * MBLK;
    const int t = threadIdx.x;

    {
        const f16x8* G = (const f16x8*)Wtg;
        for (int i = t; i < 128 * 16; i += 256) {
            int r = i >> 4, q = i & 15;
            *(f16x8*)&Wt[r][q * 8] = G[i];
        }
    }
    for (int i = t; i < MBLK * 32; i += 256) {
        int r = i >> 5, q = i & 31;
        int gr = row0 + r; if (gr >= NTX) gr = NTX - 1;
        float4 v = ((const float4*)x)[(size_t)gr * 32 + q];
        f16x4 p = {(f16)v.x, (f16)v.y, (f16)v.z, (f16)v.w};
        *(f16x4*)&xt[r][q * 4] = p;
    }
    __syncthreads();

    const int l = t & 63, w = t >> 6;
    const int l15 = l & 15, lq = l >> 4;

    f16x8 afrag[4];
#pragma unroll
    for (int kt = 0; kt < 4; kt++)
        afrag[kt] = *(const f16x8*)&xt[w * 16 + l15][kt * 32 + lq * 8];

    f32x4 acc[8];
#pragma unroll
    for (int n = 0; n < 8; n++) {
        float bc = b[n * 16 + l15];
        acc[n] = (f32x4){bc, bc, bc, bc};
#pragma unroll
        for (int kt = 0; kt < 4; kt++) {
            f16x8 bfrag = *(const f16x8*)&Wt[n * 16 + l15][kt * 32 + lq * 8];
            acc[n] = __builtin_amdgcn_mfma_f32_16x16x32_f16(afrag[kt], bfrag, acc[n], 0, 0, 0);
        }
    }

#pragma unroll
    for (int r = 0; r < 4; r++) {
        int row = row0 + w * 16 + lq * 4 + r;
        if (row < NTX) {
#pragma unroll
            for (int n = 0; n < 8; n++)
                h[(size_t)row * 128 + n * 16 + l15] = (f16)acc[n][r];
        }
    }

    auto do_dot = [&](const float* __restrict__ a, float* __restrict__ al) {
        float av[8];
#pragma unroll
        for (int n = 0; n < 8; n++) av[n] = a[n * 16 + l15];
#pragma unroll
        for (int r = 0; r < 4; r++) {
            float p0 = acc[0][r] * av[0] + acc[1][r] * av[1];
            float p1 = acc[2][r] * av[2] + acc[3][r] * av[3];
            float p2 = acc[4][r] * av[4] + acc[5][r] * av[5];
            float p3 = acc[6][r] * av[6] + acc[7][r] * av[7];
#pragma unroll
            for (int o = 1; o < 16; o <<= 1) {
                p0 += __shfl_xor(p0, o); p1 += __shfl_xor(p1, o);
                p2 += __shfl_xor(p2, o); p3 += __shfl_xor(p3, o);
            }
            int row = row0 + w * 16 + lq * 4 + r;
            if (l15 == 0 && row < NTX) {
                float4 v = make_float4(p0, p1, p2, p3);
                *(float4*)&al[(size_t)row * 4] = v;
            }
        }
    };
    if (is_tx) { do_dot(a_dat, al_dat); do_dot(a_stt, al_stt); do_dot(a_dtt, al_dtt); }
    else       { do_dot(a_sat, al_sat); }
}

// ---------------------------------------------------------------------------
// CSR build: deg2 (+rank capture) -> chunksum -> chunkscan -> scanwrite -> fill
// ---------------------------------------------------------------------------
__global__ __launch_bounds__(256) void deg2_kernel(
    const int* __restrict__ ei0, const int* __restrict__ ei1,
    int* __restrict__ deg0, int* __restrict__ deg1,
    int* __restrict__ rank0, int* __restrict__ rank1)
{
    int idx = blockIdx.x * 256 + threadIdx.x;
    if (idx < NE) rank0[idx] = atomicAdd(&deg0[ei0[NE + idx]], 1);
    else if (idx < 2 * NE) rank1[idx - NE] = atomicAdd(&deg1[ei1[NE + (idx - NE)]], 1);
}

__global__ __launch_bounds__(256) void chunksum_kernel(
    const int* __restrict__ deg0, const int* __restrict__ deg1,
    int* __restrict__ csum)   // [2][NCHUNK]
{
    const int* deg = blockIdx.y == 0 ? deg0 : deg1;
    __shared__ int s[256];
    const int t = threadIdx.x;
    int idx = blockIdx.x * 256 + t;
    s[t] = idx < NTX ? deg[idx] : 0;
    __syncthreads();
    for (int o = 128; o > 0; o >>= 1) {
        if (t < o) s[t] += s[t + o];
        __syncthreads();
    }
    if (t == 0) csum[blockIdx.y * NCHUNK + blockIdx.x] = s[0];
}

__global__ __launch_bounds__(256) void chunkscan_kernel(int* __restrict__ csum)
{
    __shared__ int s[256];
    const int t = threadIdx.x;
    int* base = csum + blockIdx.x * NCHUNK;
    int v = t < NCHUNK ? base[t] : 0;
    s[t] = v;
    __syncthreads();
    for (int o = 1; o < 256; o <<= 1) {
        int u = (t >= o) ? s[t - o] : 0;
        __syncthreads();
        s[t] += u;
        __syncthreads();
    }
    if (t < NCHUNK) base[t] = s[t] - v;   // exclusive
}

__global__ __launch_bounds__(256) void scanwrite_kernel(
    const int* __restrict__ deg0, const int* __restrict__ deg1,
    const int* __restrict__ csum,
    int* __restrict__ row0, int* __restrict__ row1)
{
    const int* deg = blockIdx.y == 0 ? deg0 : deg1;
    int* row       = blockIdx.y == 0 ? row0 : row1;
    __shared__ int s[256];
    const int t = threadIdx.x;
    int idx = blockIdx.x * 256 + t;
    int v = idx < NTX ? deg[idx] : 0;
    s[t] = v;
    __syncthreads();
    for (int o = 1; o < 256; o <<= 1) {
        int u = (t >= o) ? s[t - o] : 0;
        __syncthreads();
        s[t] += u;
        __syncthreads();
    }
    if (idx < NTX)
        row[idx] = s[t] - v + csum[blockIdx.y * NCHUNK + blockIdx.x];
}

// fill: NO atomics. pos = row[dst] + rank[e]; one scattered 4B store.
__global__ __launch_bounds__(256) void fill2_kernel(
    const int* __restrict__ ei0, const int* __restrict__ rank0,
    const int* __restrict__ row0, int* __restrict__ csr0,
    const int* __restrict__ ei1, const int* __restrict__ rank1,
    const int* __restrict__ row1, int* __restrict__ csr1)
{
    int idx = blockIdx.x * 256 + threadIdx.x;
    const int* ei; const int* rank; const int* row; int* csr;
    int e;
    if (idx < NE)          { ei = ei0; rank = rank0; row = row0; csr = csr0; e = idx; }
    else if (idx < 2 * NE) { ei = ei1; rank = rank1; row = row1; csr = csr1; e = idx - NE; }
    else return;
    int s = ei[e];
    int d = ei[NE + e];
    csr[row[d] + rank[e]] = s;
}

// ---------------------------------------------------------------------------
// Gather GAT: 16 lanes per dst (f16x8/lane = 256B row per group), 4 dsts/wave,
// 16 dsts per 256-thr block. Flat 1D grid; edge type chosen by (bid&4) so
// XCDs 0-3 stream h_ad and XCDs 4-7 stream h_tx (blockIdx->XCD = %8):
// halves each XCD's L2 working set. 4-edge unroll for MLP; f32x2 packed acc
// (v_pk_fma_f32). Softmax weights inline: w = exp(lrelu(als[s]+ald[d])).
// ---------------------------------------------------------------------------
__global__ __launch_bounds__(256) void gat_gather2_kernel(
    const int* __restrict__ row_at, const int* __restrict__ deg_at,
    const int* __restrict__ csr_at, const float* __restrict__ als_at,
    const float* __restrict__ ald_at, const f16* __restrict__ h_at,
    f16* __restrict__ out_at,
    const int* __restrict__ row_tt, const int* __restrict__ deg_tt,
    const int* __restrict__ csr_tt, const float* __restrict__ als_tt,
    const float* __restrict__ ald_tt, const f16* __restrict__ h_tt,
    f16* __restrict__ out_tt)
{
    const int bid = blockIdx.x;
    const bool at = ((bid & 4) == 0);
    const int dblk = (bid >> 3) * 4 + (bid & 3);
    if (dblk >= GBLK) return;

    const int* rs = at ? row_at : row_tt;
    const int* dg = at ? deg_at : deg_tt;
    const int* cs = at ? csr_at : csr_tt;
    const float* als = at ? als_at : als_tt;
    const float* ald = at ? ald_at : ald_tt;
    const f16* hsrc = at ? h_at : h_tt;
    f16* out = at ? out_at : out_tt;

    const int t = threadIdx.x;
    const int d = dblk * 16 + (t >> 4);         // uniform per 16-lane group
    const int ln8 = t & 15;                     // chunk: channels [ln8*8, ln8*8+8)
    const int head = ln8 >> 2;
    const int beg = rs[d];
    const int n = dg[d];
    const float aldv = ald[d * 4 + head];
    const f16x8* H = (const f16x8*)hsrc;

    f32x2 acc[4] = {{0.f, 0.f}, {0.f, 0.f}, {0.f, 0.f}, {0.f, 0.f}};
    float den = 0.f;
    int i = 0;
    for (; i + 4 <= n; i += 4) {
        int s0 = cs[beg + i],     s1 = cs[beg + i + 1];
        int s2 = cs[beg + i + 2], s3 = cs[beg + i + 3];
        float l0 = als[s0 * 4 + head], l1 = als[s1 * 4 + head];
        float l2 = als[s2 * 4 + head], l3 = als[s3 * 4 + head];
        f16x8 h0 = H[(size_t)s0 * 16 + ln8];
        f16x8 h1 = H[(size_t)s1 * 16 + ln8];
        f16x8 h2 = H[(size_t)s2 * 16 + ln8];
        f16x8 h3 = H[(size_t)s3 * 16 + ln8];
        float w0 = __expf(lrelu(l0 + aldv));
        float w1 = __expf(lrelu(l1 + aldv));
        float w2 = __expf(lrelu(l2 + aldv));
        float w3 = __expf(lrelu(l3 + aldv));
        den += (w0 + w1) + (w2 + w3);
#pragma unroll
        for (int q = 0; q < 4; q++) {
            f32x2 a0 = {(float)h0[2 * q], (float)h0[2 * q + 1]};
            f32x2 a1 = {(float)h1[2 * q], (float)h1[2 * q + 1]};
            f32x2 a2 = {(float)h2[2 * q], (float)h2[2 * q + 1]};
            f32x2 a3 = {(float)h3[2 * q], (float)h3[2 * q + 1]};
            acc[q] = a0 * w0 + (a1 * w1 + (a2 * w2 + (a3 * w3 + acc[q])));
        }
    }
    for (; i < n; i++) {
        int s0 = cs[beg + i];
        float l0 = als[s0 * 4 + head];
        f16x8 h0 = H[(size_t)s0 * 16 + ln8];
        float w0 = __expf(lrelu(l0 + aldv));
        den += w0;
#pragma unroll
        for (int q = 0; q < 4; q++) {
            f32x2 a0 = {(float)h0[2 * q], (float)h0[2 * q + 1]};
            acc[q] = a0 * w0 + acc[q];
        }
    }
    float inv = 1.f / (den + 1e-16f);
    f16x8 o;
#pragma unroll
    for (int q = 0; q < 4; q++) {
        float v0 = acc[q][0] * inv, v1 = acc[q][1] * inv;
        o[2 * q]     = (f16)(v0 > 0.f ? v0 : 0.f);
        o[2 * q + 1] = (f16)(v1 > 0.f ? v1 : 0.f);
    }
    ((f16x8*)out)[(size_t)d * 16 + ln8] = o;
}

// ---------------------------------------------------------------------------
// tanh GEMM (MFMA): BOTH metapaths per block -- Wk^T staged once (pre-transposed).
// ---------------------------------------------------------------------------
__global__ __launch_bounds__(256) void tanh_gemm_kernel(
    const f16* __restrict__ out_at, const f16* __restrict__ out_tt,
    const f16* __restrict__ Wktg, const float* __restrict__ bk,
    float* __restrict__ part)    // [2][PBM][128]
{
    __shared__ f16 Wt[128][136];
    __shared__ f16 xt[MBLK][136];
    const int row0 = blockIdx.x * MBLK;
    const int t = threadIdx.x;

    {
        const f16x8* G = (const f16x8*)Wktg;
        for (int i = t; i < 128 * 16; i += 256) {
            int r = i >> 4, q = i & 15;
            *(f16x8*)&Wt[r][q * 8] = G[i];
        }
    }

    const int l = t & 63, w = t >> 6;
    const int l15 = l & 15, lq = l >> 4;

    for (int y = 0; y < 2; y++) {
        const f16* src = (y == 0) ? out_at : out_tt;
        __syncthreads();   // y=0: nothing yet; y=1: Sblk reads done
        for (int i = t; i < MBLK * 16; i += 256) {
            int r = i >> 4, q = i & 15;
            int gr = row0 + r; if (gr >= NTX) gr = NTX - 1;
            *(f16x8*)&xt[r][q * 8] = ((const f16x8*)src)[(size_t)gr * 16 + q];
        }
        __syncthreads();   // xt (and Wt, first pass) staged

        f16x8 afrag[4];
#pragma unroll
        for (int kt = 0; kt < 4; kt++)
            afrag[kt] = *(const f16x8*)&xt[w * 16 + l15][kt * 32 + lq * 8];

        float pn[8];
#pragma unroll
        for (int n = 0; n < 8; n++) {
            float bc = bk[n * 16 + l15];
            f32x4 acc = (f32x4){bc, bc, bc, bc};
#pragma unroll
            for (int kt = 0; kt < 4; kt++) {
                f16x8 bfrag = *(const f16x8*)&Wt[n * 16 + l15][kt * 32 + lq * 8];
                acc = __builtin_amdgcn_mfma_f32_16x16x32_f16(afrag[kt], bfrag, acc, 0, 0, 0);
            }
            float s = 0.f;
#pragma unroll
            for (int r = 0; r < 4; r++) {
                int row = row0 + w * 16 + lq * 4 + r;
                if (row < NTX) s += tanhf(acc[r]);
            }
            s += __shfl_xor(s, 16);
            s += __shfl_xor(s, 32);
            pn[n] = s;
        }

        __syncthreads();                  // all waves done reading xt
        float* Sblk = (float*)&xt[0][0];  // reuse xt as [4][128] float
        if (l < 16) {
#pragma unroll
            for (int n = 0; n < 8; n++)
                Sblk[w * 128 + n * 16 + l15] = pn[n];
        }
        __syncthreads();
        if (t < 128)
            part[((size_t)y * PBM + blockIdx.x) * 128 + t] =
                Sblk[t] + Sblk[128 + t] + Sblk[256 + t] + Sblk[384 + t];
    }
}

// ---------------------------------------------------------------------------
// reduce partials -> S_k[c]
// ---------------------------------------------------------------------------
__global__ __launch_bounds__(128) void reduceS_kernel(
    const float* __restrict__ part, float* __restrict__ S_at, float* __restrict__ S_tt)
{
    const int k = blockIdx.y;
    const int c = threadIdx.x;
    float* S = (k == 0) ? S_at : S_tt;
    const int b0 = blockIdx.x * 25;
    const int b1 = min(b0 + 25, PBM);
    float s = 0.f;
    for (int b = b0; b < b1; b++)
        s += part[((size_t)k * PBM + b) * 128 + c];
    atomicAdd(&S[c], s);
}

// ---------------------------------------------------------------------------
// attn: score_k = (q . S_k) / NTX; attn = softmax over k=2
// ---------------------------------------------------------------------------
__global__ __launch_bounds__(128) void attn_kernel(
    const float* __restrict__ S0, const float* __restrict__ S1,
    const float* __restrict__ q, float* __restrict__ attn)
{
    __shared__ float r0[128], r1[128];
    int c = threadIdx.x;
    r0[c] = q[c] * S0[c];
    r1[c] = q[c] * S1[c];
    __syncthreads();
    for (int s = 64; s > 0; s >>= 1) {
        if (c < s) { r0[c] += r0[c + s]; r1[c] += r1[c + s]; }
        __syncthreads();
    }
    if (c == 0) {
        float s0 = r0[0] / (float)NTX, s1 = r1[0] / (float)NTX;
        float m = fmaxf(s0, s1);
        float e0 = expf(s0 - m), e1 = expf(s1 - m);
        float inv = 1.f / (e0 + e1);
        attn[0] = e0 * inv;
        attn[1] = e1 * inv;
    }
}

// ---------------------------------------------------------------------------
// final_pool: batch is SORTED -> group g is a contiguous run [lo,hi).
// 1024 threads = 8 row-slices x 128 channels; LDS tree over slices,
// then fused 128->2 linear.
// ---------------------------------------------------------------------------
__device__ __forceinline__ int lower_bound_g(const int* __restrict__ batch, int val)
{
    int lo = 0, hi = NTX;
    while (lo < hi) {
        int mid = (lo + hi) >> 1;
        if (batch[mid] < val) lo = mid + 1; else hi = mid;
    }
    return lo;
}

__global__ __launch_bounds__(1024) void final_pool_kernel(
    const f16* __restrict__ out_at, const f16* __restrict__ out_tt,
    const int* __restrict__ batch, const float* __restrict__ attn,
    const float* __restrict__ Wl, const float* __restrict__ bl,
    float* __restrict__ out)
{
    __shared__ float r0s[8][128], r1s[8][128];
    const int g = blockIdx.x;
    const int t = threadIdx.x;
    const int sub = t >> 7, c = t & 127;
    const int lo = lower_bound_g(batch, g);
    const int hi = lower_bound_g(batch, g + 1);
    float s0 = 0.f, s1 = 0.f;
    for (int n = lo + sub; n < hi; n += 8) {
        s0 += (float)out_at[(size_t)n * 128 + c];
        s1 += (float)out_tt[(size_t)n * 128 + c];
    }
    r0s[sub][c] = s0;
    r1s[sub][c] = s1;
    __syncthreads();
    for (int o = 4; o > 0; o >>= 1) {
        if (sub < o) {
            r0s[sub][c] += r0s[sub + o][c];
            r1s[sub][c] += r1s[sub + o][c];
        }
        __syncthreads();
    }
    if (t < 128) {
        float pooled = (attn[0] * r0s[0][t] + attn[1] * r1s[0][t])
                     / fmaxf((float)(hi - lo), 1.f);
        r0s[1][t] = pooled * Wl[t * 2 + 0];
        r1s[1][t] = pooled * Wl[t * 2 + 1];
    }
    __syncthreads();
    for (int s = 64; s > 0; s >>= 1) {
        if (t < s) { r0s[1][t] += r0s[1][t + s]; r1s[1][t] += r1s[1][t + s]; }
        __syncthreads();
    }
    if (t == 0) {
        out[g * 2 + 0] = r0s[1][0] + bl[0];
        out[g * 2 + 1] = r1s[1][0] + bl[1];
    }
}

// ---------------------------------------------------------------------------
extern "C" void kernel_launch(void* const* d_in, const int* in_sizes, int n_in,
                              void* d_out, int out_size, void* d_ws, size_t ws_size,
                              hipStream_t stream)
{
    const float* x_tx     = (const float*)d_in[0];
    const float* x_ad     = (const float*)d_in[1];
    // d_in[2] = ei_ta (dead: out_ta never consumed)
    const int*   ei_at    = (const int*)d_in[3];
    const int*   ei_tt    = (const int*)d_in[4];
    const int*   batch    = (const int*)d_in[5];
    const float* W_tx     = (const float*)d_in[6];
    const float* b_tx     = (const float*)d_in[7];
    const float* W_ad     = (const float*)d_in[8];
    const float* b_ad     = (const float*)d_in[9];
    // d_in[10], d_in[11] = a_src_ta, a_dst_ta (dead)
    const float* a_src_at = (const float*)d_in[12];
    const float* a_dst_at = (const float*)d_in[13];
    const float* a_src_tt = (const float*)d_in[14];
    const float* a_dst_tt = (const float*)d_in[15];
    const float* Wk       = (const float*)d_in[16];
    const float* bk       = (const float*)d_in[17];
    const float* q        = (const float*)d_in[18];
    const float* Wl       = (const float*)d_in[19];
    const float* bl       = (const float*)d_in[20];
    float* out = (float*)d_out;

    char* ws = (char*)d_ws;
    size_t off = 0;
    auto alloc = [&](size_t bytes) -> void* {
        void* p = ws + off;
        off += (bytes + 255) & ~(size_t)255;
        return p;
    };
    f16* h_tx      = (f16*)alloc((size_t)NTX * 128 * 2);
    f16* h_ad      = (f16*)alloc((size_t)NADDR * 128 * 2);
    f16* Wt_txg    = (f16*)alloc((size_t)128 * 128 * 2);   // pre-transposed fp16 weights
    f16* Wt_adg    = (f16*)alloc((size_t)128 * 128 * 2);
    f16* Wktg      = (f16*)alloc((size_t)128 * 128 * 2);
    float* al_sat  = (float*)alloc((size_t)NADDR * 4 * 4);
    float* al_dat  = (float*)alloc((size_t)NTX * 4 * 4);
    float* al_stt  = (float*)alloc((size_t)NTX * 4 * 4);
    float* al_dtt  = (float*)alloc((size_t)NTX * 4 * 4);
    f16* out_at    = (f16*)alloc((size_t)NTX * 128 * 2);   // fully written by gather
    f16* out_tt    = (f16*)alloc((size_t)NTX * 128 * 2);
    int* csr_at    = (int*)alloc((size_t)NE * 4);
    int* csr_tt    = (int*)alloc((size_t)NE * 4);
    int* rank_at   = (int*)alloc((size_t)NE * 4);
    int* rank_tt   = (int*)alloc((size_t)NE * 4);
    int* row_at    = (int*)alloc((size_t)NTX * 4);
    int* row_tt    = (int*)alloc((size_t)NTX * 4);
    int* csum      = (int*)alloc((size_t)2 * NCHUNK * 4);
    float* part    = (float*)alloc((size_t)2 * PBM * 128 * 4);
    // ---- zeroed region (counters / S accumulators) ----
    char* zero0 = ws + off;
    int* deg_at    = (int*)alloc((size_t)NTX * 4);
    int* deg_tt    = (int*)alloc((size_t)NTX * 4);
    float* S_at    = (float*)alloc(128 * 4);
    float* S_tt    = (float*)alloc(128 * 4);
    size_t zbytes = (size_t)((ws + off) - zero0);
    float* attnw   = (float*)alloc(2 * 4);

    hipMemsetAsync(zero0, 0, zbytes, stream);

    // one-shot fp16 weight transposes
    dim3 pgrid(4, 3);
    prep_kernel<<<pgrid, 256, 0, stream>>>(W_tx, W_ad, Wk, Wt_txg, Wt_adg, Wktg);

    // projections + attention-logit dots (MFMA, both node types, one dispatch)
    proj2_kernel<<<2 * PBM, 256, 0, stream>>>(
        x_tx, Wt_txg, b_tx, h_tx, x_ad, Wt_adg, b_ad, h_ad,
        a_dst_at, al_dat, a_src_tt, al_stt, a_dst_tt, al_dtt,
        a_src_at, al_sat);

    // CSR build (dst-major), both edge types per dispatch
    int eb2 = (2 * NE + 255) / 256;
    deg2_kernel<<<eb2, 256, 0, stream>>>(ei_at, ei_tt, deg_at, deg_tt,
                                         rank_at, rank_tt);
    dim3 sgrid(NCHUNK, 2);
    chunksum_kernel<<<sgrid, 256, 0, stream>>>(deg_at, deg_tt, csum);
    chunkscan_kernel<<<2, 256, 0, stream>>>(csum);
    scanwrite_kernel<<<sgrid, 256, 0, stream>>>(deg_at, deg_tt, csum, row_at, row_tt);
    fill2_kernel<<<eb2, 256, 0, stream>>>(
        ei_at, rank_at, row_at, csr_at,
        ei_tt, rank_tt, row_tt, csr_tt);

    // gather-style GAT: flat grid, 8-block tiles split types across XCD halves
    gat_gather2_kernel<<<PBM * 8, 256, 0, stream>>>(
        row_at, deg_at, csr_at, al_sat, al_dat, h_ad, out_at,
        row_tt, deg_tt, csr_tt, al_stt, al_dtt, h_tx, out_tt);

    // semantic attention: MFMA tanh GEMM (both metapaths/block) -> reduce -> softmax
    tanh_gemm_kernel<<<PBM, 256, 0, stream>>>(out_at, out_tt, Wktg, bk, part);
    dim3 rgrid(32, 2);
    reduceS_kernel<<<rgrid, 128, 0, stream>>>(part, S_at, S_tt);
    attn_kernel<<<1, 128, 0, stream>>>(S_at, S_tt, q, attnw);

    // fused pooling (sorted batch -> contiguous runs) + final linear
    final_pool_kernel<<<GG, 1024, 0, stream>>>(out_at, out_tt, batch, attnw, Wl, bl, out);
}